// Round 3
// baseline (970.789 us; speedup 1.0000x reference)
//
#include <hip/hip_runtime.h>

#define NN 8192      // nodes
#define NG 128       // graphs
#define NF 128       // input feats
#define CL 512       // hidden dim
#define ZD 1536      // concat dim (3*512)
#define NE 262144    // edges per edge set

typedef __attribute__((ext_vector_type(8))) short short8;
typedef __attribute__((ext_vector_type(4))) float f32x4;

__device__ __forceinline__ unsigned short f2b(float f) {
    unsigned int u = __float_as_uint(f);
    unsigned int r = (u + 0x7fffu + ((u >> 16) & 1u)) >> 16;
    return (unsigned short)r;
}
__device__ __forceinline__ float b2f(unsigned short h) {
    return __uint_as_float(((unsigned int)h) << 16);
}

// ---------------- degree / dense adjacency ----------------
__global__ void deg_kernel(const int* __restrict__ dst, float* __restrict__ deg) {
    int e = blockIdx.x * 256 + threadIdx.x;
    atomicAdd(&deg[dst[e]], 1.0f);
}

__global__ void deg_finish(float* __restrict__ deg, float* __restrict__ dinv) {
    int n = blockIdx.x * 256 + threadIdx.x;
    float d = deg[n] + 1.0f;
    deg[n] = d;
    dinv[n] = rsqrtf(d);
}

__global__ void build_adj(const int* __restrict__ src, const int* __restrict__ dst,
                          const float* __restrict__ dinv, float* __restrict__ A) {
    int e = blockIdx.x * 256 + threadIdx.x;
    int s = src[e], d = dst[e];
    int g = d >> 6;
    atomicAdd(&A[(size_t)((g << 6) + (d & 63)) * 64 + (s & 63)], dinv[s] * dinv[d]);
}

__global__ void adj_diag(const float* __restrict__ deg, float* __restrict__ A) {
    int n = blockIdx.x * 256 + threadIdx.x;
    int g = n >> 6, i = n & 63;
    A[(size_t)(g * 64 + i) * 64 + i] += 1.0f / deg[n];
}

// ---------------- conversions (hi/lo split) ----------------
__global__ void cvt_split(const float* __restrict__ in,
                          unsigned short* __restrict__ oh, unsigned short* __restrict__ ol) {
    int i = blockIdx.x * 256 + threadIdx.x;
    float4 v = *(const float4*)(in + (size_t)i * 4);
    float vv[4] = {v.x, v.y, v.z, v.w};
    ushort4 h4, l4;
    unsigned short* hp = (unsigned short*)&h4;
    unsigned short* lp = (unsigned short*)&l4;
    #pragma unroll
    for (int j = 0; j < 4; ++j) {
        unsigned short h = f2b(vv[j]);
        hp[j] = h;
        lp[j] = f2b(vv[j] - b2f(h));
    }
    *(ushort4*)(oh + (size_t)i * 4) = h4;
    *(ushort4*)(ol + (size_t)i * 4) = l4;
}

// W: Kd x Nd row-major f32 -> Wt hi/lo: Nd x Kd row-major bf16
__global__ void cvtT(const float* __restrict__ W,
                     unsigned short* __restrict__ Wh, unsigned short* __restrict__ Wl,
                     int Kd, int Nd) {
    __shared__ float t[32][33];
    int kb = blockIdx.y * 32, nb = blockIdx.x * 32;
    int tx = threadIdx.x, ty = threadIdx.y;   // 32 x 8
    for (int i = ty; i < 32; i += 8)
        t[i][tx] = W[(size_t)(kb + i) * Nd + nb + tx];
    __syncthreads();
    for (int i = ty; i < 32; i += 8) {
        float v = t[tx][i];
        unsigned short h = f2b(v);
        Wh[(size_t)(nb + i) * Kd + kb + tx] = h;
        Wl[(size_t)(nb + i) * Kd + kb + tx] = f2b(v - b2f(h));
    }
}

// scaled transpose: Wt[n][k] = W[k][n] * s[k]  (BN fold), hi/lo
__global__ void wscaleT(const float* __restrict__ W, const float* __restrict__ s,
                        unsigned short* __restrict__ Wh, unsigned short* __restrict__ Wl,
                        int Kd, int Nd) {
    __shared__ float t[32][33];
    int kb = blockIdx.y * 32, nb = blockIdx.x * 32;
    int tx = threadIdx.x, ty = threadIdx.y;
    for (int i = ty; i < 32; i += 8)
        t[i][tx] = W[(size_t)(kb + i) * Nd + nb + tx];
    __syncthreads();
    for (int i = ty; i < 32; i += 8) {
        float v = t[tx][i] * s[kb + tx];
        unsigned short h = f2b(v);
        Wh[(size_t)(nb + i) * Kd + kb + tx] = h;
        Wl[(size_t)(nb + i) * Kd + kb + tx] = f2b(v - b2f(h));
    }
}

// bias2[n] = sum_k t[k]*W[k][n]   (BN shift folded through conv weight)
__global__ void bias_dot(const float* __restrict__ W, const float* __restrict__ t,
                         float* __restrict__ bias2, int Kd, int Nd) {
    int n = blockIdx.x * 64 + threadIdx.x;
    float acc = 0.f;
    for (int k = 0; k < Kd; ++k) acc = fmaf(t[k], W[(size_t)k * Nd + n], acc);
    bias2[n] = acc;
}

// ---------------- bf16 hi/lo MFMA GEMM: C = A @ Bt^T, 128x128 tile ----------------
// A,B given as hi/lo bf16 pairs (row-major MxK / NxK). 3-term product for ~f32 accuracy.
// SPLIT=true: write C as hi/lo bf16 pair instead of f32.
template<bool HASB, bool SPLIT>
__global__ __launch_bounds__(256)
void gemm_hl(const unsigned short* __restrict__ Ah, const unsigned short* __restrict__ Al, int lda,
             const unsigned short* __restrict__ Bh, const unsigned short* __restrict__ Bl, int ldb,
             float* __restrict__ Cf, unsigned short* __restrict__ Ch, unsigned short* __restrict__ Cl,
             int ldc, const float* __restrict__ bias, int K)
{
    __shared__ unsigned short AsH[4096], AsL[4096], BsH[4096], BsL[4096];
    const int tid = threadIdx.x;
    const int lane = tid & 63, wave = tid >> 6;
    const int wr = wave >> 1, wc = wave & 1;
    const int bm = blockIdx.y * 128, bn = blockIdx.x * 128;

    f32x4 acc[4][4];
    #pragma unroll
    for (int m = 0; m < 4; ++m)
        #pragma unroll
        for (int n = 0; n < 4; ++n)
            acc[m][n] = (f32x4){0.f, 0.f, 0.f, 0.f};

    const int lrow = lane >> 2;
    const int lkb  = (lane & 3) * 8;

    for (int k0 = 0; k0 < K; k0 += 32) {
        #pragma unroll
        for (int c = 0; c < 2; ++c) {
            int chunk = wave * 2 + c;
            int row = chunk * 16 + lrow;
            size_t offA = (size_t)(bm + row) * lda + k0 + lkb;
            size_t offB = (size_t)(bn + row) * ldb + k0 + lkb;
            __builtin_amdgcn_global_load_lds(
                (const __attribute__((address_space(1))) void*)(Ah + offA),
                (__attribute__((address_space(3))) void*)&AsH[chunk * 512], 16, 0, 0);
            __builtin_amdgcn_global_load_lds(
                (const __attribute__((address_space(1))) void*)(Al + offA),
                (__attribute__((address_space(3))) void*)&AsL[chunk * 512], 16, 0, 0);
            __builtin_amdgcn_global_load_lds(
                (const __attribute__((address_space(1))) void*)(Bh + offB),
                (__attribute__((address_space(3))) void*)&BsH[chunk * 512], 16, 0, 0);
            __builtin_amdgcn_global_load_lds(
                (const __attribute__((address_space(1))) void*)(Bl + offB),
                (__attribute__((address_space(3))) void*)&BsL[chunk * 512], 16, 0, 0);
        }
        __syncthreads();
        const int fl = lane & 15, kh = (lane >> 4) * 8;
        short8 ah[4], al[4], bh[4], bl[4];
        #pragma unroll
        for (int m = 0; m < 4; ++m) {
            int r = (wr * 64 + m * 16 + fl) * 32 + kh;
            ah[m] = *(const short8*)&AsH[r];
            al[m] = *(const short8*)&AsL[r];
        }
        #pragma unroll
        for (int n = 0; n < 4; ++n) {
            int r = (wc * 64 + n * 16 + fl) * 32 + kh;
            bh[n] = *(const short8*)&BsH[r];
            bl[n] = *(const short8*)&BsL[r];
        }
        #pragma unroll
        for (int m = 0; m < 4; ++m)
            #pragma unroll
            for (int n = 0; n < 4; ++n) {
                acc[m][n] = __builtin_amdgcn_mfma_f32_16x16x32_bf16(ah[m], bh[n], acc[m][n], 0, 0, 0);
                acc[m][n] = __builtin_amdgcn_mfma_f32_16x16x32_bf16(ah[m], bl[n], acc[m][n], 0, 0, 0);
                acc[m][n] = __builtin_amdgcn_mfma_f32_16x16x32_bf16(al[m], bh[n], acc[m][n], 0, 0, 0);
            }
        __syncthreads();
    }
    const int orow0 = (lane >> 4) * 4;
    const int ocol  = lane & 15;
    #pragma unroll
    for (int m = 0; m < 4; ++m) {
        #pragma unroll
        for (int n = 0; n < 4; ++n) {
            int col = bn + wc * 64 + n * 16 + ocol;
            float bb = HASB ? bias[col] : 0.f;
            #pragma unroll
            for (int r = 0; r < 4; ++r) {
                int rowg = bm + wr * 64 + m * 16 + orow0 + r;
                float v = acc[m][n][r] + bb;
                if (SPLIT) {
                    unsigned short h = f2b(v);
                    Ch[(size_t)rowg * ldc + col] = h;
                    Cl[(size_t)rowg * ldc + col] = f2b(v - b2f(h));
                } else {
                    Cf[(size_t)rowg * ldc + col] = v;
                }
            }
        }
    }
}

// ---------------- generic tiled f32 GEMM (fc1) ----------------
template<int ACT, bool HASB>
__global__ __launch_bounds__(256)
void gemm_f32(const float* __restrict__ A, int lda,
              const float* __restrict__ B, int ldb,
              float* __restrict__ C, int ldc,
              const float* __restrict__ bias, int K)
{
    __shared__ float As[32][68];
    __shared__ float Bs[32][68];
    const int tid = threadIdx.x;
    const int bm = blockIdx.y * 64, bn = blockIdx.x * 64;
    const int tx = tid & 15, ty = tid >> 4;
    float acc[4][4] = {};
    for (int k0 = 0; k0 < K; k0 += 32) {
        #pragma unroll
        for (int idx = tid; idx < 2048; idx += 256) {
            int m = idx >> 5, kk = idx & 31;
            As[kk][m] = A[(size_t)(bm + m) * lda + k0 + kk];
        }
        #pragma unroll
        for (int idx = tid; idx < 2048; idx += 256) {
            int kk = idx >> 6, n = idx & 63;
            Bs[kk][n] = B[(size_t)(k0 + kk) * ldb + bn + n];
        }
        __syncthreads();
        #pragma unroll
        for (int kk = 0; kk < 32; ++kk) {
            float4 a = *(const float4*)&As[kk][ty * 4];
            float4 b = *(const float4*)&Bs[kk][tx * 4];
            float av[4] = {a.x, a.y, a.z, a.w};
            float bv[4] = {b.x, b.y, b.z, b.w};
            #pragma unroll
            for (int i = 0; i < 4; ++i)
                #pragma unroll
                for (int j = 0; j < 4; ++j)
                    acc[i][j] = fmaf(av[i], bv[j], acc[i][j]);
        }
        __syncthreads();
    }
    #pragma unroll
    for (int i = 0; i < 4; ++i) {
        int r = bm + ty * 4 + i;
        #pragma unroll
        for (int j = 0; j < 4; ++j) {
            int c = bn + tx * 4 + j;
            float v = acc[i][j];
            if (HASB) v += bias[c];
            if (ACT == 1) v = v > 0.f ? v : 0.f;
            if (ACT == 2) v = v > 0.f ? v : 0.01f * v;
            C[(size_t)r * ldc + c] = v;
        }
    }
}

// ---------------- batch norm stats (reads hi/lo pair) ----------------
__global__ void bn_stats_hl(const unsigned short* __restrict__ Hh,
                            const unsigned short* __restrict__ Hl, int ldh,
                            float* __restrict__ sums, float* __restrict__ sqs)
{
    int c = blockIdx.x * 256 + threadIdx.x;
    int r0 = blockIdx.y * 256;
    float s = 0.f, q = 0.f;
    for (int r = r0; r < r0 + 256; ++r) {
        size_t idx = (size_t)r * ldh + c;
        float v = b2f(Hh[idx]) + b2f(Hl[idx]);
        s += v;
        q = fmaf(v, v, q);
    }
    atomicAdd(&sums[c], s);
    atomicAdd(&sqs[c], q);
}

// s = g*inv, t = b - m*s
__global__ void bn_coef(const float* __restrict__ sums, const float* __restrict__ sqs,
                        const float* __restrict__ g, const float* __restrict__ b,
                        float* __restrict__ s, float* __restrict__ t)
{
    int c = threadIdx.x;   // 512
    float m = sums[c] * (1.0f / NN);
    float var = sqs[c] * (1.0f / NN) - m * m;
    float inv = rsqrtf(var + 1e-5f);
    float sc = inv * g[c];
    s[c] = sc;
    t[c] = b[c] - m * sc;
}

// ---------------- GCN combine: Z = relu(A_g @ H2_g + b), hi/lo bf16 out ----------------
__global__ __launch_bounds__(256)
void gcn_combine(const float* __restrict__ A, const float* __restrict__ H2,
                 const float* __restrict__ bias,
                 unsigned short* __restrict__ outh, unsigned short* __restrict__ outl)
{
    int g = blockIdx.x, ct = blockIdx.y;
    __shared__ float At[64][68];
    __shared__ float Hs[64][68];
    int tid = threadIdx.x;
    const float* Ag = A + (size_t)g * 4096;
    for (int idx = tid; idx < 4096; idx += 256) {
        int i = idx >> 6, k = idx & 63;
        At[k][i] = Ag[idx];
    }
    for (int idx = tid; idx < 4096; idx += 256) {
        int k = idx >> 6, c = idx & 63;
        Hs[k][c] = H2[(size_t)(g * 64 + k) * CL + ct * 64 + c];
    }
    __syncthreads();
    int tx = tid & 15, ty = tid >> 4;
    float acc[4][4] = {};
    #pragma unroll
    for (int k = 0; k < 64; ++k) {
        float4 a = *(const float4*)&At[k][ty * 4];
        float4 b = *(const float4*)&Hs[k][tx * 4];
        float av[4] = {a.x, a.y, a.z, a.w};
        float bv[4] = {b.x, b.y, b.z, b.w};
        #pragma unroll
        for (int i = 0; i < 4; ++i)
            #pragma unroll
            for (int j = 0; j < 4; ++j)
                acc[i][j] = fmaf(av[i], bv[j], acc[i][j]);
    }
    #pragma unroll
    for (int i = 0; i < 4; ++i) {
        int node = g * 64 + ty * 4 + i;
        #pragma unroll
        for (int j = 0; j < 4; ++j) {
            int c = ct * 64 + tx * 4 + j;
            float v = acc[i][j] + bias[c];
            v = v > 0.f ? v : 0.f;
            unsigned short h = f2b(v);
            outh[(size_t)node * ZD + c] = h;
            outl[(size_t)node * ZD + c] = f2b(v - b2f(h));
        }
    }
}

// ---------------- per-graph Gram matrix G = Z_g Z_g^T ----------------
__global__ __launch_bounds__(256)
void gram_kernel(const unsigned short* __restrict__ Zh, const unsigned short* __restrict__ Zl,
                 float* __restrict__ G)
{
    int g = blockIdx.x;
    __shared__ float Zs[32][68];
    int tid = threadIdx.x, tx = tid & 15, ty = tid >> 4;
    float acc[4][4] = {};
    for (int k0 = 0; k0 < ZD; k0 += 32) {
        for (int idx = tid; idx < 2048; idx += 256) {
            int i = idx >> 5, kk = idx & 31;
            size_t o = (size_t)(g * 64 + i) * ZD + k0 + kk;
            Zs[kk][i] = b2f(Zh[o]) + b2f(Zl[o]);
        }
        __syncthreads();
        #pragma unroll
        for (int kk = 0; kk < 32; ++kk) {
            float4 a = *(const float4*)&Zs[kk][ty * 4];
            float4 b = *(const float4*)&Zs[kk][tx * 4];
            float av[4] = {a.x, a.y, a.z, a.w};
            float bv[4] = {b.x, b.y, b.z, b.w};
            #pragma unroll
            for (int i = 0; i < 4; ++i)
                #pragma unroll
                for (int j = 0; j < 4; ++j)
                    acc[i][j] = fmaf(av[i], bv[j], acc[i][j]);
        }
        __syncthreads();
    }
    #pragma unroll
    for (int i = 0; i < 4; ++i)
        #pragma unroll
        for (int j = 0; j < 4; ++j)
            G[(size_t)(g * 64 + ty * 4 + i) * 64 + tx * 4 + j] = acc[i][j];
}

// ---------------- edge loss ----------------
__global__ void edge_loss(const int* __restrict__ e0, const int* __restrict__ e1,
                          const float* __restrict__ G, float* __restrict__ tot,
                          float* __restrict__ cnt, int negmode)
{
    __shared__ float lt[128];
    __shared__ float lc[128];
    int tid = threadIdx.x;
    if (tid < 128) { lt[tid] = 0.f; lc[tid] = 0.f; }
    __syncthreads();
    for (int e = blockIdx.x * blockDim.x + tid; e < NE; e += gridDim.x * blockDim.x) {
        int a = e0[e], b = e1[e];
        int g = a >> 6;
        float v = G[(size_t)((g << 6) + (a & 63)) * 64 + (b & 63)];
        float s = 1.f / (1.f + expf(-v));
        float p = negmode ? (1.f - s) : s;
        float l = -logf(1e-4f + p);
        atomicAdd(&lt[g], l);
        atomicAdd(&lc[g], 1.f);
    }
    __syncthreads();
    if (tid < 128) {
        atomicAdd(&tot[tid], lt[tid]);
        atomicAdd(&cnt[tid], lc[tid]);
    }
}

__global__ void lrc_final(const float* __restrict__ loss, float* __restrict__ out)
{
    int t = threadIdx.x;
    float v = loss[t] / fmaxf(loss[128 + t], 1.f) + loss[256 + t] / fmaxf(loss[384 + t], 1.f);
    __shared__ float red[128];
    red[t] = v;
    __syncthreads();
    for (int s = 64; s; s >>= 1) {
        if (t < s) red[t] += red[t + s];
        __syncthreads();
    }
    if (t == 0) out[0] = red[0] * (1.0f / 128.0f);
}

// ---------------- attention scores s1,s2 ----------------
__global__ void s12_kernel(const float* __restrict__ xh, const float* __restrict__ phi,
                           float* __restrict__ s1, float* __restrict__ s2)
{
    int idx = blockIdx.x * 256 + threadIdx.x;
    int n = idx >> 3, h = idx & 7;
    const float* xr = xh + (size_t)n * 512 + h * 64;
    const float* pa = phi + h * 128;
    const float* pb = pa + 64;
    float a = 0.f, b = 0.f;
    #pragma unroll
    for (int d = 0; d < 64; ++d) {
        float v = xr[d];
        a = fmaf(v, pa[d], a);
        b = fmaf(v, pb[d], b);
    }
    s1[idx] = a;
    s2[idx] = b;
}

// ---------------- attention aggregation ----------------
__global__ __launch_bounds__(256)
void attn_agg(const float* __restrict__ xh, const float* __restrict__ s1,
              const float* __restrict__ s2, float* __restrict__ agg)
{
    int g = blockIdx.x, h = blockIdx.y;
    __shared__ float Wt[64][68];
    __shared__ float Xs[64][68];
    __shared__ float s1s[64], s2s[64];
    int tid = threadIdx.x;
    if (tid < 64) {
        s1s[tid] = s1[(size_t)(g * 64 + tid) * 8 + h];
        s2s[tid] = s2[(size_t)(g * 64 + tid) * 8 + h];
    }
    __syncthreads();
    for (int idx = tid; idx < 4096; idx += 256) {
        int b = idx >> 6, i = idx & 63;
        float t = s1s[i] + s2s[b];
        t = t > 0.f ? t : 0.01f * t;
        Wt[b][i] = 1.f / (1.f + expf(-t));
    }
    for (int idx = tid; idx < 4096; idx += 256) {
        int b = idx >> 6, d = idx & 63;
        Xs[b][d] = xh[(size_t)(g * 64 + b) * 512 + h * 64 + d];
    }
    __syncthreads();
    int tx = tid & 15, ty = tid >> 4;
    float acc[4][4] = {};
    #pragma unroll
    for (int b = 0; b < 64; ++b) {
        float4 a = *(const float4*)&Wt[b][ty * 4];
        float4 x = *(const float4*)&Xs[b][tx * 4];
        float av[4] = {a.x, a.y, a.z, a.w};
        float xv[4] = {x.x, x.y, x.z, x.w};
        #pragma unroll
        for (int i = 0; i < 4; ++i)
            #pragma unroll
            for (int j = 0; j < 4; ++j)
                acc[i][j] = fmaf(av[i], xv[j], acc[i][j]);
    }
    #pragma unroll
    for (int i = 0; i < 4; ++i) {
        int node = g * 64 + ty * 4 + i;
        #pragma unroll
        for (int j = 0; j < 4; ++j)
            agg[(size_t)node * 512 + h * 64 + tx * 4 + j] = acc[i][j];
    }
}

// ---------------- classifier head ----------------
__global__ void head_kernel(const float* __restrict__ hid, const float* __restrict__ fc2W,
                            const float* __restrict__ fc2b, float* __restrict__ preds)
{
    int n = blockIdx.x * 256 + threadIdx.x;
    const float* hr = hid + (size_t)n * 64;
    float x[64];
    #pragma unroll
    for (int k = 0; k < 64; ++k) x[k] = hr[k];
    float lg[10];
    float mx = -1e30f;
    #pragma unroll
    for (int c = 0; c < 10; ++c) {
        float s = fc2b[c];
        #pragma unroll
        for (int k = 0; k < 64; ++k) s = fmaf(x[k], fc2W[k * 10 + c], s);
        lg[c] = s;
        mx = fmaxf(mx, s);
    }
    float sum = 0.f;
    #pragma unroll
    for (int c = 0; c < 10; ++c) {
        float t = expf(lg[c] - mx) + 1e-4f;
        lg[c] = t;
        sum += t;
    }
    float inv = 1.f / sum;
    #pragma unroll
    for (int c = 0; c < 10; ++c) preds[(size_t)n * 10 + c] = lg[c] * inv;
}

__global__ void yp_kernel(const float* __restrict__ preds, float* __restrict__ out)
{
    int g = blockIdx.x;
    int lane = threadIdx.x;
    float p[10];
    const float* pr = preds + (size_t)(g * 64 + lane) * 10;
    #pragma unroll
    for (int c = 0; c < 10; ++c) p[c] = pr[c];
    #pragma unroll
    for (int off = 32; off; off >>= 1)
        #pragma unroll
        for (int c = 0; c < 10; ++c) p[c] += __shfl_down(p[c], off);
    if (lane == 0)
        #pragma unroll
        for (int c = 0; c < 10; ++c) out[g * 10 + c] = logf(p[c] * (1.0f / 64.0f));
}

extern "C" void kernel_launch(void* const* d_in, const int* in_sizes, int n_in,
                              void* d_out, int out_size, void* d_ws, size_t ws_size,
                              hipStream_t stream)
{
    (void)in_sizes; (void)n_in; (void)out_size; (void)ws_size;
    const float* x     = (const float*)d_in[0];
    const int*   ei    = (const int*)d_in[1];
    const int*   nei   = (const int*)d_in[2];
    const float* fcW   = (const float*)d_in[5];
    const float* fcb   = (const float*)d_in[6];
    const float* bng   = (const float*)d_in[7];
    const float* bnb   = (const float*)d_in[8];
    const float* convW = (const float*)d_in[9];
    const float* convb = (const float*)d_in[10];
    const float* featW = (const float*)d_in[11];
    const float* phi   = (const float*)d_in[12];
    const float* fc1W  = (const float*)d_in[13];
    const float* fc1b  = (const float*)d_in[14];
    const float* fc2W  = (const float*)d_in[15];
    const float* fc2b  = (const float*)d_in[16];
    float* out = (float*)d_out;

    char* ws = (char*)d_ws;
    unsigned short* Zh      = (unsigned short*)(ws);              // 24 MB
    unsigned short* Zl      = (unsigned short*)(ws + 25165824);   // 24 MB
    unsigned short* H0h     = (unsigned short*)(ws + 50331648);   // 8 MB
    unsigned short* H0l     = (unsigned short*)(ws + 58720256);   // 8 MB
    float*          H2      = (float*)(ws + 67108864);            // 16 MB (conv out; AGG later)
    unsigned short* xbh     = (unsigned short*)(ws + 67108864);   // 2 MB (dead before H2 written)
    unsigned short* xbl     = (unsigned short*)(ws + 69206016);   // 2 MB
    unsigned short* fcWth   = (unsigned short*)(ws + 83886080);   // 128 KB
    unsigned short* fcWtl   = (unsigned short*)(ws + 84017152);   // 128 KB
    unsigned short* convWsh = (unsigned short*)(ws + 84148224);   // 512 KB (per-layer, reused)
    unsigned short* convWsl = (unsigned short*)(ws + 84672512);   // 512 KB
    unsigned short* featWth = (unsigned short*)(ws + 85196800);   // 1.5 MB
    unsigned short* featWtl = (unsigned short*)(ws + 86769664);   // 1.5 MB
    float*          Amat    = (float*)(ws + 88342528);            // 2 MB
    float*          Gram    = (float*)(ws + 90439680);            // 2 MB
    float*          DEG     = (float*)(ws + 92536832);
    float*          DINV    = (float*)(ws + 92569600);
    float*          BNS     = (float*)(ws + 92602368);            // sums,sqs,s,t (8 KB)
    float*          B2      = (float*)(ws + 92610560);            // bias2 (2 KB)
    float*          LOSS    = (float*)(ws + 92612608);            // 2 KB
    float*          S12     = (float*)(ws + 92614656);            // 512 KB
    float*          XH      = (float*)(ws + 50331648);            // reuse H0 region (16 MB)
    float*          HID     = (float*)(ws + 50331648);            // reuse after attn

    const int* src = ei;
    const int* dst = ei + NE;

    hipMemsetAsync(DEG, 0, NN * 4, stream);
    hipMemsetAsync(Amat, 0, (size_t)NG * 64 * 64 * 4, stream);
    hipMemsetAsync(LOSS, 0, 512 * 4, stream);

    deg_kernel<<<NE / 256, 256, 0, stream>>>(dst, DEG);
    deg_finish<<<NN / 256, 256, 0, stream>>>(DEG, DINV);
    build_adj<<<NE / 256, 256, 0, stream>>>(src, dst, DINV, Amat);
    adj_diag<<<NN / 256, 256, 0, stream>>>(DEG, Amat);

    // hi/lo conversions
    cvt_split<<<(NN * NF / 4) / 256, 256, 0, stream>>>(x, xbh, xbl);
    cvtT<<<dim3(CL / 32, NF / 32), dim3(32, 8), 0, stream>>>(fcW, fcWth, fcWtl, NF, CL);
    cvtT<<<dim3(CL / 32, ZD / 32), dim3(32, 8), 0, stream>>>(featW, featWth, featWtl, ZD, CL);

    // h0 = x @ fc_W + fc_b  (hi/lo MFMA, split output)
    gemm_hl<true, true><<<dim3(CL / 128, NN / 128), 256, 0, stream>>>(
        xbh, xbl, NF, fcWth, fcWtl, NF, nullptr, H0h, H0l, CL, fcb, NF);

    for (int i = 0; i < 3; ++i) {
        const unsigned short* Ah = (i == 0) ? H0h : (Zh + (size_t)(i - 1) * CL);
        const unsigned short* Al = (i == 0) ? H0l : (Zl + (size_t)(i - 1) * CL);
        int lda = (i == 0) ? CL : ZD;
        hipMemsetAsync(BNS, 0, 1024 * 4, stream);
        bn_stats_hl<<<dim3(2, 32), 256, 0, stream>>>(Ah, Al, lda, BNS, BNS + 512);
        bn_coef<<<1, 512, 0, stream>>>(BNS, BNS + 512, bng + i * CL, bnb + i * CL,
                                       BNS + 1024, BNS + 1536);
        // fold BN into conv weights: W' = diag(s) W (transposed, hi/lo), bias2 = t . W
        wscaleT<<<dim3(CL / 32, CL / 32), dim3(32, 8), 0, stream>>>(
            convW + (size_t)i * CL * CL, BNS + 1024, convWsh, convWsl, CL, CL);
        bias_dot<<<CL / 64, 64, 0, stream>>>(convW + (size_t)i * CL * CL, BNS + 1536, B2, CL, CL);
        // H2 = BN(h) @ W  (+ t.W)
        gemm_hl<true, false><<<dim3(CL / 128, NN / 128), 256, 0, stream>>>(
            Ah, Al, lda, convWsh, convWsl, CL, H2, nullptr, nullptr, CL, B2, CL);
        gcn_combine<<<dim3(NG, CL / 64), 256, 0, stream>>>(Amat, H2, convb + i * CL,
                                                           Zh + (size_t)i * CL,
                                                           Zl + (size_t)i * CL);
    }

    // edge reconstruction loss via per-graph Gram matrices
    gram_kernel<<<NG, 256, 0, stream>>>(Zh, Zl, Gram);
    edge_loss<<<128, 256, 0, stream>>>(ei, ei + NE, Gram, LOSS, LOSS + 128, 0);
    edge_loss<<<128, 256, 0, stream>>>(nei, nei + NE, Gram, LOSS + 256, LOSS + 384, 1);
    lrc_final<<<1, 128, 0, stream>>>(LOSS, out + 1280);

    // xh = z @ feat_W  (hi/lo MFMA, f32 out into old H0 region)
    gemm_hl<false, false><<<dim3(CL / 128, NN / 128), 256, 0, stream>>>(
        Zh, Zl, ZD, featWth, featWtl, ZD, XH, nullptr, nullptr, CL, nullptr, ZD);
    s12_kernel<<<(NN * 8) / 256, 256, 0, stream>>>(XH, phi, S12, S12 + NN * 8);
    attn_agg<<<dim3(NG, 8), 256, 0, stream>>>(XH, S12, S12 + NN * 8, H2);

    // hid = leaky_relu(agg @ fc1 + b)
    gemm_f32<2, true><<<dim3(1, NN / 64), 256, 0, stream>>>(
        H2, CL, fc1W, 64, HID, 64, fc1b, CL);
    head_kernel<<<NN / 256, 256, 0, stream>>>(HID, fc2W, fc2b, out + 1281);
    yp_kernel<<<NG, 64, 0, stream>>>(out + 1281, out);
}

// Round 4
// 641.752 us; speedup vs baseline: 1.5127x; 1.5127x over previous
//
#include <hip/hip_runtime.h>

#define NN 8192      // nodes
#define NG 128       // graphs
#define NF 128       // input feats
#define CL 512       // hidden dim
#define ZD 1536      // concat dim (3*512)
#define NE 262144    // edges per edge set

typedef __attribute__((ext_vector_type(8))) short short8;
typedef __attribute__((ext_vector_type(4))) float f32x4;

__device__ __forceinline__ unsigned short f2b(float f) {
    unsigned int u = __float_as_uint(f);
    unsigned int r = (u + 0x7fffu + ((u >> 16) & 1u)) >> 16;
    return (unsigned short)r;
}
__device__ __forceinline__ float b2f(unsigned short h) {
    return __uint_as_float(((unsigned int)h) << 16);
}

// ---------------- degree / dense adjacency ----------------
__global__ void deg_kernel(const int* __restrict__ dst, float* __restrict__ deg) {
    int e = blockIdx.x * 256 + threadIdx.x;
    atomicAdd(&deg[dst[e]], 1.0f);
}

__global__ void deg_finish(float* __restrict__ deg, float* __restrict__ dinv) {
    int n = blockIdx.x * 256 + threadIdx.x;
    float d = deg[n] + 1.0f;
    deg[n] = d;
    dinv[n] = rsqrtf(d);
}

__global__ void build_adj(const int* __restrict__ src, const int* __restrict__ dst,
                          const float* __restrict__ dinv, float* __restrict__ A) {
    int e = blockIdx.x * 256 + threadIdx.x;
    int s = src[e], d = dst[e];
    int g = d >> 6;
    atomicAdd(&A[(size_t)((g << 6) + (d & 63)) * 64 + (s & 63)], dinv[s] * dinv[d]);
}

__global__ void adj_diag(const float* __restrict__ deg, float* __restrict__ A) {
    int n = blockIdx.x * 256 + threadIdx.x;
    int g = n >> 6, i = n & 63;
    A[(size_t)(g * 64 + i) * 64 + i] += 1.0f / deg[n];
}

// ---------------- conversions (hi/lo split) ----------------
__global__ void cvt_split(const float* __restrict__ in,
                          unsigned short* __restrict__ oh, unsigned short* __restrict__ ol) {
    int i = blockIdx.x * 256 + threadIdx.x;
    float4 v = *(const float4*)(in + (size_t)i * 4);
    float vv[4] = {v.x, v.y, v.z, v.w};
    ushort4 h4, l4;
    unsigned short* hp = (unsigned short*)&h4;
    unsigned short* lp = (unsigned short*)&l4;
    #pragma unroll
    for (int j = 0; j < 4; ++j) {
        unsigned short h = f2b(vv[j]);
        hp[j] = h;
        lp[j] = f2b(vv[j] - b2f(h));
    }
    *(ushort4*)(oh + (size_t)i * 4) = h4;
    *(ushort4*)(ol + (size_t)i * 4) = l4;
}

// W: Kd x Nd row-major f32 -> Wt hi/lo: Nd x Kd row-major bf16
__global__ void cvtT(const float* __restrict__ W,
                     unsigned short* __restrict__ Wh, unsigned short* __restrict__ Wl,
                     int Kd, int Nd) {
    __shared__ float t[32][33];
    int kb = blockIdx.y * 32, nb = blockIdx.x * 32;
    int tx = threadIdx.x, ty = threadIdx.y;   // 32 x 8
    for (int i = ty; i < 32; i += 8)
        t[i][tx] = W[(size_t)(kb + i) * Nd + nb + tx];
    __syncthreads();
    for (int i = ty; i < 32; i += 8) {
        float v = t[tx][i];
        unsigned short h = f2b(v);
        Wh[(size_t)(nb + i) * Kd + kb + tx] = h;
        Wl[(size_t)(nb + i) * Kd + kb + tx] = f2b(v - b2f(h));
    }
}

// scaled transpose with inline BN coef: Wt[n][k] = W[k][n] * s[k], s = g*rsqrt(var+eps)
__global__ void wscaleT(const float* __restrict__ W,
                        const float* __restrict__ sums, const float* __restrict__ sqs,
                        const float* __restrict__ g,
                        unsigned short* __restrict__ Wh, unsigned short* __restrict__ Wl,
                        int Kd, int Nd) {
    __shared__ float t[32][33];
    int kb = blockIdx.y * 32, nb = blockIdx.x * 32;
    int tx = threadIdx.x, ty = threadIdx.y;
    for (int i = ty; i < 32; i += 8)
        t[i][tx] = W[(size_t)(kb + i) * Nd + nb + tx];
    __syncthreads();
    int kc = kb + tx;
    float m = sums[kc] * (1.0f / NN);
    float var = sqs[kc] * (1.0f / NN) - m * m;
    float sc = rsqrtf(var + 1e-5f) * g[kc];
    for (int i = ty; i < 32; i += 8) {
        float v = t[tx][i] * sc;
        unsigned short h = f2b(v);
        Wh[(size_t)(nb + i) * Kd + kb + tx] = h;
        Wl[(size_t)(nb + i) * Kd + kb + tx] = f2b(v - b2f(h));
    }
}

// bias2[n] = sum_k t[k]*W[k][n], t = b - m*s  (BN shift folded through conv weight)
__global__ void bias_dot(const float* __restrict__ W,
                         const float* __restrict__ sums, const float* __restrict__ sqs,
                         const float* __restrict__ g, const float* __restrict__ b,
                         float* __restrict__ bias2, int Kd, int Nd) {
    __shared__ float tl[512];
    int tid = threadIdx.x;   // 64
    for (int k = tid; k < Kd; k += 64) {
        float m = sums[k] * (1.0f / NN);
        float var = sqs[k] * (1.0f / NN) - m * m;
        float sc = rsqrtf(var + 1e-5f) * g[k];
        tl[k] = b[k] - m * sc;
    }
    __syncthreads();
    int n = blockIdx.x * 64 + tid;
    float acc = 0.f;
    for (int k = 0; k < Kd; ++k) acc = fmaf(tl[k], W[(size_t)k * Nd + n], acc);
    bias2[n] = acc;
}

// ---------------- bf16 hi/lo MFMA GEMM: C = A @ Bt^T, 128x64 tile ----------------
// A,B hi/lo bf16 (row-major MxK / NxK). 3-term product for ~f32 accuracy.
// grid (N/64, M/128), 256 threads (4 waves, 2x2: wave covers 64 rows x 32 cols).
// ACT: 0 none, 2 leaky. SPLIT: write hi/lo bf16 pair instead of f32.
template<int ACT, bool HASB, bool SPLIT>
__global__ __launch_bounds__(256)
void gemm_hl(const unsigned short* __restrict__ Ah, const unsigned short* __restrict__ Al, int lda,
             const unsigned short* __restrict__ Bh, const unsigned short* __restrict__ Bl, int ldb,
             float* __restrict__ Cf, unsigned short* __restrict__ Ch, unsigned short* __restrict__ Cl,
             int ldc, const float* __restrict__ bias, int K)
{
    __shared__ unsigned short AsH[4096], AsL[4096];   // [128][32]
    __shared__ unsigned short BsH[2048], BsL[2048];   // [64][32]
    const int tid = threadIdx.x;
    const int lane = tid & 63, wave = tid >> 6;
    const int wr = wave >> 1, wc = wave & 1;
    const int bm = blockIdx.y * 128, bn = blockIdx.x * 64;

    f32x4 acc[4][2];
    #pragma unroll
    for (int m = 0; m < 4; ++m)
        #pragma unroll
        for (int n = 0; n < 2; ++n)
            acc[m][n] = (f32x4){0.f, 0.f, 0.f, 0.f};

    const int lrow = lane >> 2;
    const int lkb  = (lane & 3) * 8;

    for (int k0 = 0; k0 < K; k0 += 32) {
        #pragma unroll
        for (int c = 0; c < 2; ++c) {
            int chunk = wave * 2 + c;              // 0..7
            int row = chunk * 16 + lrow;
            size_t offA = (size_t)(bm + row) * lda + k0 + lkb;
            __builtin_amdgcn_global_load_lds(
                (const __attribute__((address_space(1))) void*)(Ah + offA),
                (__attribute__((address_space(3))) void*)&AsH[chunk * 512], 16, 0, 0);
            __builtin_amdgcn_global_load_lds(
                (const __attribute__((address_space(1))) void*)(Al + offA),
                (__attribute__((address_space(3))) void*)&AsL[chunk * 512], 16, 0, 0);
        }
        {
            int rowb = wave * 16 + lrow;           // 0..63
            size_t offB = (size_t)(bn + rowb) * ldb + k0 + lkb;
            __builtin_amdgcn_global_load_lds(
                (const __attribute__((address_space(1))) void*)(Bh + offB),
                (__attribute__((address_space(3))) void*)&BsH[wave * 512], 16, 0, 0);
            __builtin_amdgcn_global_load_lds(
                (const __attribute__((address_space(1))) void*)(Bl + offB),
                (__attribute__((address_space(3))) void*)&BsL[wave * 512], 16, 0, 0);
        }
        __syncthreads();
        const int fl = lane & 15, kh = (lane >> 4) * 8;
        short8 ah[4], al[4], bh[2], bl[2];
        #pragma unroll
        for (int m = 0; m < 4; ++m) {
            int r = (wr * 64 + m * 16 + fl) * 32 + kh;
            ah[m] = *(const short8*)&AsH[r];
            al[m] = *(const short8*)&AsL[r];
        }
        #pragma unroll
        for (int n = 0; n < 2; ++n) {
            int r = (wc * 32 + n * 16 + fl) * 32 + kh;
            bh[n] = *(const short8*)&BsH[r];
            bl[n] = *(const short8*)&BsL[r];
        }
        #pragma unroll
        for (int m = 0; m < 4; ++m)
            #pragma unroll
            for (int n = 0; n < 2; ++n) {
                acc[m][n] = __builtin_amdgcn_mfma_f32_16x16x32_bf16(ah[m], bh[n], acc[m][n], 0, 0, 0);
                acc[m][n] = __builtin_amdgcn_mfma_f32_16x16x32_bf16(ah[m], bl[n], acc[m][n], 0, 0, 0);
                acc[m][n] = __builtin_amdgcn_mfma_f32_16x16x32_bf16(al[m], bh[n], acc[m][n], 0, 0, 0);
            }
        __syncthreads();
    }
    const int orow0 = (lane >> 4) * 4;
    const int ocol  = lane & 15;
    #pragma unroll
    for (int m = 0; m < 4; ++m) {
        #pragma unroll
        for (int n = 0; n < 2; ++n) {
            int col = bn + wc * 32 + n * 16 + ocol;
            float bb = HASB ? bias[col] : 0.f;
            #pragma unroll
            for (int r = 0; r < 4; ++r) {
                int rowg = bm + wr * 64 + m * 16 + orow0 + r;
                float v = acc[m][n][r] + bb;
                if (ACT == 2) v = v > 0.f ? v : 0.01f * v;
                if (SPLIT) {
                    unsigned short h = f2b(v);
                    Ch[(size_t)rowg * ldc + col] = h;
                    Cl[(size_t)rowg * ldc + col] = f2b(v - b2f(h));
                } else {
                    Cf[(size_t)rowg * ldc + col] = v;
                }
            }
        }
    }
}

// ---------------- batch norm stats (reads hi/lo pair), grid (2, 128) ----------------
__global__ void bn_stats_hl(const unsigned short* __restrict__ Hh,
                            const unsigned short* __restrict__ Hl, int ldh,
                            float* __restrict__ sums, float* __restrict__ sqs)
{
    int c = blockIdx.x * 256 + threadIdx.x;
    int r0 = blockIdx.y * 64;
    float s = 0.f, q = 0.f;
    for (int r = r0; r < r0 + 64; ++r) {
        size_t idx = (size_t)r * ldh + c;
        float v = b2f(Hh[idx]) + b2f(Hl[idx]);
        s += v;
        q = fmaf(v, v, q);
    }
    atomicAdd(&sums[c], s);
    atomicAdd(&sqs[c], q);
}

// ---------------- GCN combine: Z = relu(A_g @ H2_g + b), hi/lo bf16 out ----------------
__global__ __launch_bounds__(256)
void gcn_combine(const float* __restrict__ A, const float* __restrict__ H2,
                 const float* __restrict__ bias,
                 unsigned short* __restrict__ outh, unsigned short* __restrict__ outl)
{
    int g = blockIdx.x, ct = blockIdx.y;
    __shared__ float At[64][68];
    __shared__ float Hs[64][68];
    int tid = threadIdx.x;
    const float* Ag = A + (size_t)g * 4096;
    for (int idx = tid; idx < 4096; idx += 256) {
        int i = idx >> 6, k = idx & 63;
        At[k][i] = Ag[idx];
    }
    for (int idx = tid; idx < 4096; idx += 256) {
        int k = idx >> 6, c = idx & 63;
        Hs[k][c] = H2[(size_t)(g * 64 + k) * CL + ct * 64 + c];
    }
    __syncthreads();
    int tx = tid & 15, ty = tid >> 4;
    float acc[4][4] = {};
    #pragma unroll
    for (int k = 0; k < 64; ++k) {
        float4 a = *(const float4*)&At[k][ty * 4];
        float4 b = *(const float4*)&Hs[k][tx * 4];
        float av[4] = {a.x, a.y, a.z, a.w};
        float bv[4] = {b.x, b.y, b.z, b.w};
        #pragma unroll
        for (int i = 0; i < 4; ++i)
            #pragma unroll
            for (int j = 0; j < 4; ++j)
                acc[i][j] = fmaf(av[i], bv[j], acc[i][j]);
    }
    #pragma unroll
    for (int i = 0; i < 4; ++i) {
        int node = g * 64 + ty * 4 + i;
        #pragma unroll
        for (int j = 0; j < 4; ++j) {
            int c = ct * 64 + tx * 4 + j;
            float v = acc[i][j] + bias[c];
            v = v > 0.f ? v : 0.f;
            unsigned short h = f2b(v);
            outh[(size_t)node * ZD + c] = h;
            outl[(size_t)node * ZD + c] = f2b(v - b2f(h));
        }
    }
}

// ---------------- per-graph Gram matrix G = Z_g Z_g^T via MFMA hi/lo ----------------
// 1 block per graph, 4 waves; wave w computes rows 16w..16w+15 x all 64 cols.
__global__ __launch_bounds__(256)
void gram_mfma(const unsigned short* __restrict__ Zh, const unsigned short* __restrict__ Zl,
               float* __restrict__ G)
{
    __shared__ unsigned short ZsH[2048], ZsL[2048];   // [64][32]
    const int g = blockIdx.x;
    const int tid = threadIdx.x;
    const int lane = tid & 63, wave = tid >> 6;
    const int lrow = lane >> 2, lkb = (lane & 3) * 8;

    f32x4 acc[4];
    #pragma unroll
    for (int n = 0; n < 4; ++n) acc[n] = (f32x4){0.f, 0.f, 0.f, 0.f};

    for (int k0 = 0; k0 < ZD; k0 += 32) {
        int row = wave * 16 + lrow;
        size_t off = (size_t)(g * 64 + row) * ZD + k0 + lkb;
        __builtin_amdgcn_global_load_lds(
            (const __attribute__((address_space(1))) void*)(Zh + off),
            (__attribute__((address_space(3))) void*)&ZsH[wave * 512], 16, 0, 0);
        __builtin_amdgcn_global_load_lds(
            (const __attribute__((address_space(1))) void*)(Zl + off),
            (__attribute__((address_space(3))) void*)&ZsL[wave * 512], 16, 0, 0);
        __syncthreads();
        const int fl = lane & 15, kh = (lane >> 4) * 8;
        int ra = (wave * 16 + fl) * 32 + kh;
        short8 ah = *(const short8*)&ZsH[ra];
        short8 al = *(const short8*)&ZsL[ra];
        #pragma unroll
        for (int n = 0; n < 4; ++n) {
            int rb = (n * 16 + fl) * 32 + kh;
            short8 bh = *(const short8*)&ZsH[rb];
            short8 bl = *(const short8*)&ZsL[rb];
            acc[n] = __builtin_amdgcn_mfma_f32_16x16x32_bf16(ah, bh, acc[n], 0, 0, 0);
            acc[n] = __builtin_amdgcn_mfma_f32_16x16x32_bf16(ah, bl, acc[n], 0, 0, 0);
            acc[n] = __builtin_amdgcn_mfma_f32_16x16x32_bf16(al, bh, acc[n], 0, 0, 0);
        }
        __syncthreads();
    }
    const int orow0 = (lane >> 4) * 4;
    const int ocol  = lane & 15;
    #pragma unroll
    for (int n = 0; n < 4; ++n)
        #pragma unroll
        for (int r = 0; r < 4; ++r)
            G[(size_t)(g * 64 + wave * 16 + orow0 + r) * 64 + n * 16 + ocol] = acc[n][r];
}

// ---------------- edge loss ----------------
__global__ void edge_loss(const int* __restrict__ e0, const int* __restrict__ e1,
                          const float* __restrict__ G, float* __restrict__ tot,
                          float* __restrict__ cnt, int negmode)
{
    __shared__ float lt[128];
    __shared__ float lc[128];
    int tid = threadIdx.x;
    if (tid < 128) { lt[tid] = 0.f; lc[tid] = 0.f; }
    __syncthreads();
    for (int e = blockIdx.x * blockDim.x + tid; e < NE; e += gridDim.x * blockDim.x) {
        int a = e0[e], b = e1[e];
        int g = a >> 6;
        float v = G[(size_t)((g << 6) + (a & 63)) * 64 + (b & 63)];
        float s = 1.f / (1.f + expf(-v));
        float p = negmode ? (1.f - s) : s;
        float l = -logf(1e-4f + p);
        atomicAdd(&lt[g], l);
        atomicAdd(&lc[g], 1.f);
    }
    __syncthreads();
    if (tid < 128) {
        atomicAdd(&tot[tid], lt[tid]);
        atomicAdd(&cnt[tid], lc[tid]);
    }
}

__global__ void lrc_final(const float* __restrict__ loss, float* __restrict__ out)
{
    int t = threadIdx.x;
    float v = loss[t] / fmaxf(loss[128 + t], 1.f) + loss[256 + t] / fmaxf(loss[384 + t], 1.f);
    __shared__ float red[128];
    red[t] = v;
    __syncthreads();
    for (int s = 64; s; s >>= 1) {
        if (t < s) red[t] += red[t + s];
        __syncthreads();
    }
    if (t == 0) out[0] = red[0] * (1.0f / 128.0f);
}

// ---------------- attention scores s1,s2 ----------------
__global__ void s12_kernel(const float* __restrict__ xh, const float* __restrict__ phi,
                           float* __restrict__ s1, float* __restrict__ s2)
{
    int idx = blockIdx.x * 256 + threadIdx.x;
    int n = idx >> 3, h = idx & 7;
    const float4* xr = (const float4*)(xh + (size_t)n * 512 + h * 64);
    const float4* pa = (const float4*)(phi + h * 128);
    const float4* pb = (const float4*)(phi + h * 128 + 64);
    float a = 0.f, b = 0.f;
    #pragma unroll
    for (int d = 0; d < 16; ++d) {
        float4 v = xr[d], A4 = pa[d], B4 = pb[d];
        a = fmaf(v.x, A4.x, a); a = fmaf(v.y, A4.y, a);
        a = fmaf(v.z, A4.z, a); a = fmaf(v.w, A4.w, a);
        b = fmaf(v.x, B4.x, b); b = fmaf(v.y, B4.y, b);
        b = fmaf(v.z, B4.z, b); b = fmaf(v.w, B4.w, b);
    }
    s1[idx] = a;
    s2[idx] = b;
}

// ---------------- attention aggregation (hi/lo bf16 out) ----------------
__global__ __launch_bounds__(256)
void attn_agg(const float* __restrict__ xh, const float* __restrict__ s1,
              const float* __restrict__ s2,
              unsigned short* __restrict__ aggh, unsigned short* __restrict__ aggl)
{
    int g = blockIdx.x, h = blockIdx.y;
    __shared__ float Wt[64][68];
    __shared__ float Xs[64][68];
    __shared__ float s1s[64], s2s[64];
    int tid = threadIdx.x;
    if (tid < 64) {
        s1s[tid] = s1[(size_t)(g * 64 + tid) * 8 + h];
        s2s[tid] = s2[(size_t)(g * 64 + tid) * 8 + h];
    }
    __syncthreads();
    for (int idx = tid; idx < 4096; idx += 256) {
        int b = idx >> 6, i = idx & 63;
        float t = s1s[i] + s2s[b];
        t = t > 0.f ? t : 0.01f * t;
        Wt[b][i] = 1.f / (1.f + expf(-t));
    }
    for (int idx = tid; idx < 4096; idx += 256) {
        int b = idx >> 6, d = idx & 63;
        Xs[b][d] = xh[(size_t)(g * 64 + b) * 512 + h * 64 + d];
    }
    __syncthreads();
    int tx = tid & 15, ty = tid >> 4;
    float acc[4][4] = {};
    #pragma unroll
    for (int b = 0; b < 64; ++b) {
        float4 a = *(const float4*)&Wt[b][ty * 4];
        float4 x = *(const float4*)&Xs[b][tx * 4];
        float av[4] = {a.x, a.y, a.z, a.w};
        float xv[4] = {x.x, x.y, x.z, x.w};
        #pragma unroll
        for (int i = 0; i < 4; ++i)
            #pragma unroll
            for (int j = 0; j < 4; ++j)
                acc[i][j] = fmaf(av[i], xv[j], acc[i][j]);
    }
    #pragma unroll
    for (int i = 0; i < 4; ++i) {
        int node = g * 64 + ty * 4 + i;
        #pragma unroll
        for (int j = 0; j < 4; ++j) {
            size_t o = (size_t)node * 512 + h * 64 + tx * 4 + j;
            float v = acc[i][j];
            unsigned short hh = f2b(v);
            aggh[o] = hh;
            aggl[o] = f2b(v - b2f(hh));
        }
    }
}

// ---------------- classifier head ----------------
__global__ void head_kernel(const float* __restrict__ hid, const float* __restrict__ fc2W,
                            const float* __restrict__ fc2b, float* __restrict__ preds)
{
    int n = blockIdx.x * 256 + threadIdx.x;
    const float* hr = hid + (size_t)n * 64;
    float x[64];
    #pragma unroll
    for (int k = 0; k < 64; ++k) x[k] = hr[k];
    float lg[10];
    float mx = -1e30f;
    #pragma unroll
    for (int c = 0; c < 10; ++c) {
        float s = fc2b[c];
        #pragma unroll
        for (int k = 0; k < 64; ++k) s = fmaf(x[k], fc2W[k * 10 + c], s);
        lg[c] = s;
        mx = fmaxf(mx, s);
    }
    float sum = 0.f;
    #pragma unroll
    for (int c = 0; c < 10; ++c) {
        float t = expf(lg[c] - mx) + 1e-4f;
        lg[c] = t;
        sum += t;
    }
    float inv = 1.f / sum;
    #pragma unroll
    for (int c = 0; c < 10; ++c) preds[(size_t)n * 10 + c] = lg[c] * inv;
}

__global__ void yp_kernel(const float* __restrict__ preds, float* __restrict__ out)
{
    int g = blockIdx.x;
    int lane = threadIdx.x;
    float p[10];
    const float* pr = preds + (size_t)(g * 64 + lane) * 10;
    #pragma unroll
    for (int c = 0; c < 10; ++c) p[c] = pr[c];
    #pragma unroll
    for (int off = 32; off; off >>= 1)
        #pragma unroll
        for (int c = 0; c < 10; ++c) p[c] += __shfl_down(p[c], off);
    if (lane == 0)
        #pragma unroll
        for (int c = 0; c < 10; ++c) out[g * 10 + c] = logf(p[c] * (1.0f / 64.0f));
}

extern "C" void kernel_launch(void* const* d_in, const int* in_sizes, int n_in,
                              void* d_out, int out_size, void* d_ws, size_t ws_size,
                              hipStream_t stream)
{
    (void)in_sizes; (void)n_in; (void)out_size; (void)ws_size;
    const float* x     = (const float*)d_in[0];
    const int*   ei    = (const int*)d_in[1];
    const int*   nei   = (const int*)d_in[2];
    const float* fcW   = (const float*)d_in[5];
    const float* fcb   = (const float*)d_in[6];
    const float* bng   = (const float*)d_in[7];
    const float* bnb   = (const float*)d_in[8];
    const float* convW = (const float*)d_in[9];
    const float* convb = (const float*)d_in[10];
    const float* featW = (const float*)d_in[11];
    const float* phi   = (const float*)d_in[12];
    const float* fc1W  = (const float*)d_in[13];
    const float* fc1b  = (const float*)d_in[14];
    const float* fc2W  = (const float*)d_in[15];
    const float* fc2b  = (const float*)d_in[16];
    float* out = (float*)d_out;

    char* ws = (char*)d_ws;
    unsigned short* Zh      = (unsigned short*)(ws);              // 24 MB
    unsigned short* Zl      = (unsigned short*)(ws + 25165824);   // 24 MB -> 50331648
    unsigned short* H0h     = (unsigned short*)(ws + 50331648);   // 8 MB
    unsigned short* H0l     = (unsigned short*)(ws + 58720256);   // 8 MB -> 67108864
    float*          H2      = (float*)(ws + 67108864);            // 16 MB -> 83886080
    unsigned short* xbh     = (unsigned short*)(ws + 67108864);   // 2 MB (dead before H2)
    unsigned short* xbl     = (unsigned short*)(ws + 69206016);   // 2 MB
    unsigned short* AGGh    = (unsigned short*)(ws + 67108864);   // 8 MB (after conv loop)
    unsigned short* AGGl    = (unsigned short*)(ws + 75497472);   // 8 MB
    unsigned short* fcWth   = (unsigned short*)(ws + 83886080);   // 128 KB
    unsigned short* fcWtl   = (unsigned short*)(ws + 84017152);   // 128 KB
    unsigned short* convWsh = (unsigned short*)(ws + 84148224);   // 512 KB (per-layer)
    unsigned short* convWsl = (unsigned short*)(ws + 84672512);   // 512 KB
    unsigned short* featWth = (unsigned short*)(ws + 85196800);   // 1.5 MB
    unsigned short* featWtl = (unsigned short*)(ws + 86769664);   // 1.5 MB -> 88342528
    unsigned short* fc1Wth  = (unsigned short*)(ws + 88342528);   // 64 KB
    unsigned short* fc1Wtl  = (unsigned short*)(ws + 88408064);   // 64 KB -> 88473600
    float*          Gram    = (float*)(ws + 88473600);            // 2 MB -> 90570752
    float*          DINV    = (float*)(ws + 90570752);            // 32 KB -> 90603520
    float*          S12     = (float*)(ws + 90603520);            // 512 KB -> 91127808
    // zeroed region (single memset): DEG + Amat + LOSS + BNS3
    float*          DEG     = (float*)(ws + 91127808);            // 32 KB
    float*          Amat    = (float*)(ws + 91160576);            // 2 MB
    float*          LOSS    = (float*)(ws + 93257728);            // 2 KB
    float*          BNS3    = (float*)(ws + 93259776);            // 12 KB -> 93272064
    float*          B2      = (float*)(ws + 93272064);            // 2 KB
    float*          XH      = (float*)(ws + 50331648);            // reuse H0 (16 MB)
    float*          HID     = (float*)(ws + 50331648);            // reuse after attn

    const int* src = ei;
    const int* dst = ei + NE;

    hipMemsetAsync(DEG, 0, 93272064 - 91127808, stream);

    deg_kernel<<<NE / 256, 256, 0, stream>>>(dst, DEG);
    deg_finish<<<NN / 256, 256, 0, stream>>>(DEG, DINV);
    build_adj<<<NE / 256, 256, 0, stream>>>(src, dst, DINV, Amat);
    adj_diag<<<NN / 256, 256, 0, stream>>>(DEG, Amat);

    // hi/lo conversions
    cvt_split<<<(NN * NF / 4) / 256, 256, 0, stream>>>(x, xbh, xbl);
    cvtT<<<dim3(CL / 32, NF / 32), dim3(32, 8), 0, stream>>>(fcW, fcWth, fcWtl, NF, CL);
    cvtT<<<dim3(CL / 32, ZD / 32), dim3(32, 8), 0, stream>>>(featW, featWth, featWtl, ZD, CL);
    cvtT<<<dim3(2, 16), dim3(32, 8), 0, stream>>>(fc1W, fc1Wth, fc1Wtl, 512, 64);

    // h0 = x @ fc_W + fc_b  (hi/lo MFMA, split output)
    gemm_hl<0, true, true><<<dim3(CL / 64, NN / 128), 256, 0, stream>>>(
        xbh, xbl, NF, fcWth, fcWtl, NF, nullptr, H0h, H0l, CL, fcb, NF);

    for (int i = 0; i < 3; ++i) {
        const unsigned short* Ah = (i == 0) ? H0h : (Zh + (size_t)(i - 1) * CL);
        const unsigned short* Al = (i == 0) ? H0l : (Zl + (size_t)(i - 1) * CL);
        int lda = (i == 0) ? CL : ZD;
        float* sums = BNS3 + i * 1024;
        float* sqs  = sums + 512;
        bn_stats_hl<<<dim3(2, 128), 256, 0, stream>>>(Ah, Al, lda, sums, sqs);
        wscaleT<<<dim3(CL / 32, CL / 32), dim3(32, 8), 0, stream>>>(
            convW + (size_t)i * CL * CL, sums, sqs, bng + i * CL, convWsh, convWsl, CL, CL);
        bias_dot<<<CL / 64, 64, 0, stream>>>(convW + (size_t)i * CL * CL, sums, sqs,
                                             bng + i * CL, bnb + i * CL, B2, CL, CL);
        gemm_hl<0, true, false><<<dim3(CL / 64, NN / 128), 256, 0, stream>>>(
            Ah, Al, lda, convWsh, convWsl, CL, H2, nullptr, nullptr, CL, B2, CL);
        gcn_combine<<<dim3(NG, CL / 64), 256, 0, stream>>>(Amat, H2, convb + i * CL,
                                                           Zh + (size_t)i * CL,
                                                           Zl + (size_t)i * CL);
    }

    // edge reconstruction loss via per-graph Gram matrices (MFMA)
    gram_mfma<<<NG, 256, 0, stream>>>(Zh, Zl, Gram);
    edge_loss<<<128, 256, 0, stream>>>(ei, ei + NE, Gram, LOSS, LOSS + 128, 0);
    edge_loss<<<128, 256, 0, stream>>>(nei, nei + NE, Gram, LOSS + 256, LOSS + 384, 1);
    lrc_final<<<1, 128, 0, stream>>>(LOSS, out + 1280);

    // xh = z @ feat_W  (hi/lo MFMA, f32 out into old H0 region)
    gemm_hl<0, false, false><<<dim3(CL / 64, NN / 128), 256, 0, stream>>>(
        Zh, Zl, ZD, featWth, featWtl, ZD, XH, nullptr, nullptr, CL, nullptr, ZD);
    s12_kernel<<<(NN * 8) / 256, 256, 0, stream>>>(XH, phi, S12, S12 + NN * 8);
    attn_agg<<<dim3(NG, 8), 256, 0, stream>>>(XH, S12, S12 + NN * 8, AGGh, AGGl);

    // hid = leaky_relu(agg @ fc1 + b)  (hi/lo MFMA)
    gemm_hl<2, true, false><<<dim3(1, NN / 128), 256, 0, stream>>>(
        AGGh, AGGl, CL, fc1Wth, fc1Wtl, CL, HID, nullptr, nullptr, 64, fc1b, CL);
    head_kernel<<<NN / 256, 256, 0, stream>>>(HID, fc2W, fc2b, out + 1281);
    yp_kernel<<<NG, 64, 0, stream>>>(out + 1281, out);
}

// Round 5
// 471.089 us; speedup vs baseline: 2.0607x; 1.3623x over previous
//
#include <hip/hip_runtime.h>

#define NN 8192      // nodes
#define NG 128       // graphs
#define NF 128       // input feats
#define CL 512       // hidden dim
#define ZD 1536      // concat dim (3*512)
#define NE 262144    // edges per edge set

typedef __attribute__((ext_vector_type(8))) short short8;
typedef __attribute__((ext_vector_type(8))) unsigned short u16x8;
typedef __attribute__((ext_vector_type(4))) float f32x4;

__device__ __forceinline__ unsigned short f2b(float f) {
    unsigned int u = __float_as_uint(f);
    unsigned int r = (u + 0x7fffu + ((u >> 16) & 1u)) >> 16;
    return (unsigned short)r;
}
__device__ __forceinline__ float b2f(unsigned short h) {
    return __uint_as_float(((unsigned int)h) << 16);
}

// ---------------- degree / dense adjacency ----------------
__global__ void deg_kernel(const int* __restrict__ dst, float* __restrict__ deg) {
    int e = blockIdx.x * 256 + threadIdx.x;
    atomicAdd(&deg[dst[e]], 1.0f);
}

__global__ void deg_finish(float* __restrict__ deg, float* __restrict__ dinv) {
    int n = blockIdx.x * 256 + threadIdx.x;
    float d = deg[n] + 1.0f;
    deg[n] = d;
    dinv[n] = rsqrtf(d);
}

__global__ void build_adj(const int* __restrict__ src, const int* __restrict__ dst,
                          const float* __restrict__ dinv, float* __restrict__ A) {
    int e = blockIdx.x * 256 + threadIdx.x;
    int s = src[e], d = dst[e];
    int g = d >> 6;
    atomicAdd(&A[(size_t)((g << 6) + (d & 63)) * 64 + (s & 63)], dinv[s] * dinv[d]);
}

__global__ void adj_diag(const float* __restrict__ deg, float* __restrict__ A) {
    int n = blockIdx.x * 256 + threadIdx.x;
    int g = n >> 6, i = n & 63;
    A[(size_t)(g * 64 + i) * 64 + i] += 1.0f / deg[n];
}

// ---------------- conversions (hi/lo split) ----------------
__global__ void cvt_split(const float* __restrict__ in,
                          unsigned short* __restrict__ oh, unsigned short* __restrict__ ol) {
    int i = blockIdx.x * 256 + threadIdx.x;
    float4 v = *(const float4*)(in + (size_t)i * 4);
    float vv[4] = {v.x, v.y, v.z, v.w};
    ushort4 h4, l4;
    unsigned short* hp = (unsigned short*)&h4;
    unsigned short* lp = (unsigned short*)&l4;
    #pragma unroll
    for (int j = 0; j < 4; ++j) {
        unsigned short h = f2b(vv[j]);
        hp[j] = h;
        lp[j] = f2b(vv[j] - b2f(h));
    }
    *(ushort4*)(oh + (size_t)i * 4) = h4;
    *(ushort4*)(ol + (size_t)i * 4) = l4;
}

// W: Kd x Nd row-major f32 -> Wt hi/lo: Nd x Kd row-major bf16
__global__ void cvtT(const float* __restrict__ W,
                     unsigned short* __restrict__ Wh, unsigned short* __restrict__ Wl,
                     int Kd, int Nd) {
    __shared__ float t[32][33];
    int kb = blockIdx.y * 32, nb = blockIdx.x * 32;
    int tx = threadIdx.x, ty = threadIdx.y;   // 32 x 8
    for (int i = ty; i < 32; i += 8)
        t[i][tx] = W[(size_t)(kb + i) * Nd + nb + tx];
    __syncthreads();
    for (int i = ty; i < 32; i += 8) {
        float v = t[tx][i];
        unsigned short h = f2b(v);
        Wh[(size_t)(nb + i) * Kd + kb + tx] = h;
        Wl[(size_t)(nb + i) * Kd + kb + tx] = f2b(v - b2f(h));
    }
}

// scaled transpose with inline BN coef: Wt[n][k] = W[k][n] * s[k], s = g*rsqrt(var+eps)
__global__ void wscaleT(const float* __restrict__ W,
                        const float* __restrict__ sums, const float* __restrict__ sqs,
                        const float* __restrict__ g,
                        unsigned short* __restrict__ Wh, unsigned short* __restrict__ Wl,
                        int Kd, int Nd) {
    __shared__ float t[32][33];
    int kb = blockIdx.y * 32, nb = blockIdx.x * 32;
    int tx = threadIdx.x, ty = threadIdx.y;
    for (int i = ty; i < 32; i += 8)
        t[i][tx] = W[(size_t)(kb + i) * Nd + nb + tx];
    __syncthreads();
    int kc = kb + tx;
    float m = sums[kc] * (1.0f / NN);
    float var = sqs[kc] * (1.0f / NN) - m * m;
    float sc = rsqrtf(var + 1e-5f) * g[kc];
    for (int i = ty; i < 32; i += 8) {
        float v = t[tx][i] * sc;
        unsigned short h = f2b(v);
        Wh[(size_t)(nb + i) * Kd + kb + tx] = h;
        Wl[(size_t)(nb + i) * Kd + kb + tx] = f2b(v - b2f(h));
    }
}

// bias2[n] = sum_k t[k]*W[k][n], t = b - m*s. grid (Nd/64), 256 thr, 4-way k-split.
__global__ void bias_dot(const float* __restrict__ W,
                         const float* __restrict__ sums, const float* __restrict__ sqs,
                         const float* __restrict__ g, const float* __restrict__ b,
                         float* __restrict__ bias2, int Kd, int Nd) {
    __shared__ float red[256];
    int n = blockIdx.x * 64 + (threadIdx.x & 63);
    int kp = threadIdx.x >> 6;
    float acc = 0.f;
    for (int k = kp; k < Kd; k += 4) {
        float m = sums[k] * (1.0f / NN);
        float var = sqs[k] * (1.0f / NN) - m * m;
        float sc = rsqrtf(var + 1e-5f) * g[k];
        float tk = b[k] - m * sc;
        acc = fmaf(tk, W[(size_t)k * Nd + n], acc);
    }
    red[threadIdx.x] = acc;
    __syncthreads();
    if (threadIdx.x < 64)
        bias2[n] = red[threadIdx.x] + red[threadIdx.x + 64] +
                   red[threadIdx.x + 128] + red[threadIdx.x + 192];
}

// ---------------- bf16 hi/lo MFMA GEMM: C = A @ Bt^T, 128x64 tile ----------------
template<int ACT, bool HASB, bool SPLIT>
__global__ __launch_bounds__(256)
void gemm_hl(const unsigned short* __restrict__ Ah, const unsigned short* __restrict__ Al, int lda,
             const unsigned short* __restrict__ Bh, const unsigned short* __restrict__ Bl, int ldb,
             float* __restrict__ Cf, unsigned short* __restrict__ Ch, unsigned short* __restrict__ Cl,
             int ldc, const float* __restrict__ bias, int K)
{
    __shared__ unsigned short AsH[4096], AsL[4096];   // [128][32]
    __shared__ unsigned short BsH[2048], BsL[2048];   // [64][32]
    const int tid = threadIdx.x;
    const int lane = tid & 63, wave = tid >> 6;
    const int wr = wave >> 1, wc = wave & 1;
    const int bm = blockIdx.y * 128, bn = blockIdx.x * 64;

    f32x4 acc[4][2];
    #pragma unroll
    for (int m = 0; m < 4; ++m)
        #pragma unroll
        for (int n = 0; n < 2; ++n)
            acc[m][n] = (f32x4){0.f, 0.f, 0.f, 0.f};

    const int lrow = lane >> 2;
    const int lkb  = (lane & 3) * 8;

    for (int k0 = 0; k0 < K; k0 += 32) {
        #pragma unroll
        for (int c = 0; c < 2; ++c) {
            int chunk = wave * 2 + c;
            int row = chunk * 16 + lrow;
            size_t offA = (size_t)(bm + row) * lda + k0 + lkb;
            __builtin_amdgcn_global_load_lds(
                (const __attribute__((address_space(1))) void*)(Ah + offA),
                (__attribute__((address_space(3))) void*)&AsH[chunk * 512], 16, 0, 0);
            __builtin_amdgcn_global_load_lds(
                (const __attribute__((address_space(1))) void*)(Al + offA),
                (__attribute__((address_space(3))) void*)&AsL[chunk * 512], 16, 0, 0);
        }
        {
            int rowb = wave * 16 + lrow;
            size_t offB = (size_t)(bn + rowb) * ldb + k0 + lkb;
            __builtin_amdgcn_global_load_lds(
                (const __attribute__((address_space(1))) void*)(Bh + offB),
                (__attribute__((address_space(3))) void*)&BsH[wave * 512], 16, 0, 0);
            __builtin_amdgcn_global_load_lds(
                (const __attribute__((address_space(1))) void*)(Bl + offB),
                (__attribute__((address_space(3))) void*)&BsL[wave * 512], 16, 0, 0);
        }
        __syncthreads();
        const int fl = lane & 15, kh = (lane >> 4) * 8;
        short8 ah[4], al[4], bh[2], bl[2];
        #pragma unroll
        for (int m = 0; m < 4; ++m) {
            int r = (wr * 64 + m * 16 + fl) * 32 + kh;
            ah[m] = *(const short8*)&AsH[r];
            al[m] = *(const short8*)&AsL[r];
        }
        #pragma unroll
        for (int n = 0; n < 2; ++n) {
            int r = (wc * 32 + n * 16 + fl) * 32 + kh;
            bh[n] = *(const short8*)&BsH[r];
            bl[n] = *(const short8*)&BsL[r];
        }
        #pragma unroll
        for (int m = 0; m < 4; ++m)
            #pragma unroll
            for (int n = 0; n < 2; ++n) {
                acc[m][n] = __builtin_amdgcn_mfma_f32_16x16x32_bf16(ah[m], bh[n], acc[m][n], 0, 0, 0);
                acc[m][n] = __builtin_amdgcn_mfma_f32_16x16x32_bf16(ah[m], bl[n], acc[m][n], 0, 0, 0);
                acc[m][n] = __builtin_amdgcn_mfma_f32_16x16x32_bf16(al[m], bh[n], acc[m][n], 0, 0, 0);
            }
        __syncthreads();
    }
    const int orow0 = (lane >> 4) * 4;
    const int ocol  = lane & 15;
    #pragma unroll
    for (int m = 0; m < 4; ++m) {
        #pragma unroll
        for (int n = 0; n < 2; ++n) {
            int col = bn + wc * 32 + n * 16 + ocol;
            float bb = HASB ? bias[col] : 0.f;
            #pragma unroll
            for (int r = 0; r < 4; ++r) {
                int rowg = bm + wr * 64 + m * 16 + orow0 + r;
                float v = acc[m][n][r] + bb;
                if (ACT == 2) v = v > 0.f ? v : 0.01f * v;
                if (SPLIT) {
                    unsigned short h = f2b(v);
                    Ch[(size_t)rowg * ldc + col] = h;
                    Cl[(size_t)rowg * ldc + col] = f2b(v - b2f(h));
                } else {
                    Cf[(size_t)rowg * ldc + col] = v;
                }
            }
        }
    }
}

// ---------------- batch norm stats (reads hi/lo pair), grid (2, 128) ----------------
__global__ void bn_stats_hl(const unsigned short* __restrict__ Hh,
                            const unsigned short* __restrict__ Hl, int ldh,
                            float* __restrict__ sums, float* __restrict__ sqs)
{
    int c = blockIdx.x * 256 + threadIdx.x;
    int r0 = blockIdx.y * 64;
    float s = 0.f, q = 0.f;
    for (int r = r0; r < r0 + 64; ++r) {
        size_t idx = (size_t)r * ldh + c;
        float v = b2f(Hh[idx]) + b2f(Hl[idx]);
        s += v;
        q = fmaf(v, v, q);
    }
    atomicAdd(&sums[c], s);
    atomicAdd(&sqs[c], q);
}

// ---------------- GCN combine via MFMA: Z = relu(A_g @ H2_g + b), hi/lo bf16 out ----------------
// grid (NG, CL/64), 256 threads (4 waves). A f32 -> hi/lo LDS; H2 f32 -> transposed hi/lo LDS.
__global__ __launch_bounds__(256)
void gcn_mfma(const float* __restrict__ Amat, const float* __restrict__ H2,
              const float* __restrict__ bias,
              unsigned short* __restrict__ outh, unsigned short* __restrict__ outl)
{
    const int g = blockIdx.x, ct = blockIdx.y;
    __shared__ unsigned short AsH[4096], AsL[4096];   // [i][s] swizzled
    __shared__ unsigned short XsH[4096], XsL[4096];   // [c][s] swizzled (H2^T)
    __shared__ float Cs[64 * 68];
    const int tid = threadIdx.x;
    // stage A rows (coalesced) -> swizzled hi/lo
    {
        const int i = tid >> 2, sq = tid & 3;
        const float* ar = Amat + (size_t)g * 4096 + i * 64 + sq * 16;
        #pragma unroll
        for (int j = 0; j < 4; ++j) {
            float4 v = *(const float4*)(ar + j * 4);
            float vv[4] = {v.x, v.y, v.z, v.w};
            #pragma unroll
            for (int e = 0; e < 4; ++e) {
                int s = sq * 16 + j * 4 + e;
                unsigned short hh = f2b(vv[e]);
                int idx = (i * 64 + s) ^ ((i & 7) << 3);
                AsH[idx] = hh;
                AsL[idx] = f2b(vv[e] - b2f(hh));
            }
        }
    }
    // stage H2^T (coalesced row reads, transposed LDS writes)
    {
        const int s = tid >> 2, dq = tid & 3;
        const float* hr = H2 + (size_t)(g * 64 + s) * CL + ct * 64 + dq * 16;
        #pragma unroll
        for (int j = 0; j < 4; ++j) {
            float4 v = *(const float4*)(hr + j * 4);
            float vv[4] = {v.x, v.y, v.z, v.w};
            #pragma unroll
            for (int e = 0; e < 4; ++e) {
                int c = dq * 16 + j * 4 + e;
                unsigned short hh = f2b(vv[e]);
                int idx = (c * 64 + s) ^ ((c & 7) << 3);
                XsH[idx] = hh;
                XsL[idx] = f2b(vv[e] - b2f(hh));
            }
        }
    }
    __syncthreads();
    const int lane = tid & 63, wave = tid >> 6;
    const int fl = lane & 15, kh = (lane >> 4) * 8;
    f32x4 acc[4];
    #pragma unroll
    for (int n = 0; n < 4; ++n) acc[n] = (f32x4){0.f, 0.f, 0.f, 0.f};
    #pragma unroll
    for (int kc = 0; kc < 2; ++kc) {
        int rowa = wave * 16 + fl;
        int ra = (rowa * 64 + kc * 32 + kh) ^ ((rowa & 7) << 3);
        short8 ah = *(const short8*)&AsH[ra];
        short8 al = *(const short8*)&AsL[ra];
        #pragma unroll
        for (int n = 0; n < 4; ++n) {
            int rowb = n * 16 + fl;
            int rb = (rowb * 64 + kc * 32 + kh) ^ ((rowb & 7) << 3);
            short8 bh = *(const short8*)&XsH[rb];
            short8 bl = *(const short8*)&XsL[rb];
            acc[n] = __builtin_amdgcn_mfma_f32_16x16x32_bf16(ah, bh, acc[n], 0, 0, 0);
            acc[n] = __builtin_amdgcn_mfma_f32_16x16x32_bf16(ah, bl, acc[n], 0, 0, 0);
            acc[n] = __builtin_amdgcn_mfma_f32_16x16x32_bf16(al, bh, acc[n], 0, 0, 0);
        }
    }
    const int orow0 = (lane >> 4) * 4, ocol = lane & 15;
    #pragma unroll
    for (int n = 0; n < 4; ++n)
        #pragma unroll
        for (int r = 0; r < 4; ++r)
            Cs[(wave * 16 + orow0 + r) * 68 + n * 16 + ocol] = acc[n][r];
    __syncthreads();
    // vectorized hi/lo write-out: 8 threads per row, 128B contiguous per instruction
    {
        const int rr = tid >> 3, dq = tid & 7;
        #pragma unroll
        for (int half = 0; half < 2; ++half) {
            int nd = half * 32 + rr;
            u16x8 hv, lv;
            #pragma unroll
            for (int e = 0; e < 8; ++e) {
                float v = Cs[nd * 68 + dq * 8 + e] + bias[ct * 64 + dq * 8 + e];
                v = v > 0.f ? v : 0.f;
                unsigned short hh = f2b(v);
                hv[e] = hh;
                lv[e] = f2b(v - b2f(hh));
            }
            size_t o = (size_t)(g * 64 + nd) * ZD + ct * 64 + dq * 8;
            *(u16x8*)(outh + o) = hv;
            *(u16x8*)(outl + o) = lv;
        }
    }
}

// ---------------- per-graph Gram matrix G = Z_g Z_g^T via MFMA hi/lo ----------------
__global__ __launch_bounds__(256)
void gram_mfma(const unsigned short* __restrict__ Zh, const unsigned short* __restrict__ Zl,
               float* __restrict__ G)
{
    __shared__ unsigned short ZsH[2048], ZsL[2048];   // [64][32]
    const int g = blockIdx.x;
    const int tid = threadIdx.x;
    const int lane = tid & 63, wave = tid >> 6;
    const int lrow = lane >> 2, lkb = (lane & 3) * 8;

    f32x4 acc[4];
    #pragma unroll
    for (int n = 0; n < 4; ++n) acc[n] = (f32x4){0.f, 0.f, 0.f, 0.f};

    for (int k0 = 0; k0 < ZD; k0 += 32) {
        int row = wave * 16 + lrow;
        size_t off = (size_t)(g * 64 + row) * ZD + k0 + lkb;
        __builtin_amdgcn_global_load_lds(
            (const __attribute__((address_space(1))) void*)(Zh + off),
            (__attribute__((address_space(3))) void*)&ZsH[wave * 512], 16, 0, 0);
        __builtin_amdgcn_global_load_lds(
            (const __attribute__((address_space(1))) void*)(Zl + off),
            (__attribute__((address_space(3))) void*)&ZsL[wave * 512], 16, 0, 0);
        __syncthreads();
        const int fl = lane & 15, kh = (lane >> 4) * 8;
        int ra = (wave * 16 + fl) * 32 + kh;
        short8 ah = *(const short8*)&ZsH[ra];
        short8 al = *(const short8*)&ZsL[ra];
        #pragma unroll
        for (int n = 0; n < 4; ++n) {
            int rb = (n * 16 + fl) * 32 + kh;
            short8 bh = *(const short8*)&ZsH[rb];
            short8 bl = *(const short8*)&ZsL[rb];
            acc[n] = __builtin_amdgcn_mfma_f32_16x16x32_bf16(ah, bh, acc[n], 0, 0, 0);
            acc[n] = __builtin_amdgcn_mfma_f32_16x16x32_bf16(ah, bl, acc[n], 0, 0, 0);
            acc[n] = __builtin_amdgcn_mfma_f32_16x16x32_bf16(al, bh, acc[n], 0, 0, 0);
        }
        __syncthreads();
    }
    const int orow0 = (lane >> 4) * 4;
    const int ocol  = lane & 15;
    #pragma unroll
    for (int n = 0; n < 4; ++n)
        #pragma unroll
        for (int r = 0; r < 4; ++r)
            G[(size_t)(g * 64 + wave * 16 + orow0 + r) * 64 + n * 16 + ocol] = acc[n][r];
}

// ---------------- edge loss ----------------
__global__ void edge_loss(const int* __restrict__ e0, const int* __restrict__ e1,
                          const float* __restrict__ G, float* __restrict__ tot,
                          float* __restrict__ cnt, int negmode)
{
    __shared__ float lt[128];
    __shared__ float lc[128];
    int tid = threadIdx.x;
    if (tid < 128) { lt[tid] = 0.f; lc[tid] = 0.f; }
    __syncthreads();
    for (int e = blockIdx.x * blockDim.x + tid; e < NE; e += gridDim.x * blockDim.x) {
        int a = e0[e], b = e1[e];
        int g = a >> 6;
        float v = G[(size_t)((g << 6) + (a & 63)) * 64 + (b & 63)];
        float s = 1.f / (1.f + expf(-v));
        float p = negmode ? (1.f - s) : s;
        float l = -logf(1e-4f + p);
        atomicAdd(&lt[g], l);
        atomicAdd(&lc[g], 1.f);
    }
    __syncthreads();
    if (tid < 128) {
        atomicAdd(&tot[tid], lt[tid]);
        atomicAdd(&cnt[tid], lc[tid]);
    }
}

__global__ void lrc_final(const float* __restrict__ loss, float* __restrict__ out)
{
    int t = threadIdx.x;
    float v = loss[t] / fmaxf(loss[128 + t], 1.f) + loss[256 + t] / fmaxf(loss[384 + t], 1.f);
    __shared__ float red[128];
    red[t] = v;
    __syncthreads();
    for (int s = 64; s; s >>= 1) {
        if (t < s) red[t] += red[t + s];
        __syncthreads();
    }
    if (t == 0) out[0] = red[0] * (1.0f / 128.0f);
}

// ---------------- fused attention: s1/s2 + w + agg, per (graph, head), MFMA ----------------
__global__ __launch_bounds__(256)
void attn_fused(const float* __restrict__ xh, const float* __restrict__ phi,
                unsigned short* __restrict__ aggh, unsigned short* __restrict__ aggl)
{
    const int g = blockIdx.x, h = blockIdx.y;
    __shared__ unsigned short XtH[4096], XtL[4096];   // [d][b] swizzled
    __shared__ unsigned short WH[4096], WL[4096];     // [i][b] swizzled
    __shared__ float Cs[64 * 68];
    __shared__ float s1s[64], s2s[64];
    const int tid = threadIdx.x;
    // load X slice (coalesced), build X^T hi/lo, partial s1/s2 dots
    {
        const int b = tid >> 2, dq = tid & 3;
        const float* xr = xh + (size_t)(g * 64 + b) * CL + h * 64 + dq * 16;
        const float* pa = phi + h * 128 + dq * 16;
        const float* pb = pa + 64;
        float sa = 0.f, sb = 0.f;
        #pragma unroll
        for (int j = 0; j < 4; ++j) {
            float4 v = *(const float4*)(xr + j * 4);
            float4 A4 = *(const float4*)(pa + j * 4);
            float4 B4 = *(const float4*)(pb + j * 4);
            float vv[4] = {v.x, v.y, v.z, v.w};
            float aa[4] = {A4.x, A4.y, A4.z, A4.w};
            float bb[4] = {B4.x, B4.y, B4.z, B4.w};
            #pragma unroll
            for (int e = 0; e < 4; ++e) {
                int d = dq * 16 + j * 4 + e;
                unsigned short hh = f2b(vv[e]);
                int idx = (d * 64 + b) ^ ((d & 7) << 3);
                XtH[idx] = hh;
                XtL[idx] = f2b(vv[e] - b2f(hh));
                sa = fmaf(vv[e], aa[e], sa);
                sb = fmaf(vv[e], bb[e], sb);
            }
        }
        sa += __shfl_down(sa, 2); sa += __shfl_down(sa, 1);
        sb += __shfl_down(sb, 2); sb += __shfl_down(sb, 1);
        if (dq == 0) { s1s[b] = sa; s2s[b] = sb; }
    }
    __syncthreads();
    // W[i][b] = sigmoid(leaky(s1[i]+s2[b])), hi/lo swizzled
    {
        const int i = tid >> 2, bq = tid & 3;
        float si = s1s[i];
        #pragma unroll
        for (int e = 0; e < 16; ++e) {
            int b = bq * 16 + e;
            float t = si + s2s[b];
            t = t > 0.f ? t : 0.01f * t;
            float w = 1.f / (1.f + expf(-t));
            unsigned short hh = f2b(w);
            int idx = (i * 64 + b) ^ ((i & 7) << 3);
            WH[idx] = hh;
            WL[idx] = f2b(w - b2f(hh));
        }
    }
    __syncthreads();
    const int lane = tid & 63, wave = tid >> 6;
    const int fl = lane & 15, kh = (lane >> 4) * 8;
    f32x4 acc[4];
    #pragma unroll
    for (int n = 0; n < 4; ++n) acc[n] = (f32x4){0.f, 0.f, 0.f, 0.f};
    #pragma unroll
    for (int kc = 0; kc < 2; ++kc) {
        int rowa = wave * 16 + fl;
        int ra = (rowa * 64 + kc * 32 + kh) ^ ((rowa & 7) << 3);
        short8 ah = *(const short8*)&WH[ra];
        short8 al = *(const short8*)&WL[ra];
        #pragma unroll
        for (int n = 0; n < 4; ++n) {
            int rowb = n * 16 + fl;
            int rb = (rowb * 64 + kc * 32 + kh) ^ ((rowb & 7) << 3);
            short8 bh = *(const short8*)&XtH[rb];
            short8 bl = *(const short8*)&XtL[rb];
            acc[n] = __builtin_amdgcn_mfma_f32_16x16x32_bf16(ah, bh, acc[n], 0, 0, 0);
            acc[n] = __builtin_amdgcn_mfma_f32_16x16x32_bf16(ah, bl, acc[n], 0, 0, 0);
            acc[n] = __builtin_amdgcn_mfma_f32_16x16x32_bf16(al, bh, acc[n], 0, 0, 0);
        }
    }
    const int orow0 = (lane >> 4) * 4, ocol = lane & 15;
    #pragma unroll
    for (int n = 0; n < 4; ++n)
        #pragma unroll
        for (int r = 0; r < 4; ++r)
            Cs[(wave * 16 + orow0 + r) * 68 + n * 16 + ocol] = acc[n][r];
    __syncthreads();
    // vectorized hi/lo write-out
    {
        const int rr = tid >> 3, dq = tid & 7;
        #pragma unroll
        for (int half = 0; half < 2; ++half) {
            int nd = half * 32 + rr;
            u16x8 hv, lv;
            #pragma unroll
            for (int e = 0; e < 8; ++e) {
                float v = Cs[nd * 68 + dq * 8 + e];
                unsigned short hh = f2b(v);
                hv[e] = hh;
                lv[e] = f2b(v - b2f(hh));
            }
            size_t o = (size_t)(g * 64 + nd) * CL + h * 64 + dq * 8;
            *(u16x8*)(aggh + o) = hv;
            *(u16x8*)(aggl + o) = lv;
        }
    }
}

// ---------------- classifier head ----------------
__global__ void head_kernel(const float* __restrict__ hid, const float* __restrict__ fc2W,
                            const float* __restrict__ fc2b, float* __restrict__ preds)
{
    int n = blockIdx.x * 256 + threadIdx.x;
    const float* hr = hid + (size_t)n * 64;
    float x[64];
    #pragma unroll
    for (int k = 0; k < 64; ++k) x[k] = hr[k];
    float lg[10];
    float mx = -1e30f;
    #pragma unroll
    for (int c = 0; c < 10; ++c) {
        float s = fc2b[c];
        #pragma unroll
        for (int k = 0; k < 64; ++k) s = fmaf(x[k], fc2W[k * 10 + c], s);
        lg[c] = s;
        mx = fmaxf(mx, s);
    }
    float sum = 0.f;
    #pragma unroll
    for (int c = 0; c < 10; ++c) {
        float t = expf(lg[c] - mx) + 1e-4f;
        lg[c] = t;
        sum += t;
    }
    float inv = 1.f / sum;
    #pragma unroll
    for (int c = 0; c < 10; ++c) preds[(size_t)n * 10 + c] = lg[c] * inv;
}

__global__ void yp_kernel(const float* __restrict__ preds, float* __restrict__ out)
{
    int g = blockIdx.x;
    int lane = threadIdx.x;
    float p[10];
    const float* pr = preds + (size_t)(g * 64 + lane) * 10;
    #pragma unroll
    for (int c = 0; c < 10; ++c) p[c] = pr[c];
    #pragma unroll
    for (int off = 32; off; off >>= 1)
        #pragma unroll
        for (int c = 0; c < 10; ++c) p[c] += __shfl_down(p[c], off);
    if (lane == 0)
        #pragma unroll
        for (int c = 0; c < 10; ++c) out[g * 10 + c] = logf(p[c] * (1.0f / 64.0f));
}

extern "C" void kernel_launch(void* const* d_in, const int* in_sizes, int n_in,
                              void* d_out, int out_size, void* d_ws, size_t ws_size,
                              hipStream_t stream)
{
    (void)in_sizes; (void)n_in; (void)out_size; (void)ws_size;
    const float* x     = (const float*)d_in[0];
    const int*   ei    = (const int*)d_in[1];
    const int*   nei   = (const int*)d_in[2];
    const float* fcW   = (const float*)d_in[5];
    const float* fcb   = (const float*)d_in[6];
    const float* bng   = (const float*)d_in[7];
    const float* bnb   = (const float*)d_in[8];
    const float* convW = (const float*)d_in[9];
    const float* convb = (const float*)d_in[10];
    const float* featW = (const float*)d_in[11];
    const float* phi   = (const float*)d_in[12];
    const float* fc1W  = (const float*)d_in[13];
    const float* fc1b  = (const float*)d_in[14];
    const float* fc2W  = (const float*)d_in[15];
    const float* fc2b  = (const float*)d_in[16];
    float* out = (float*)d_out;

    char* ws = (char*)d_ws;
    unsigned short* Zh      = (unsigned short*)(ws);              // 24 MB
    unsigned short* Zl      = (unsigned short*)(ws + 25165824);   // 24 MB -> 50331648
    unsigned short* H0h     = (unsigned short*)(ws + 50331648);   // 8 MB
    unsigned short* H0l     = (unsigned short*)(ws + 58720256);   // 8 MB -> 67108864
    float*          H2      = (float*)(ws + 67108864);            // 16 MB -> 83886080
    unsigned short* xbh     = (unsigned short*)(ws + 67108864);   // 2 MB (dead before H2)
    unsigned short* xbl     = (unsigned short*)(ws + 69206016);   // 2 MB
    unsigned short* AGGh    = (unsigned short*)(ws + 67108864);   // 8 MB (after conv loop)
    unsigned short* AGGl    = (unsigned short*)(ws + 75497472);   // 8 MB
    unsigned short* fcWth   = (unsigned short*)(ws + 83886080);   // 128 KB
    unsigned short* fcWtl   = (unsigned short*)(ws + 84017152);   // 128 KB
    unsigned short* convWsh = (unsigned short*)(ws + 84148224);   // 512 KB (per-layer)
    unsigned short* convWsl = (unsigned short*)(ws + 84672512);   // 512 KB
    unsigned short* featWth = (unsigned short*)(ws + 85196800);   // 1.5 MB
    unsigned short* featWtl = (unsigned short*)(ws + 86769664);   // 1.5 MB -> 88342528
    unsigned short* fc1Wth  = (unsigned short*)(ws + 88342528);   // 64 KB
    unsigned short* fc1Wtl  = (unsigned short*)(ws + 88408064);   // 64 KB -> 88473600
    float*          Gram    = (float*)(ws + 88473600);            // 2 MB -> 90570752
    float*          DINV    = (float*)(ws + 90570752);            // 32 KB -> 90603520
    // zeroed region (single memset): DEG + Amat + LOSS + BNS3
    float*          DEG     = (float*)(ws + 91127808);            // 32 KB
    float*          Amat    = (float*)(ws + 91160576);            // 2 MB
    float*          LOSS    = (float*)(ws + 93257728);            // 2 KB
    float*          BNS3    = (float*)(ws + 93259776);            // 12 KB -> 93272064
    float*          B2      = (float*)(ws + 93272064);            // 2 KB
    float*          XH      = (float*)(ws + 50331648);            // reuse H0 (16 MB)
    float*          HID     = (float*)(ws + 50331648);            // reuse after attn

    const int* src = ei;
    const int* dst = ei + NE;

    hipMemsetAsync(DEG, 0, 93272064 - 91127808, stream);

    deg_kernel<<<NE / 256, 256, 0, stream>>>(dst, DEG);
    deg_finish<<<NN / 256, 256, 0, stream>>>(DEG, DINV);
    build_adj<<<NE / 256, 256, 0, stream>>>(src, dst, DINV, Amat);
    adj_diag<<<NN / 256, 256, 0, stream>>>(DEG, Amat);

    // hi/lo conversions
    cvt_split<<<(NN * NF / 4) / 256, 256, 0, stream>>>(x, xbh, xbl);
    cvtT<<<dim3(CL / 32, NF / 32), dim3(32, 8), 0, stream>>>(fcW, fcWth, fcWtl, NF, CL);
    cvtT<<<dim3(CL / 32, ZD / 32), dim3(32, 8), 0, stream>>>(featW, featWth, featWtl, ZD, CL);
    cvtT<<<dim3(2, 16), dim3(32, 8), 0, stream>>>(fc1W, fc1Wth, fc1Wtl, 512, 64);

    // h0 = x @ fc_W + fc_b  (hi/lo MFMA, split output)
    gemm_hl<0, true, true><<<dim3(CL / 64, NN / 128), 256, 0, stream>>>(
        xbh, xbl, NF, fcWth, fcWtl, NF, nullptr, H0h, H0l, CL, fcb, NF);

    for (int i = 0; i < 3; ++i) {
        const unsigned short* Ah = (i == 0) ? H0h : (Zh + (size_t)(i - 1) * CL);
        const unsigned short* Al = (i == 0) ? H0l : (Zl + (size_t)(i - 1) * CL);
        int lda = (i == 0) ? CL : ZD;
        float* sums = BNS3 + i * 1024;
        float* sqs  = sums + 512;
        bn_stats_hl<<<dim3(2, 128), 256, 0, stream>>>(Ah, Al, lda, sums, sqs);
        wscaleT<<<dim3(CL / 32, CL / 32), dim3(32, 8), 0, stream>>>(
            convW + (size_t)i * CL * CL, sums, sqs, bng + i * CL, convWsh, convWsl, CL, CL);
        bias_dot<<<CL / 64, 256, 0, stream>>>(convW + (size_t)i * CL * CL, sums, sqs,
                                              bng + i * CL, bnb + i * CL, B2, CL, CL);
        gemm_hl<0, true, false><<<dim3(CL / 64, NN / 128), 256, 0, stream>>>(
            Ah, Al, lda, convWsh, convWsl, CL, H2, nullptr, nullptr, CL, B2, CL);
        gcn_mfma<<<dim3(NG, CL / 64), 256, 0, stream>>>(Amat, H2, convb + i * CL,
                                                        Zh + (size_t)i * CL,
                                                        Zl + (size_t)i * CL);
    }

    // edge reconstruction loss via per-graph Gram matrices (MFMA)
    gram_mfma<<<NG, 256, 0, stream>>>(Zh, Zl, Gram);
    edge_loss<<<128, 256, 0, stream>>>(ei, ei + NE, Gram, LOSS, LOSS + 128, 0);
    edge_loss<<<128, 256, 0, stream>>>(nei, nei + NE, Gram, LOSS + 256, LOSS + 384, 1);
    lrc_final<<<1, 128, 0, stream>>>(LOSS, out + 1280);

    // xh = z @ feat_W  (hi/lo MFMA, f32 out into old H0 region)
    gemm_hl<0, false, false><<<dim3(CL / 64, NN / 128), 256, 0, stream>>>(
        Zh, Zl, ZD, featWth, featWtl, ZD, XH, nullptr, nullptr, CL, nullptr, ZD);

    // fused s12 + attention aggregation (MFMA), hi/lo bf16 AGG out
    attn_fused<<<dim3(NG, 8), 256, 0, stream>>>(XH, phi, AGGh, AGGl);

    // hid = leaky_relu(agg @ fc1 + b)  (hi/lo MFMA)
    gemm_hl<2, true, false><<<dim3(1, NN / 128), 256, 0, stream>>>(
        AGGh, AGGl, CL, fc1Wth, fc1Wtl, CL, HID, nullptr, nullptr, 64, fc1b, CL);
    head_kernel<<<NN / 256, 256, 0, stream>>>(HID, fc2W, fc2b, out + 1281);
    yp_kernel<<<NG, 64, 0, stream>>>(out + 1281, out);
}

// Round 6
// 419.413 us; speedup vs baseline: 2.3146x; 1.1232x over previous
//
#include <hip/hip_runtime.h>

#define NN 8192      // nodes
#define NG 128       // graphs
#define NF 128       // input feats
#define CL 512       // hidden dim
#define ZD 1536      // concat dim (3*512)
#define NE 262144    // edges per edge set

typedef __attribute__((ext_vector_type(8))) short short8;
typedef __attribute__((ext_vector_type(8))) unsigned short u16x8;
typedef __attribute__((ext_vector_type(4))) float f32x4;

__device__ __forceinline__ unsigned short f2b(float f) {
    unsigned int u = __float_as_uint(f);
    unsigned int r = (u + 0x7fffu + ((u >> 16) & 1u)) >> 16;
    return (unsigned short)r;
}
__device__ __forceinline__ float b2f(unsigned short h) {
    return __uint_as_float(((unsigned int)h) << 16);
}

// ---------------- degree / dense adjacency ----------------
__global__ void deg_kernel(const int* __restrict__ dst, float* __restrict__ deg) {
    int e = blockIdx.x * 256 + threadIdx.x;
    atomicAdd(&deg[dst[e]], 1.0f);
}

__global__ void deg_finish(float* __restrict__ deg, float* __restrict__ dinv) {
    int n = blockIdx.x * 256 + threadIdx.x;
    float d = deg[n] + 1.0f;
    deg[n] = d;
    dinv[n] = rsqrtf(d);
}

__global__ void build_adj(const int* __restrict__ src, const int* __restrict__ dst,
                          const float* __restrict__ dinv, float* __restrict__ A) {
    int e = blockIdx.x * 256 + threadIdx.x;
    int s = src[e], d = dst[e];
    int g = d >> 6;
    atomicAdd(&A[(size_t)((g << 6) + (d & 63)) * 64 + (s & 63)], dinv[s] * dinv[d]);
}

__global__ void adj_diag(const float* __restrict__ deg, float* __restrict__ A) {
    int n = blockIdx.x * 256 + threadIdx.x;
    int g = n >> 6, i = n & 63;
    A[(size_t)(g * 64 + i) * 64 + i] += 1.0f / deg[n];
}

// ---------------- conversions (hi/lo split) ----------------
__global__ void cvt_split(const float* __restrict__ in,
                          unsigned short* __restrict__ oh, unsigned short* __restrict__ ol) {
    int i = blockIdx.x * 256 + threadIdx.x;
    float4 v = *(const float4*)(in + (size_t)i * 4);
    float vv[4] = {v.x, v.y, v.z, v.w};
    ushort4 h4, l4;
    unsigned short* hp = (unsigned short*)&h4;
    unsigned short* lp = (unsigned short*)&l4;
    #pragma unroll
    for (int j = 0; j < 4; ++j) {
        unsigned short h = f2b(vv[j]);
        hp[j] = h;
        lp[j] = f2b(vv[j] - b2f(h));
    }
    *(ushort4*)(oh + (size_t)i * 4) = h4;
    *(ushort4*)(ol + (size_t)i * 4) = l4;
}

// W: Kd x Nd row-major f32 -> Wt hi/lo: Nd x Kd row-major bf16
__global__ void cvtT(const float* __restrict__ W,
                     unsigned short* __restrict__ Wh, unsigned short* __restrict__ Wl,
                     int Kd, int Nd) {
    __shared__ float t[32][33];
    int kb = blockIdx.y * 32, nb = blockIdx.x * 32;
    int tx = threadIdx.x, ty = threadIdx.y;   // 32 x 8
    for (int i = ty; i < 32; i += 8)
        t[i][tx] = W[(size_t)(kb + i) * Nd + nb + tx];
    __syncthreads();
    for (int i = ty; i < 32; i += 8) {
        float v = t[tx][i];
        unsigned short h = f2b(v);
        Wh[(size_t)(nb + i) * Kd + kb + tx] = h;
        Wl[(size_t)(nb + i) * Kd + kb + tx] = f2b(v - b2f(h));
    }
}

// scaled transpose with inline BN coef: Wt[n][k] = W[k][n] * s[k], s = g*rsqrt(var+eps)
__global__ void wscaleT(const float* __restrict__ W,
                        const float* __restrict__ sums, const float* __restrict__ sqs,
                        const float* __restrict__ g,
                        unsigned short* __restrict__ Wh, unsigned short* __restrict__ Wl,
                        int Kd, int Nd) {
    __shared__ float t[32][33];
    int kb = blockIdx.y * 32, nb = blockIdx.x * 32;
    int tx = threadIdx.x, ty = threadIdx.y;
    for (int i = ty; i < 32; i += 8)
        t[i][tx] = W[(size_t)(kb + i) * Nd + nb + tx];
    __syncthreads();
    int kc = kb + tx;
    float m = sums[kc] * (1.0f / NN);
    float var = sqs[kc] * (1.0f / NN) - m * m;
    float sc = rsqrtf(var + 1e-5f) * g[kc];
    for (int i = ty; i < 32; i += 8) {
        float v = t[tx][i] * sc;
        unsigned short h = f2b(v);
        Wh[(size_t)(nb + i) * Kd + kb + tx] = h;
        Wl[(size_t)(nb + i) * Kd + kb + tx] = f2b(v - b2f(h));
    }
}

// bias2[n] = sum_k t[k]*W[k][n], t = b - m*s. grid (Nd/64), 256 thr, 4-way k-split.
__global__ void bias_dot(const float* __restrict__ W,
                         const float* __restrict__ sums, const float* __restrict__ sqs,
                         const float* __restrict__ g, const float* __restrict__ b,
                         float* __restrict__ bias2, int Kd, int Nd) {
    __shared__ float red[256];
    int n = blockIdx.x * 64 + (threadIdx.x & 63);
    int kp = threadIdx.x >> 6;
    float acc = 0.f;
    for (int k = kp; k < Kd; k += 4) {
        float m = sums[k] * (1.0f / NN);
        float var = sqs[k] * (1.0f / NN) - m * m;
        float sc = rsqrtf(var + 1e-5f) * g[k];
        float tk = b[k] - m * sc;
        acc = fmaf(tk, W[(size_t)k * Nd + n], acc);
    }
    red[threadIdx.x] = acc;
    __syncthreads();
    if (threadIdx.x < 64)
        bias2[n] = red[threadIdx.x] + red[threadIdx.x + 64] +
                   red[threadIdx.x + 128] + red[threadIdx.x + 192];
}

// ---------------- bf16 hi/lo MFMA GEMM: C = A @ Bt^T, 128x64 tile ----------------
// XCD-aware swizzle: the gridDim.x N-tiles sharing one A-panel map to the SAME XCD
// (linear_id % 8 == panel % 8) so the A-panel stays in that XCD's L2.
// STATS: epilogue accumulates per-column sum/sumsq of C (for BN fold) via atomics.
template<int ACT, bool HASB, bool SPLIT, bool STATS>
__global__ __launch_bounds__(256)
void gemm_hl(const unsigned short* __restrict__ Ah, const unsigned short* __restrict__ Al, int lda,
             const unsigned short* __restrict__ Bh, const unsigned short* __restrict__ Bl, int ldb,
             float* __restrict__ Cf, unsigned short* __restrict__ Ch, unsigned short* __restrict__ Cl,
             int ldc, const float* __restrict__ bias, int K,
             float* __restrict__ sums, float* __restrict__ sqs)
{
    __shared__ unsigned short AsH[4096], AsL[4096];   // [128][32]
    __shared__ unsigned short BsH[2048], BsL[2048];   // [64][32]
    const int tid = threadIdx.x;
    const int lane = tid & 63, wave = tid >> 6;
    const int wr = wave >> 1, wc = wave & 1;
    // XCD swizzle (bijective; requires gridDim.y % 8 == 0)
    const int ntile = gridDim.x;
    const int li = blockIdx.y * ntile + blockIdx.x;
    const int x8 = li & 7, rest = li >> 3;
    const int bt = rest % ntile;
    const int bp = (rest / ntile) * 8 + x8;
    const int bm = bp * 128, bn = bt * 64;

    f32x4 acc[4][2];
    #pragma unroll
    for (int m = 0; m < 4; ++m)
        #pragma unroll
        for (int n = 0; n < 2; ++n)
            acc[m][n] = (f32x4){0.f, 0.f, 0.f, 0.f};

    const int lrow = lane >> 2;
    const int lkb  = (lane & 3) * 8;

    for (int k0 = 0; k0 < K; k0 += 32) {
        #pragma unroll
        for (int c = 0; c < 2; ++c) {
            int chunk = wave * 2 + c;
            int row = chunk * 16 + lrow;
            size_t offA = (size_t)(bm + row) * lda + k0 + lkb;
            __builtin_amdgcn_global_load_lds(
                (const __attribute__((address_space(1))) void*)(Ah + offA),
                (__attribute__((address_space(3))) void*)&AsH[chunk * 512], 16, 0, 0);
            __builtin_amdgcn_global_load_lds(
                (const __attribute__((address_space(1))) void*)(Al + offA),
                (__attribute__((address_space(3))) void*)&AsL[chunk * 512], 16, 0, 0);
        }
        {
            int rowb = wave * 16 + lrow;
            size_t offB = (size_t)(bn + rowb) * ldb + k0 + lkb;
            __builtin_amdgcn_global_load_lds(
                (const __attribute__((address_space(1))) void*)(Bh + offB),
                (__attribute__((address_space(3))) void*)&BsH[wave * 512], 16, 0, 0);
            __builtin_amdgcn_global_load_lds(
                (const __attribute__((address_space(1))) void*)(Bl + offB),
                (__attribute__((address_space(3))) void*)&BsL[wave * 512], 16, 0, 0);
        }
        __syncthreads();
        const int fl = lane & 15, kh = (lane >> 4) * 8;
        short8 ah[4], al[4], bh[2], bl[2];
        #pragma unroll
        for (int m = 0; m < 4; ++m) {
            int r = (wr * 64 + m * 16 + fl) * 32 + kh;
            ah[m] = *(const short8*)&AsH[r];
            al[m] = *(const short8*)&AsL[r];
        }
        #pragma unroll
        for (int n = 0; n < 2; ++n) {
            int r = (wc * 32 + n * 16 + fl) * 32 + kh;
            bh[n] = *(const short8*)&BsH[r];
            bl[n] = *(const short8*)&BsL[r];
        }
        #pragma unroll
        for (int m = 0; m < 4; ++m)
            #pragma unroll
            for (int n = 0; n < 2; ++n) {
                acc[m][n] = __builtin_amdgcn_mfma_f32_16x16x32_bf16(ah[m], bh[n], acc[m][n], 0, 0, 0);
                acc[m][n] = __builtin_amdgcn_mfma_f32_16x16x32_bf16(ah[m], bl[n], acc[m][n], 0, 0, 0);
                acc[m][n] = __builtin_amdgcn_mfma_f32_16x16x32_bf16(al[m], bh[n], acc[m][n], 0, 0, 0);
            }
        __syncthreads();
    }
    const int orow0 = (lane >> 4) * 4;
    const int ocol  = lane & 15;
    #pragma unroll
    for (int n = 0; n < 2; ++n) {
        int col = bn + wc * 32 + n * 16 + ocol;
        float bb = HASB ? bias[col] : 0.f;
        float ss = 0.f, qq = 0.f;
        #pragma unroll
        for (int m = 0; m < 4; ++m) {
            #pragma unroll
            for (int r = 0; r < 4; ++r) {
                int rowg = bm + wr * 64 + m * 16 + orow0 + r;
                float v = acc[m][n][r] + bb;
                if (ACT == 2) v = v > 0.f ? v : 0.01f * v;
                if (STATS) { ss += v; qq = fmaf(v, v, qq); }
                if (SPLIT) {
                    unsigned short h = f2b(v);
                    Ch[(size_t)rowg * ldc + col] = h;
                    Cl[(size_t)rowg * ldc + col] = f2b(v - b2f(h));
                } else {
                    Cf[(size_t)rowg * ldc + col] = v;
                }
            }
        }
        if (STATS) {
            ss += __shfl_down(ss, 32); ss += __shfl_down(ss, 16);
            qq += __shfl_down(qq, 32); qq += __shfl_down(qq, 16);
            if (lane < 16) {
                atomicAdd(&sums[col], ss);
                atomicAdd(&sqs[col], qq);
            }
        }
    }
}

// ---------------- GCN combine via MFMA: Z = relu(A_g @ H2_g + b), hi/lo bf16 out ----------------
// grid (NG, CL/64), 256 threads (4 waves). STATS: per-column sum/sumsq of Z for next BN.
template<bool STATS>
__global__ __launch_bounds__(256)
void gcn_mfma(const float* __restrict__ Amat, const float* __restrict__ H2,
              const float* __restrict__ bias,
              unsigned short* __restrict__ outh, unsigned short* __restrict__ outl,
              float* __restrict__ sums, float* __restrict__ sqs)
{
    const int g = blockIdx.x, ct = blockIdx.y;
    __shared__ unsigned short AsH[4096], AsL[4096];   // [i][s] swizzled
    __shared__ unsigned short XsH[4096], XsL[4096];   // [c][s] swizzled (H2^T)
    __shared__ float Cs[64 * 68];
    const int tid = threadIdx.x;
    {
        const int i = tid >> 2, sq = tid & 3;
        const float* ar = Amat + (size_t)g * 4096 + i * 64 + sq * 16;
        #pragma unroll
        for (int j = 0; j < 4; ++j) {
            float4 v = *(const float4*)(ar + j * 4);
            float vv[4] = {v.x, v.y, v.z, v.w};
            #pragma unroll
            for (int e = 0; e < 4; ++e) {
                int s = sq * 16 + j * 4 + e;
                unsigned short hh = f2b(vv[e]);
                int idx = (i * 64 + s) ^ ((i & 7) << 3);
                AsH[idx] = hh;
                AsL[idx] = f2b(vv[e] - b2f(hh));
            }
        }
    }
    {
        const int s = tid >> 2, dq = tid & 3;
        const float* hr = H2 + (size_t)(g * 64 + s) * CL + ct * 64 + dq * 16;
        #pragma unroll
        for (int j = 0; j < 4; ++j) {
            float4 v = *(const float4*)(hr + j * 4);
            float vv[4] = {v.x, v.y, v.z, v.w};
            #pragma unroll
            for (int e = 0; e < 4; ++e) {
                int c = dq * 16 + j * 4 + e;
                unsigned short hh = f2b(vv[e]);
                int idx = (c * 64 + s) ^ ((c & 7) << 3);
                XsH[idx] = hh;
                XsL[idx] = f2b(vv[e] - b2f(hh));
            }
        }
    }
    __syncthreads();
    const int lane = tid & 63, wave = tid >> 6;
    const int fl = lane & 15, kh = (lane >> 4) * 8;
    f32x4 acc[4];
    #pragma unroll
    for (int n = 0; n < 4; ++n) acc[n] = (f32x4){0.f, 0.f, 0.f, 0.f};
    #pragma unroll
    for (int kc = 0; kc < 2; ++kc) {
        int rowa = wave * 16 + fl;
        int ra = (rowa * 64 + kc * 32 + kh) ^ ((rowa & 7) << 3);
        short8 ah = *(const short8*)&AsH[ra];
        short8 al = *(const short8*)&AsL[ra];
        #pragma unroll
        for (int n = 0; n < 4; ++n) {
            int rowb = n * 16 + fl;
            int rb = (rowb * 64 + kc * 32 + kh) ^ ((rowb & 7) << 3);
            short8 bh = *(const short8*)&XsH[rb];
            short8 bl = *(const short8*)&XsL[rb];
            acc[n] = __builtin_amdgcn_mfma_f32_16x16x32_bf16(ah, bh, acc[n], 0, 0, 0);
            acc[n] = __builtin_amdgcn_mfma_f32_16x16x32_bf16(ah, bl, acc[n], 0, 0, 0);
            acc[n] = __builtin_amdgcn_mfma_f32_16x16x32_bf16(al, bh, acc[n], 0, 0, 0);
        }
    }
    const int orow0 = (lane >> 4) * 4, ocol = lane & 15;
    #pragma unroll
    for (int n = 0; n < 4; ++n)
        #pragma unroll
        for (int r = 0; r < 4; ++r)
            Cs[(wave * 16 + orow0 + r) * 68 + n * 16 + ocol] = acc[n][r];
    __syncthreads();
    {
        const int rr = tid >> 3, dq = tid & 7;
        #pragma unroll
        for (int half = 0; half < 2; ++half) {
            int nd = half * 32 + rr;
            u16x8 hv, lv;
            #pragma unroll
            for (int e = 0; e < 8; ++e) {
                float v = Cs[nd * 68 + dq * 8 + e] + bias[ct * 64 + dq * 8 + e];
                v = v > 0.f ? v : 0.f;
                unsigned short hh = f2b(v);
                hv[e] = hh;
                lv[e] = f2b(v - b2f(hh));
            }
            size_t o = (size_t)(g * 64 + nd) * ZD + ct * 64 + dq * 8;
            *(u16x8*)(outh + o) = hv;
            *(u16x8*)(outl + o) = lv;
        }
    }
    if (STATS && tid < 64) {
        float bb = bias[ct * 64 + tid];
        float ss = 0.f, qq = 0.f;
        for (int row = 0; row < 64; ++row) {
            float v = Cs[row * 68 + tid] + bb;
            v = v > 0.f ? v : 0.f;
            ss += v;
            qq = fmaf(v, v, qq);
        }
        atomicAdd(&sums[ct * 64 + tid], ss);
        atomicAdd(&sqs[ct * 64 + tid], qq);
    }
}

// ---------------- per-graph Gram matrix G = Z_g Z_g^T via MFMA hi/lo ----------------
__global__ __launch_bounds__(256)
void gram_mfma(const unsigned short* __restrict__ Zh, const unsigned short* __restrict__ Zl,
               float* __restrict__ G)
{
    __shared__ unsigned short ZsH[2048], ZsL[2048];   // [64][32]
    const int g = blockIdx.x;
    const int tid = threadIdx.x;
    const int lane = tid & 63, wave = tid >> 6;
    const int lrow = lane >> 2, lkb = (lane & 3) * 8;

    f32x4 acc[4];
    #pragma unroll
    for (int n = 0; n < 4; ++n) acc[n] = (f32x4){0.f, 0.f, 0.f, 0.f};

    for (int k0 = 0; k0 < ZD; k0 += 32) {
        int row = wave * 16 + lrow;
        size_t off = (size_t)(g * 64 + row) * ZD + k0 + lkb;
        __builtin_amdgcn_global_load_lds(
            (const __attribute__((address_space(1))) void*)(Zh + off),
            (__attribute__((address_space(3))) void*)&ZsH[wave * 512], 16, 0, 0);
        __builtin_amdgcn_global_load_lds(
            (const __attribute__((address_space(1))) void*)(Zl + off),
            (__attribute__((address_space(3))) void*)&ZsL[wave * 512], 16, 0, 0);
        __syncthreads();
        const int fl = lane & 15, kh = (lane >> 4) * 8;
        int ra = (wave * 16 + fl) * 32 + kh;
        short8 ah = *(const short8*)&ZsH[ra];
        short8 al = *(const short8*)&ZsL[ra];
        #pragma unroll
        for (int n = 0; n < 4; ++n) {
            int rb = (n * 16 + fl) * 32 + kh;
            short8 bh = *(const short8*)&ZsH[rb];
            short8 bl = *(const short8*)&ZsL[rb];
            acc[n] = __builtin_amdgcn_mfma_f32_16x16x32_bf16(ah, bh, acc[n], 0, 0, 0);
            acc[n] = __builtin_amdgcn_mfma_f32_16x16x32_bf16(ah, bl, acc[n], 0, 0, 0);
            acc[n] = __builtin_amdgcn_mfma_f32_16x16x32_bf16(al, bh, acc[n], 0, 0, 0);
        }
        __syncthreads();
    }
    const int orow0 = (lane >> 4) * 4;
    const int ocol  = lane & 15;
    #pragma unroll
    for (int n = 0; n < 4; ++n)
        #pragma unroll
        for (int r = 0; r < 4; ++r)
            G[(size_t)(g * 64 + wave * 16 + orow0 + r) * 64 + n * 16 + ocol] = acc[n][r];
}

// ---------------- edge loss ----------------
__global__ void edge_loss(const int* __restrict__ e0, const int* __restrict__ e1,
                          const float* __restrict__ G, float* __restrict__ tot,
                          float* __restrict__ cnt, int negmode)
{
    __shared__ float lt[128];
    __shared__ float lc[128];
    int tid = threadIdx.x;
    if (tid < 128) { lt[tid] = 0.f; lc[tid] = 0.f; }
    __syncthreads();
    for (int e = blockIdx.x * blockDim.x + tid; e < NE; e += gridDim.x * blockDim.x) {
        int a = e0[e], b = e1[e];
        int g = a >> 6;
        float v = G[(size_t)((g << 6) + (a & 63)) * 64 + (b & 63)];
        float s = 1.f / (1.f + expf(-v));
        float p = negmode ? (1.f - s) : s;
        float l = -logf(1e-4f + p);
        atomicAdd(&lt[g], l);
        atomicAdd(&lc[g], 1.f);
    }
    __syncthreads();
    if (tid < 128) {
        atomicAdd(&tot[tid], lt[tid]);
        atomicAdd(&cnt[tid], lc[tid]);
    }
}

__global__ void lrc_final(const float* __restrict__ loss, float* __restrict__ out)
{
    int t = threadIdx.x;
    float v = loss[t] / fmaxf(loss[128 + t], 1.f) + loss[256 + t] / fmaxf(loss[384 + t], 1.f);
    __shared__ float red[128];
    red[t] = v;
    __syncthreads();
    for (int s = 64; s; s >>= 1) {
        if (t < s) red[t] += red[t + s];
        __syncthreads();
    }
    if (t == 0) out[0] = red[0] * (1.0f / 128.0f);
}

// ---------------- fused attention: s1/s2 + w + agg, per (graph, head), MFMA ----------------
__global__ __launch_bounds__(256)
void attn_fused(const float* __restrict__ xh, const float* __restrict__ phi,
                unsigned short* __restrict__ aggh, unsigned short* __restrict__ aggl)
{
    const int g = blockIdx.x, h = blockIdx.y;
    __shared__ unsigned short XtH[4096], XtL[4096];   // [d][b] swizzled
    __shared__ unsigned short WH[4096], WL[4096];     // [i][b] swizzled
    __shared__ float Cs[64 * 68];
    __shared__ float s1s[64], s2s[64];
    const int tid = threadIdx.x;
    {
        const int b = tid >> 2, dq = tid & 3;
        const float* xr = xh + (size_t)(g * 64 + b) * CL + h * 64 + dq * 16;
        const float* pa = phi + h * 128 + dq * 16;
        const float* pb = pa + 64;
        float sa = 0.f, sb = 0.f;
        #pragma unroll
        for (int j = 0; j < 4; ++j) {
            float4 v = *(const float4*)(xr + j * 4);
            float4 A4 = *(const float4*)(pa + j * 4);
            float4 B4 = *(const float4*)(pb + j * 4);
            float vv[4] = {v.x, v.y, v.z, v.w};
            float aa[4] = {A4.x, A4.y, A4.z, A4.w};
            float bb[4] = {B4.x, B4.y, B4.z, B4.w};
            #pragma unroll
            for (int e = 0; e < 4; ++e) {
                int d = dq * 16 + j * 4 + e;
                unsigned short hh = f2b(vv[e]);
                int idx = (d * 64 + b) ^ ((d & 7) << 3);
                XtH[idx] = hh;
                XtL[idx] = f2b(vv[e] - b2f(hh));
                sa = fmaf(vv[e], aa[e], sa);
                sb = fmaf(vv[e], bb[e], sb);
            }
        }
        sa += __shfl_down(sa, 2); sa += __shfl_down(sa, 1);
        sb += __shfl_down(sb, 2); sb += __shfl_down(sb, 1);
        if (dq == 0) { s1s[b] = sa; s2s[b] = sb; }
    }
    __syncthreads();
    {
        const int i = tid >> 2, bq = tid & 3;
        float si = s1s[i];
        #pragma unroll
        for (int e = 0; e < 16; ++e) {
            int b = bq * 16 + e;
            float t = si + s2s[b];
            t = t > 0.f ? t : 0.01f * t;
            float w = 1.f / (1.f + expf(-t));
            unsigned short hh = f2b(w);
            int idx = (i * 64 + b) ^ ((i & 7) << 3);
            WH[idx] = hh;
            WL[idx] = f2b(w - b2f(hh));
        }
    }
    __syncthreads();
    const int lane = tid & 63, wave = tid >> 6;
    const int fl = lane & 15, kh = (lane >> 4) * 8;
    f32x4 acc[4];
    #pragma unroll
    for (int n = 0; n < 4; ++n) acc[n] = (f32x4){0.f, 0.f, 0.f, 0.f};
    #pragma unroll
    for (int kc = 0; kc < 2; ++kc) {
        int rowa = wave * 16 + fl;
        int ra = (rowa * 64 + kc * 32 + kh) ^ ((rowa & 7) << 3);
        short8 ah = *(const short8*)&WH[ra];
        short8 al = *(const short8*)&WL[ra];
        #pragma unroll
        for (int n = 0; n < 4; ++n) {
            int rowb = n * 16 + fl;
            int rb = (rowb * 64 + kc * 32 + kh) ^ ((rowb & 7) << 3);
            short8 bh = *(const short8*)&XtH[rb];
            short8 bl = *(const short8*)&XtL[rb];
            acc[n] = __builtin_amdgcn_mfma_f32_16x16x32_bf16(ah, bh, acc[n], 0, 0, 0);
            acc[n] = __builtin_amdgcn_mfma_f32_16x16x32_bf16(ah, bl, acc[n], 0, 0, 0);
            acc[n] = __builtin_amdgcn_mfma_f32_16x16x32_bf16(al, bh, acc[n], 0, 0, 0);
        }
    }
    const int orow0 = (lane >> 4) * 4, ocol = lane & 15;
    #pragma unroll
    for (int n = 0; n < 4; ++n)
        #pragma unroll
        for (int r = 0; r < 4; ++r)
            Cs[(wave * 16 + orow0 + r) * 68 + n * 16 + ocol] = acc[n][r];
    __syncthreads();
    {
        const int rr = tid >> 3, dq = tid & 7;
        #pragma unroll
        for (int half = 0; half < 2; ++half) {
            int nd = half * 32 + rr;
            u16x8 hv, lv;
            #pragma unroll
            for (int e = 0; e < 8; ++e) {
                float v = Cs[nd * 68 + dq * 8 + e];
                unsigned short hh = f2b(v);
                hv[e] = hh;
                lv[e] = f2b(v - b2f(hh));
            }
            size_t o = (size_t)(g * 64 + nd) * CL + h * 64 + dq * 8;
            *(u16x8*)(aggh + o) = hv;
            *(u16x8*)(aggl + o) = lv;
        }
    }
}

// ---------------- classifier head ----------------
__global__ void head_kernel(const float* __restrict__ hid, const float* __restrict__ fc2W,
                            const float* __restrict__ fc2b, float* __restrict__ preds)
{
    int n = blockIdx.x * 256 + threadIdx.x;
    const float* hr = hid + (size_t)n * 64;
    float x[64];
    #pragma unroll
    for (int k = 0; k < 64; ++k) x[k] = hr[k];
    float lg[10];
    float mx = -1e30f;
    #pragma unroll
    for (int c = 0; c < 10; ++c) {
        float s = fc2b[c];
        #pragma unroll
        for (int k = 0; k < 64; ++k) s = fmaf(x[k], fc2W[k * 10 + c], s);
        lg[c] = s;
        mx = fmaxf(mx, s);
    }
    float sum = 0.f;
    #pragma unroll
    for (int c = 0; c < 10; ++c) {
        float t = expf(lg[c] - mx) + 1e-4f;
        lg[c] = t;
        sum += t;
    }
    float inv = 1.f / sum;
    #pragma unroll
    for (int c = 0; c < 10; ++c) preds[(size_t)n * 10 + c] = lg[c] * inv;
}

__global__ void yp_kernel(const float* __restrict__ preds, float* __restrict__ out)
{
    int g = blockIdx.x;
    int lane = threadIdx.x;
    float p[10];
    const float* pr = preds + (size_t)(g * 64 + lane) * 10;
    #pragma unroll
    for (int c = 0; c < 10; ++c) p[c] = pr[c];
    #pragma unroll
    for (int off = 32; off; off >>= 1)
        #pragma unroll
        for (int c = 0; c < 10; ++c) p[c] += __shfl_down(p[c], off);
    if (lane == 0)
        #pragma unroll
        for (int c = 0; c < 10; ++c) out[g * 10 + c] = logf(p[c] * (1.0f / 64.0f));
}

extern "C" void kernel_launch(void* const* d_in, const int* in_sizes, int n_in,
                              void* d_out, int out_size, void* d_ws, size_t ws_size,
                              hipStream_t stream)
{
    (void)in_sizes; (void)n_in; (void)out_size; (void)ws_size;
    const float* x     = (const float*)d_in[0];
    const int*   ei    = (const int*)d_in[1];
    const int*   nei   = (const int*)d_in[2];
    const float* fcW   = (const float*)d_in[5];
    const float* fcb   = (const float*)d_in[6];
    const float* bng   = (const float*)d_in[7];
    const float* bnb   = (const float*)d_in[8];
    const float* convW = (const float*)d_in[9];
    const float* convb = (const float*)d_in[10];
    const float* featW = (const float*)d_in[11];
    const float* phi   = (const float*)d_in[12];
    const float* fc1W  = (const float*)d_in[13];
    const float* fc1b  = (const float*)d_in[14];
    const float* fc2W  = (const float*)d_in[15];
    const float* fc2b  = (const float*)d_in[16];
    float* out = (float*)d_out;

    char* ws = (char*)d_ws;
    unsigned short* Zh      = (unsigned short*)(ws);              // 24 MB
    unsigned short* Zl      = (unsigned short*)(ws + 25165824);   // 24 MB -> 50331648
    unsigned short* H0h     = (unsigned short*)(ws + 50331648);   // 8 MB
    unsigned short* H0l     = (unsigned short*)(ws + 58720256);   // 8 MB -> 67108864
    float*          H2      = (float*)(ws + 67108864);            // 16 MB -> 83886080
    unsigned short* xbh     = (unsigned short*)(ws + 67108864);   // 2 MB (dead before H2)
    unsigned short* xbl     = (unsigned short*)(ws + 69206016);   // 2 MB
    unsigned short* AGGh    = (unsigned short*)(ws + 67108864);   // 8 MB (after conv loop)
    unsigned short* AGGl    = (unsigned short*)(ws + 75497472);   // 8 MB
    unsigned short* fcWth   = (unsigned short*)(ws + 83886080);   // 128 KB
    unsigned short* fcWtl   = (unsigned short*)(ws + 84017152);   // 128 KB
    unsigned short* convWsh = (unsigned short*)(ws + 84148224);   // 512 KB (per-layer)
    unsigned short* convWsl = (unsigned short*)(ws + 84672512);   // 512 KB
    unsigned short* featWth = (unsigned short*)(ws + 85196800);   // 1.5 MB
    unsigned short* featWtl = (unsigned short*)(ws + 86769664);   // 1.5 MB -> 88342528
    unsigned short* fc1Wth  = (unsigned short*)(ws + 88342528);   // 64 KB
    unsigned short* fc1Wtl  = (unsigned short*)(ws + 88408064);   // 64 KB -> 88473600
    float*          Gram    = (float*)(ws + 88473600);            // 2 MB -> 90570752
    float*          DINV    = (float*)(ws + 90570752);            // 32 KB -> 90603520
    // zeroed region (single memset): DEG + Amat + LOSS + BNS3
    float*          DEG     = (float*)(ws + 91127808);            // 32 KB
    float*          Amat    = (float*)(ws + 91160576);            // 2 MB
    float*          LOSS    = (float*)(ws + 93257728);            // 2 KB
    float*          BNS3    = (float*)(ws + 93259776);            // 12 KB -> 93272064
    float*          B2      = (float*)(ws + 93272064);            // 2 KB
    float*          XH      = (float*)(ws + 50331648);            // reuse H0 (16 MB)
    float*          HID     = (float*)(ws + 50331648);            // reuse after attn

    const int* src = ei;
    const int* dst = ei + NE;

    hipMemsetAsync(DEG, 0, 93272064 - 91127808, stream);

    deg_kernel<<<NE / 256, 256, 0, stream>>>(dst, DEG);
    deg_finish<<<NN / 256, 256, 0, stream>>>(DEG, DINV);
    build_adj<<<NE / 256, 256, 0, stream>>>(src, dst, DINV, Amat);
    adj_diag<<<NN / 256, 256, 0, stream>>>(DEG, Amat);

    // hi/lo conversions
    cvt_split<<<(NN * NF / 4) / 256, 256, 0, stream>>>(x, xbh, xbl);
    cvtT<<<dim3(CL / 32, NF / 32), dim3(32, 8), 0, stream>>>(fcW, fcWth, fcWtl, NF, CL);
    cvtT<<<dim3(CL / 32, ZD / 32), dim3(32, 8), 0, stream>>>(featW, featWth, featWtl, ZD, CL);
    cvtT<<<dim3(2, 16), dim3(32, 8), 0, stream>>>(fc1W, fc1Wth, fc1Wtl, 512, 64);

    // h0 = x @ fc_W + fc_b  (hi/lo MFMA, split output, layer-0 BN stats fused)
    gemm_hl<0, true, true, true><<<dim3(CL / 64, NN / 128), 256, 0, stream>>>(
        xbh, xbl, NF, fcWth, fcWtl, NF, nullptr, H0h, H0l, CL, fcb, NF,
        BNS3, BNS3 + 512);

    for (int i = 0; i < 3; ++i) {
        const unsigned short* Ah = (i == 0) ? H0h : (Zh + (size_t)(i - 1) * CL);
        const unsigned short* Al = (i == 0) ? H0l : (Zl + (size_t)(i - 1) * CL);
        int lda = (i == 0) ? CL : ZD;
        float* sums = BNS3 + i * 1024;
        float* sqs  = sums + 512;
        wscaleT<<<dim3(CL / 32, CL / 32), dim3(32, 8), 0, stream>>>(
            convW + (size_t)i * CL * CL, sums, sqs, bng + i * CL, convWsh, convWsl, CL, CL);
        bias_dot<<<CL / 64, 256, 0, stream>>>(convW + (size_t)i * CL * CL, sums, sqs,
                                              bng + i * CL, bnb + i * CL, B2, CL, CL);
        gemm_hl<0, true, false, false><<<dim3(CL / 64, NN / 128), 256, 0, stream>>>(
            Ah, Al, lda, convWsh, convWsl, CL, H2, nullptr, nullptr, CL, B2, CL,
            nullptr, nullptr);
        if (i < 2)
            gcn_mfma<true><<<dim3(NG, CL / 64), 256, 0, stream>>>(
                Amat, H2, convb + i * CL, Zh + (size_t)i * CL, Zl + (size_t)i * CL,
                BNS3 + (i + 1) * 1024, BNS3 + (i + 1) * 1024 + 512);
        else
            gcn_mfma<false><<<dim3(NG, CL / 64), 256, 0, stream>>>(
                Amat, H2, convb + i * CL, Zh + (size_t)i * CL, Zl + (size_t)i * CL,
                nullptr, nullptr);
    }

    // edge reconstruction loss via per-graph Gram matrices (MFMA)
    gram_mfma<<<NG, 256, 0, stream>>>(Zh, Zl, Gram);
    edge_loss<<<128, 256, 0, stream>>>(ei, ei + NE, Gram, LOSS, LOSS + 128, 0);
    edge_loss<<<128, 256, 0, stream>>>(nei, nei + NE, Gram, LOSS + 256, LOSS + 384, 1);
    lrc_final<<<1, 128, 0, stream>>>(LOSS, out + 1280);

    // xh = z @ feat_W  (hi/lo MFMA, f32 out into old H0 region)
    gemm_hl<0, false, false, false><<<dim3(CL / 64, NN / 128), 256, 0, stream>>>(
        Zh, Zl, ZD, featWth, featWtl, ZD, XH, nullptr, nullptr, CL, nullptr, ZD,
        nullptr, nullptr);

    // fused s12 + attention aggregation (MFMA), hi/lo bf16 AGG out
    attn_fused<<<dim3(NG, 8), 256, 0, stream>>>(XH, phi, AGGh, AGGl);

    // hid = leaky_relu(agg @ fc1 + b)  (hi/lo MFMA)
    gemm_hl<2, true, false, false><<<dim3(1, NN / 128), 256, 0, stream>>>(
        AGGh, AGGl, CL, fc1Wth, fc1Wtl, CL, HID, nullptr, nullptr, 64, fc1b, CL,
        nullptr, nullptr);
    head_kernel<<<NN / 256, 256, 0, stream>>>(HID, fc2W, fc2b, out + 1281);
    yp_kernel<<<NG, 64, 0, stream>>>(out + 1281, out);
}

// Round 7
// 334.960 us; speedup vs baseline: 2.8982x; 1.2521x over previous
//
#include <hip/hip_runtime.h>

#define NN 8192      // nodes
#define NG 128       // graphs
#define NF 128       // input feats
#define CL 512       // hidden dim
#define ZD 1536      // concat dim (3*512)
#define NE 262144    // edges per edge set

typedef __attribute__((ext_vector_type(8))) _Float16 half8;
typedef __attribute__((ext_vector_type(4))) float f32x4;

__device__ __forceinline__ _Float16 f2h(float f) { return (_Float16)f; }

// ---------------- degree / dense adjacency ----------------
__global__ void deg_kernel(const int* __restrict__ dst, float* __restrict__ deg) {
    int e = blockIdx.x * 256 + threadIdx.x;
    atomicAdd(&deg[dst[e]], 1.0f);
}

__global__ void deg_finish(float* __restrict__ deg, float* __restrict__ dinv) {
    int n = blockIdx.x * 256 + threadIdx.x;
    float d = deg[n] + 1.0f;
    deg[n] = d;
    dinv[n] = rsqrtf(d);
}

__global__ void build_adj(const int* __restrict__ src, const int* __restrict__ dst,
                          const float* __restrict__ dinv, float* __restrict__ A) {
    int e = blockIdx.x * 256 + threadIdx.x;
    int s = src[e], d = dst[e];
    int g = d >> 6;
    atomicAdd(&A[(size_t)((g << 6) + (d & 63)) * 64 + (s & 63)], dinv[s] * dinv[d]);
}

__global__ void adj_diag(const float* __restrict__ deg, float* __restrict__ A) {
    int n = blockIdx.x * 256 + threadIdx.x;
    int g = n >> 6, i = n & 63;
    A[(size_t)(g * 64 + i) * 64 + i] += 1.0f / deg[n];
}

// ---------------- conversions (f32 -> f16) ----------------
__global__ void cvt_h(const float* __restrict__ in, _Float16* __restrict__ out) {
    int i = blockIdx.x * 256 + threadIdx.x;
    float4 a = *(const float4*)(in + (size_t)i * 8);
    float4 b = *(const float4*)(in + (size_t)i * 8 + 4);
    half8 o;
    o[0] = (_Float16)a.x; o[1] = (_Float16)a.y; o[2] = (_Float16)a.z; o[3] = (_Float16)a.w;
    o[4] = (_Float16)b.x; o[5] = (_Float16)b.y; o[6] = (_Float16)b.z; o[7] = (_Float16)b.w;
    *(half8*)(out + (size_t)i * 8) = o;
}

// W: Kd x Nd row-major f32 -> Wt: Nd x Kd row-major f16
__global__ void cvtT(const float* __restrict__ W, _Float16* __restrict__ Wt,
                     int Kd, int Nd) {
    __shared__ float t[32][33];
    int kb = blockIdx.y * 32, nb = blockIdx.x * 32;
    int tx = threadIdx.x, ty = threadIdx.y;   // 32 x 8
    for (int i = ty; i < 32; i += 8)
        t[i][tx] = W[(size_t)(kb + i) * Nd + nb + tx];
    __syncthreads();
    for (int i = ty; i < 32; i += 8)
        Wt[(size_t)(nb + i) * Kd + kb + tx] = (_Float16)t[tx][i];
}

// scaled transpose with inline BN coef: Wt[n][k] = W[k][n] * s[k], s = g*rsqrt(var+eps)
__global__ void wscaleT(const float* __restrict__ W,
                        const float* __restrict__ sums, const float* __restrict__ sqs,
                        const float* __restrict__ g,
                        _Float16* __restrict__ Wt, int Kd, int Nd) {
    __shared__ float t[32][33];
    int kb = blockIdx.y * 32, nb = blockIdx.x * 32;
    int tx = threadIdx.x, ty = threadIdx.y;
    for (int i = ty; i < 32; i += 8)
        t[i][tx] = W[(size_t)(kb + i) * Nd + nb + tx];
    __syncthreads();
    int kc = kb + tx;
    float m = sums[kc] * (1.0f / NN);
    float var = sqs[kc] * (1.0f / NN) - m * m;
    float sc = rsqrtf(var + 1e-5f) * g[kc];
    for (int i = ty; i < 32; i += 8)
        Wt[(size_t)(nb + i) * Kd + kb + tx] = (_Float16)(t[tx][i] * sc);
}

// bias2[n] = sum_k t[k]*W[k][n], t = b - m*s. grid (Nd/64), 256 thr, 4-way k-split.
__global__ void bias_dot(const float* __restrict__ W,
                         const float* __restrict__ sums, const float* __restrict__ sqs,
                         const float* __restrict__ g, const float* __restrict__ b,
                         float* __restrict__ bias2, int Kd, int Nd) {
    __shared__ float red[256];
    int n = blockIdx.x * 64 + (threadIdx.x & 63);
    int kp = threadIdx.x >> 6;
    float acc = 0.f;
    for (int k = kp; k < Kd; k += 4) {
        float m = sums[k] * (1.0f / NN);
        float var = sqs[k] * (1.0f / NN) - m * m;
        float sc = rsqrtf(var + 1e-5f) * g[k];
        float tk = b[k] - m * sc;
        acc = fmaf(tk, W[(size_t)k * Nd + n], acc);
    }
    red[threadIdx.x] = acc;
    __syncthreads();
    if (threadIdx.x < 64)
        bias2[n] = red[threadIdx.x] + red[threadIdx.x + 64] +
                   red[threadIdx.x + 128] + red[threadIdx.x + 192];
}

// ---------------- f16 MFMA GEMM: C = A @ Bt^T, 128x64 tile ----------------
// XCD-aware swizzle: the gridDim.x N-tiles sharing one A-panel map to the SAME XCD.
// OUT16: write f16 C. STATS: per-column sum/sumsq of f32 C via atomics (BN fold).
template<int ACT, bool HASB, bool OUT16, bool STATS>
__global__ __launch_bounds__(256)
void gemm_f16(const _Float16* __restrict__ A, int lda,
              const _Float16* __restrict__ Bt, int ldb,
              float* __restrict__ Cf, _Float16* __restrict__ Ch,
              int ldc, const float* __restrict__ bias, int K,
              float* __restrict__ sums, float* __restrict__ sqs)
{
    __shared__ _Float16 As[4096];   // [128][32]
    __shared__ _Float16 Bs[2048];   // [64][32]
    const int tid = threadIdx.x;
    const int lane = tid & 63, wave = tid >> 6;
    const int wr = wave >> 1, wc = wave & 1;
    // XCD swizzle (bijective; total blocks % 8 == 0)
    const int ntile = gridDim.x;
    const int li = blockIdx.y * ntile + blockIdx.x;
    const int x8 = li & 7, rest = li >> 3;
    const int bt = rest % ntile;
    const int bp = (rest / ntile) * 8 + x8;
    const int bm = bp * 128, bn = bt * 64;

    f32x4 acc[4][2];
    #pragma unroll
    for (int m = 0; m < 4; ++m)
        #pragma unroll
        for (int n = 0; n < 2; ++n)
            acc[m][n] = (f32x4){0.f, 0.f, 0.f, 0.f};

    const int lrow = lane >> 2;
    const int lkb  = (lane & 3) * 8;

    for (int k0 = 0; k0 < K; k0 += 32) {
        #pragma unroll
        for (int c = 0; c < 2; ++c) {
            int chunk = wave * 2 + c;              // 0..7
            int row = chunk * 16 + lrow;
            size_t offA = (size_t)(bm + row) * lda + k0 + lkb;
            __builtin_amdgcn_global_load_lds(
                (const __attribute__((address_space(1))) void*)(A + offA),
                (__attribute__((address_space(3))) void*)&As[chunk * 512], 16, 0, 0);
        }
        {
            int rowb = wave * 16 + lrow;
            size_t offB = (size_t)(bn + rowb) * ldb + k0 + lkb;
            __builtin_amdgcn_global_load_lds(
                (const __attribute__((address_space(1))) void*)(Bt + offB),
                (__attribute__((address_space(3))) void*)&Bs[wave * 512], 16, 0, 0);
        }
        __syncthreads();
        const int fl = lane & 15, kh = (lane >> 4) * 8;
        half8 av[4], bv[2];
        #pragma unroll
        for (int m = 0; m < 4; ++m)
            av[m] = *(const half8*)&As[(wr * 64 + m * 16 + fl) * 32 + kh];
        #pragma unroll
        for (int n = 0; n < 2; ++n)
            bv[n] = *(const half8*)&Bs[(wc * 32 + n * 16 + fl) * 32 + kh];
        #pragma unroll
        for (int m = 0; m < 4; ++m)
            #pragma unroll
            for (int n = 0; n < 2; ++n)
                acc[m][n] = __builtin_amdgcn_mfma_f32_16x16x32_f16(av[m], bv[n], acc[m][n], 0, 0, 0);
        __syncthreads();
    }
    const int orow0 = (lane >> 4) * 4;
    const int ocol  = lane & 15;
    #pragma unroll
    for (int n = 0; n < 2; ++n) {
        int col = bn + wc * 32 + n * 16 + ocol;
        float bb = HASB ? bias[col] : 0.f;
        float ss = 0.f, qq = 0.f;
        #pragma unroll
        for (int m = 0; m < 4; ++m) {
            #pragma unroll
            for (int r = 0; r < 4; ++r) {
                int rowg = bm + wr * 64 + m * 16 + orow0 + r;
                float v = acc[m][n][r] + bb;
                if (ACT == 2) v = v > 0.f ? v : 0.01f * v;
                if (STATS) { ss += v; qq = fmaf(v, v, qq); }
                if (OUT16) Ch[(size_t)rowg * ldc + col] = (_Float16)v;
                else       Cf[(size_t)rowg * ldc + col] = v;
            }
        }
        if (STATS) {
            ss += __shfl_down(ss, 32); ss += __shfl_down(ss, 16);
            qq += __shfl_down(qq, 32); qq += __shfl_down(qq, 16);
            if (lane < 16) {
                atomicAdd(&sums[col], ss);
                atomicAdd(&sqs[col], qq);
            }
        }
    }
}

// ---------------- GCN combine via MFMA: Z = relu(A_g @ H2_g + b), f16 out ----------------
// grid (NG, CL/64). A f32 -> f16 LDS; H2 f16 -> transposed f16 LDS. STATS for next BN.
template<bool STATS>
__global__ __launch_bounds__(256)
void gcn_mfma(const float* __restrict__ Amat, const _Float16* __restrict__ H2,
              const float* __restrict__ bias, _Float16* __restrict__ outz,
              float* __restrict__ sums, float* __restrict__ sqs)
{
    const int g = blockIdx.x, ct = blockIdx.y;
    __shared__ _Float16 As[4096];   // [i][s] swizzled
    __shared__ _Float16 Xs[4096];   // [c][s] swizzled (H2^T)
    __shared__ float Cs[64 * 68];
    const int tid = threadIdx.x;
    {
        const int i = tid >> 2, sq = tid & 3;
        const float* ar = Amat + (size_t)g * 4096 + i * 64 + sq * 16;
        #pragma unroll
        for (int j = 0; j < 4; ++j) {
            float4 v = *(const float4*)(ar + j * 4);
            float vv[4] = {v.x, v.y, v.z, v.w};
            #pragma unroll
            for (int e = 0; e < 4; ++e) {
                int s = sq * 16 + j * 4 + e;
                As[(i * 64 + s) ^ ((i & 7) << 3)] = (_Float16)vv[e];
            }
        }
    }
    {
        const int s = tid >> 2, dq = tid & 3;
        const _Float16* hr = H2 + (size_t)(g * 64 + s) * CL + ct * 64 + dq * 16;
        #pragma unroll
        for (int j = 0; j < 2; ++j) {
            half8 v = *(const half8*)(hr + j * 8);
            #pragma unroll
            for (int e = 0; e < 8; ++e) {
                int c = dq * 16 + j * 8 + e;
                Xs[(c * 64 + s) ^ ((c & 7) << 3)] = v[e];
            }
        }
    }
    __syncthreads();
    const int lane = tid & 63, wave = tid >> 6;
    const int fl = lane & 15, kh = (lane >> 4) * 8;
    f32x4 acc[4];
    #pragma unroll
    for (int n = 0; n < 4; ++n) acc[n] = (f32x4){0.f, 0.f, 0.f, 0.f};
    #pragma unroll
    for (int kc = 0; kc < 2; ++kc) {
        int rowa = wave * 16 + fl;
        half8 av = *(const half8*)&As[(rowa * 64 + kc * 32 + kh) ^ ((rowa & 7) << 3)];
        #pragma unroll
        for (int n = 0; n < 4; ++n) {
            int rowb = n * 16 + fl;
            half8 bv = *(const half8*)&Xs[(rowb * 64 + kc * 32 + kh) ^ ((rowb & 7) << 3)];
            acc[n] = __builtin_amdgcn_mfma_f32_16x16x32_f16(av, bv, acc[n], 0, 0, 0);
        }
    }
    const int orow0 = (lane >> 4) * 4, ocol = lane & 15;
    #pragma unroll
    for (int n = 0; n < 4; ++n)
        #pragma unroll
        for (int r = 0; r < 4; ++r)
            Cs[(wave * 16 + orow0 + r) * 68 + n * 16 + ocol] = acc[n][r];
    __syncthreads();
    {
        const int rr = tid >> 3, dq = tid & 7;
        #pragma unroll
        for (int half = 0; half < 2; ++half) {
            int nd = half * 32 + rr;
            half8 hv;
            #pragma unroll
            for (int e = 0; e < 8; ++e) {
                float v = Cs[nd * 68 + dq * 8 + e] + bias[ct * 64 + dq * 8 + e];
                v = v > 0.f ? v : 0.f;
                hv[e] = (_Float16)v;
            }
            *(half8*)(outz + (size_t)(g * 64 + nd) * ZD + ct * 64 + dq * 8) = hv;
        }
    }
    if (STATS && tid < 64) {
        float bb = bias[ct * 64 + tid];
        float ss = 0.f, qq = 0.f;
        for (int row = 0; row < 64; ++row) {
            float v = Cs[row * 68 + tid] + bb;
            v = v > 0.f ? v : 0.f;
            ss += v;
            qq = fmaf(v, v, qq);
        }
        atomicAdd(&sums[ct * 64 + tid], ss);
        atomicAdd(&sqs[ct * 64 + tid], qq);
    }
}

// ---------------- per-graph Gram matrix G = Z_g Z_g^T via f16 MFMA ----------------
__global__ __launch_bounds__(256)
void gram_mfma(const _Float16* __restrict__ Z, float* __restrict__ G)
{
    __shared__ _Float16 Zs[2048];   // [64][32]
    const int g = blockIdx.x;
    const int tid = threadIdx.x;
    const int lane = tid & 63, wave = tid >> 6;
    const int lrow = lane >> 2, lkb = (lane & 3) * 8;

    f32x4 acc[4];
    #pragma unroll
    for (int n = 0; n < 4; ++n) acc[n] = (f32x4){0.f, 0.f, 0.f, 0.f};

    for (int k0 = 0; k0 < ZD; k0 += 32) {
        int row = wave * 16 + lrow;
        size_t off = (size_t)(g * 64 + row) * ZD + k0 + lkb;
        __builtin_amdgcn_global_load_lds(
            (const __attribute__((address_space(1))) void*)(Z + off),
            (__attribute__((address_space(3))) void*)&Zs[wave * 512], 16, 0, 0);
        __syncthreads();
        const int fl = lane & 15, kh = (lane >> 4) * 8;
        half8 av = *(const half8*)&Zs[(wave * 16 + fl) * 32 + kh];
        #pragma unroll
        for (int n = 0; n < 4; ++n) {
            half8 bv = *(const half8*)&Zs[(n * 16 + fl) * 32 + kh];
            acc[n] = __builtin_amdgcn_mfma_f32_16x16x32_f16(av, bv, acc[n], 0, 0, 0);
        }
        __syncthreads();
    }
    const int orow0 = (lane >> 4) * 4;
    const int ocol  = lane & 15;
    #pragma unroll
    for (int n = 0; n < 4; ++n)
        #pragma unroll
        for (int r = 0; r < 4; ++r)
            G[(size_t)(g * 64 + wave * 16 + orow0 + r) * 64 + n * 16 + ocol] = acc[n][r];
}

// ---------------- edge loss (both sets in one launch; grid (128, 2)) ----------------
__global__ void edge_loss2(const int* __restrict__ ei, const int* __restrict__ nei,
                           const float* __restrict__ G, float* __restrict__ LOSS)
{
    const int setid = blockIdx.y;
    const int* e0 = setid ? nei : ei;
    const int* e1 = e0 + NE;
    float* tot = LOSS + setid * 256;
    float* cnt = tot + 128;
    __shared__ float lt[128];
    __shared__ float lc[128];
    int tid = threadIdx.x;
    if (tid < 128) { lt[tid] = 0.f; lc[tid] = 0.f; }
    __syncthreads();
    for (int e = blockIdx.x * blockDim.x + tid; e < NE; e += gridDim.x * blockDim.x) {
        int a = e0[e], b = e1[e];
        int g = a >> 6;
        float v = G[(size_t)((g << 6) + (a & 63)) * 64 + (b & 63)];
        float s = 1.f / (1.f + expf(-v));
        float p = setid ? (1.f - s) : s;
        float l = -logf(1e-4f + p);
        atomicAdd(&lt[g], l);
        atomicAdd(&lc[g], 1.f);
    }
    __syncthreads();
    if (tid < 128) {
        atomicAdd(&tot[tid], lt[tid]);
        atomicAdd(&cnt[tid], lc[tid]);
    }
}

__global__ void lrc_final(const float* __restrict__ loss, float* __restrict__ out)
{
    int t = threadIdx.x;
    float v = loss[t] / fmaxf(loss[128 + t], 1.f) + loss[256 + t] / fmaxf(loss[384 + t], 1.f);
    __shared__ float red[128];
    red[t] = v;
    __syncthreads();
    for (int s = 64; s; s >>= 1) {
        if (t < s) red[t] += red[t + s];
        __syncthreads();
    }
    if (t == 0) out[0] = red[0] * (1.0f / 128.0f);
}

// ---------------- fused attention: s1/s2 + w + agg, per (graph, head), MFMA ----------------
__global__ __launch_bounds__(256)
void attn_fused(const _Float16* __restrict__ xh, const float* __restrict__ phi,
                _Float16* __restrict__ agg)
{
    const int g = blockIdx.x, h = blockIdx.y;
    __shared__ _Float16 Xt[4096];   // [d][b] swizzled
    __shared__ _Float16 Ws[4096];   // [i][b] swizzled
    __shared__ float Cs[64 * 68];
    __shared__ float s1s[64], s2s[64];
    const int tid = threadIdx.x;
    {
        const int b = tid >> 2, dq = tid & 3;
        const _Float16* xr = xh + (size_t)(g * 64 + b) * CL + h * 64 + dq * 16;
        const float* pa = phi + h * 128 + dq * 16;
        const float* pb = pa + 64;
        float sa = 0.f, sb = 0.f;
        #pragma unroll
        for (int j = 0; j < 2; ++j) {
            half8 v = *(const half8*)(xr + j * 8);
            float4 A4 = *(const float4*)(pa + j * 8);
            float4 A5 = *(const float4*)(pa + j * 8 + 4);
            float4 B4 = *(const float4*)(pb + j * 8);
            float4 B5 = *(const float4*)(pb + j * 8 + 4);
            float aa[8] = {A4.x, A4.y, A4.z, A4.w, A5.x, A5.y, A5.z, A5.w};
            float bb[8] = {B4.x, B4.y, B4.z, B4.w, B5.x, B5.y, B5.z, B5.w};
            #pragma unroll
            for (int e = 0; e < 8; ++e) {
                int d = dq * 16 + j * 8 + e;
                float vf = (float)v[e];
                Xt[(d * 64 + b) ^ ((d & 7) << 3)] = v[e];
                sa = fmaf(vf, aa[e], sa);
                sb = fmaf(vf, bb[e], sb);
            }
        }
        sa += __shfl_down(sa, 2); sa += __shfl_down(sa, 1);
        sb += __shfl_down(sb, 2); sb += __shfl_down(sb, 1);
        if (dq == 0) { s1s[b] = sa; s2s[b] = sb; }
    }
    __syncthreads();
    {
        const int i = tid >> 2, bq = tid & 3;
        float si = s1s[i];
        #pragma unroll
        for (int e = 0; e < 16; ++e) {
            int b = bq * 16 + e;
            float t = si + s2s[b];
            t = t > 0.f ? t : 0.01f * t;
            float w = 1.f / (1.f + expf(-t));
            Ws[(i * 64 + b) ^ ((i & 7) << 3)] = (_Float16)w;
        }
    }
    __syncthreads();
    const int lane = tid & 63, wave = tid >> 6;
    const int fl = lane & 15, kh = (lane >> 4) * 8;
    f32x4 acc[4];
    #pragma unroll
    for (int n = 0; n < 4; ++n) acc[n] = (f32x4){0.f, 0.f, 0.f, 0.f};
    #pragma unroll
    for (int kc = 0; kc < 2; ++kc) {
        int rowa = wave * 16 + fl;
        half8 av = *(const half8*)&Ws[(rowa * 64 + kc * 32 + kh) ^ ((rowa & 7) << 3)];
        #pragma unroll
        for (int n = 0; n < 4; ++n) {
            int rowb = n * 16 + fl;
            half8 bv = *(const half8*)&Xt[(rowb * 64 + kc * 32 + kh) ^ ((rowb & 7) << 3)];
            acc[n] = __builtin_amdgcn_mfma_f32_16x16x32_f16(av, bv, acc[n], 0, 0, 0);
        }
    }
    const int orow0 = (lane >> 4) * 4, ocol = lane & 15;
    #pragma unroll
    for (int n = 0; n < 4; ++n)
        #pragma unroll
        for (int r = 0; r < 4; ++r)
            Cs[(wave * 16 + orow0 + r) * 68 + n * 16 + ocol] = acc[n][r];
    __syncthreads();
    {
        const int rr = tid >> 3, dq = tid & 7;
        #pragma unroll
        for (int half = 0; half < 2; ++half) {
            int nd = half * 32 + rr;
            half8 hv;
            #pragma unroll
            for (int e = 0; e < 8; ++e)
                hv[e] = (_Float16)Cs[nd * 68 + dq * 8 + e];
            *(half8*)(agg + (size_t)(g * 64 + nd) * CL + h * 64 + dq * 8) = hv;
        }
    }
}

// ---------------- classifier head + per-graph mean (fused) ----------------
// grid NG, 64 threads: each lane one node; wave-reduce preds for log(yp).
__global__ void head_yp(const float* __restrict__ hid, const float* __restrict__ fc2W,
                        const float* __restrict__ fc2b,
                        float* __restrict__ preds, float* __restrict__ outlog)
{
    int g = blockIdx.x, lane = threadIdx.x;
    int n = g * 64 + lane;
    const float* hr = hid + (size_t)n * 64;
    float x[64];
    #pragma unroll
    for (int k = 0; k < 64; ++k) x[k] = hr[k];
    float lg[10];
    float mx = -1e30f;
    #pragma unroll
    for (int c = 0; c < 10; ++c) {
        float s = fc2b[c];
        #pragma unroll
        for (int k = 0; k < 64; ++k) s = fmaf(x[k], fc2W[k * 10 + c], s);
        lg[c] = s;
        mx = fmaxf(mx, s);
    }
    float sum = 0.f;
    #pragma unroll
    for (int c = 0; c < 10; ++c) {
        float t = expf(lg[c] - mx) + 1e-4f;
        lg[c] = t;
        sum += t;
    }
    float inv = 1.f / sum;
    #pragma unroll
    for (int c = 0; c < 10; ++c) {
        lg[c] *= inv;
        preds[(size_t)n * 10 + c] = lg[c];
    }
    #pragma unroll
    for (int off = 32; off; off >>= 1)
        #pragma unroll
        for (int c = 0; c < 10; ++c) lg[c] += __shfl_down(lg[c], off);
    if (lane == 0)
        #pragma unroll
        for (int c = 0; c < 10; ++c) outlog[g * 10 + c] = logf(lg[c] * (1.0f / 64.0f));
}

extern "C" void kernel_launch(void* const* d_in, const int* in_sizes, int n_in,
                              void* d_out, int out_size, void* d_ws, size_t ws_size,
                              hipStream_t stream)
{
    (void)in_sizes; (void)n_in; (void)out_size; (void)ws_size;
    const float* x     = (const float*)d_in[0];
    const int*   ei    = (const int*)d_in[1];
    const int*   nei   = (const int*)d_in[2];
    const float* fcW   = (const float*)d_in[5];
    const float* fcb   = (const float*)d_in[6];
    const float* bng   = (const float*)d_in[7];
    const float* bnb   = (const float*)d_in[8];
    const float* convW = (const float*)d_in[9];
    const float* convb = (const float*)d_in[10];
    const float* featW = (const float*)d_in[11];
    const float* phi   = (const float*)d_in[12];
    const float* fc1W  = (const float*)d_in[13];
    const float* fc1b  = (const float*)d_in[14];
    const float* fc2W  = (const float*)d_in[15];
    const float* fc2b  = (const float*)d_in[16];
    float* out = (float*)d_out;

    char* ws = (char*)d_ws;
    _Float16* Z       = (_Float16*)(ws);              // 24 MB -> 25165824
    _Float16* H0      = (_Float16*)(ws + 25165824);   // 8 MB  -> 33554432 (XH later)
    _Float16* H2      = (_Float16*)(ws + 33554432);   // 8 MB  -> 41943040 (AGG later)
    _Float16* xb      = (_Float16*)(ws + 41943040);   // 2 MB  -> 44040192
    _Float16* fcWt    = (_Float16*)(ws + 44040192);   // 128 KB -> 44171264
    _Float16* convWs  = (_Float16*)(ws + 44171264);   // 512 KB -> 44695552
    _Float16* featWt  = (_Float16*)(ws + 44695552);   // 1.5 MB -> 46268416
    _Float16* fc1Wt   = (_Float16*)(ws + 46268416);   // 64 KB -> 46333952
    float*    Gram    = (float*)(ws + 46333952);      // 2 MB  -> 48431104
    float*    DINV    = (float*)(ws + 48431104);      // 32 KB -> 48463872
    float*    HID     = (float*)(ws + 48463872);      // 2 MB  -> 50561024
    // zeroed region: DEG + Amat + LOSS + BNS3
    float*    DEG     = (float*)(ws + 50561024);      // 32 KB -> 50593792
    float*    Amat    = (float*)(ws + 50593792);      // 2 MB  -> 52690944
    float*    LOSS    = (float*)(ws + 52690944);      // 2 KB  -> 52692992
    float*    BNS3    = (float*)(ws + 52692992);      // 12 KB -> 52705280
    float*    B2      = (float*)(ws + 52705280);      // 2 KB
    _Float16* XH      = H0;
    _Float16* AGG     = H2;

    const int* src = ei;
    const int* dst = ei + NE;

    hipMemsetAsync(DEG, 0, 52705280 - 50561024, stream);

    deg_kernel<<<NE / 256, 256, 0, stream>>>(dst, DEG);
    deg_finish<<<NN / 256, 256, 0, stream>>>(DEG, DINV);
    build_adj<<<NE / 256, 256, 0, stream>>>(src, dst, DINV, Amat);
    adj_diag<<<NN / 256, 256, 0, stream>>>(DEG, Amat);

    // f16 conversions
    cvt_h<<<(NN * NF / 8) / 256, 256, 0, stream>>>(x, xb);
    cvtT<<<dim3(CL / 32, NF / 32), dim3(32, 8), 0, stream>>>(fcW, fcWt, NF, CL);
    cvtT<<<dim3(CL / 32, ZD / 32), dim3(32, 8), 0, stream>>>(featW, featWt, ZD, CL);
    cvtT<<<dim3(2, 16), dim3(32, 8), 0, stream>>>(fc1W, fc1Wt, 512, 64);

    // h0 = x @ fc_W + fc_b  (f16 MFMA, f16 out, layer-0 BN stats fused)
    gemm_f16<0, true, true, true><<<dim3(CL / 64, NN / 128), 256, 0, stream>>>(
        xb, NF, fcWt, NF, nullptr, H0, CL, fcb, NF, BNS3, BNS3 + 512);

    for (int i = 0; i < 3; ++i) {
        const _Float16* Ain = (i == 0) ? H0 : (Z + (size_t)(i - 1) * CL);
        int lda = (i == 0) ? CL : ZD;
        float* sums = BNS3 + i * 1024;
        float* sqs  = sums + 512;
        wscaleT<<<dim3(CL / 32, CL / 32), dim3(32, 8), 0, stream>>>(
            convW + (size_t)i * CL * CL, sums, sqs, bng + i * CL, convWs, CL, CL);
        bias_dot<<<CL / 64, 256, 0, stream>>>(convW + (size_t)i * CL * CL, sums, sqs,
                                              bng + i * CL, bnb + i * CL, B2, CL, CL);
        gemm_f16<0, true, true, false><<<dim3(CL / 64, NN / 128), 256, 0, stream>>>(
            Ain, lda, convWs, CL, nullptr, H2, CL, B2, CL, nullptr, nullptr);
        if (i < 2)
            gcn_mfma<true><<<dim3(NG, CL / 64), 256, 0, stream>>>(
                Amat, H2, convb + i * CL, Z + (size_t)i * CL,
                BNS3 + (i + 1) * 1024, BNS3 + (i + 1) * 1024 + 512);
        else
            gcn_mfma<false><<<dim3(NG, CL / 64), 256, 0, stream>>>(
                Amat, H2, convb + i * CL, Z + (size_t)i * CL, nullptr, nullptr);
    }

    // edge reconstruction loss via per-graph Gram matrices (MFMA)
    gram_mfma<<<NG, 256, 0, stream>>>(Z, Gram);
    edge_loss2<<<dim3(128, 2), 256, 0, stream>>>(ei, nei, Gram, LOSS);
    lrc_final<<<1, 128, 0, stream>>>(LOSS, out + 1280);

    // xh = z @ feat_W  (f16 MFMA, f16 out into H0 region)
    gemm_f16<0, false, true, false><<<dim3(CL / 64, NN / 128), 256, 0, stream>>>(
        Z, ZD, featWt, ZD, nullptr, XH, CL, nullptr, ZD, nullptr, nullptr);

    // fused s12 + attention aggregation (MFMA), f16 AGG out
    attn_fused<<<dim3(NG, 8), 256, 0, stream>>>(XH, phi, AGG);

    // hid = leaky_relu(agg @ fc1 + b)  (f16 MFMA, f32 out)
    gemm_f16<2, true, false, false><<<dim3(1, NN / 128), 256, 0, stream>>>(
        AGG, CL, fc1Wt, CL, HID, nullptr, 64, fc1b, CL, nullptr, nullptr);

    // head + per-graph mean (fused)
    head_yp<<<NG, 64, 0, stream>>>(HID, fc2W, fc2b, out + 1281, out);
}

// Round 8
// 196.507 us; speedup vs baseline: 4.9402x; 1.7046x over previous
//
#include <hip/hip_runtime.h>

#define NN 8192      // nodes
#define NG 128       // graphs
#define NF 128       // input feats
#define CL 512       // hidden dim
#define ZD 1536      // concat dim (3*512)
#define NE 262144    // edges per edge set

typedef __attribute__((ext_vector_type(8))) _Float16 half8;
typedef __attribute__((ext_vector_type(4))) float f32x4;

// ---------------- degree / dense adjacency ----------------
__global__ void deg_kernel(const int* __restrict__ dst, float* __restrict__ deg) {
    int e = blockIdx.x * 256 + threadIdx.x;
    atomicAdd(&deg[dst[e]], 1.0f);
}

__global__ void deg_finish(float* __restrict__ deg, float* __restrict__ dinv) {
    int n = blockIdx.x * 256 + threadIdx.x;
    float d = deg[n] + 1.0f;
    deg[n] = d;
    dinv[n] = rsqrtf(d);
}

__global__ void build_adj(const int* __restrict__ src, const int* __restrict__ dst,
                          const float* __restrict__ dinv, float* __restrict__ A) {
    int e = blockIdx.x * 256 + threadIdx.x;
    int s = src[e], d = dst[e];
    int g = d >> 6;
    atomicAdd(&A[(size_t)((g << 6) + (d & 63)) * 64 + (s & 63)], dinv[s] * dinv[d]);
}

__global__ void adj_diag(const float* __restrict__ deg, float* __restrict__ A) {
    int n = blockIdx.x * 256 + threadIdx.x;
    int g = n >> 6, i = n & 63;
    A[(size_t)(g * 64 + i) * 64 + i] += 1.0f / deg[n];
}

// Amat f32 [g][i][s] -> Ah f16 PRE-SWIZZLED: Ah[g*4096 + ((i*64+s) ^ ((i&7)<<3))]
__global__ void cvtA(const float* __restrict__ Amat, _Float16* __restrict__ Ah) {
    int t = blockIdx.x * 256 + threadIdx.x;      // 4 elems per thread
    int i4 = t * 4;
    int g = i4 >> 12, loc = i4 & 4095;
    float4 v = *(const float4*)(Amat + (size_t)g * 4096 + loc);
    float vv[4] = {v.x, v.y, v.z, v.w};
    int row = loc >> 6;
    int swz = (row & 7) << 3;
    #pragma unroll
    for (int e = 0; e < 4; ++e)
        Ah[(size_t)g * 4096 + ((loc + e) ^ swz)] = (_Float16)vv[e];
}

// ---------------- conversions (f32 -> f16) ----------------
__global__ void cvt_h(const float* __restrict__ in, _Float16* __restrict__ out) {
    int i = blockIdx.x * 256 + threadIdx.x;
    float4 a = *(const float4*)(in + (size_t)i * 8);
    float4 b = *(const float4*)(in + (size_t)i * 8 + 4);
    half8 o;
    o[0] = (_Float16)a.x; o[1] = (_Float16)a.y; o[2] = (_Float16)a.z; o[3] = (_Float16)a.w;
    o[4] = (_Float16)b.x; o[5] = (_Float16)b.y; o[6] = (_Float16)b.z; o[7] = (_Float16)b.w;
    *(half8*)(out + (size_t)i * 8) = o;
}

// W: Kd x Nd row-major f32 -> Wt: Nd x Kd row-major f16
__global__ void cvtT(const float* __restrict__ W, _Float16* __restrict__ Wt,
                     int Kd, int Nd) {
    __shared__ float t[32][33];
    int kb = blockIdx.y * 32, nb = blockIdx.x * 32;
    int tx = threadIdx.x, ty = threadIdx.y;   // 32 x 8
    for (int i = ty; i < 32; i += 8)
        t[i][tx] = W[(size_t)(kb + i) * Nd + nb + tx];
    __syncthreads();
    for (int i = ty; i < 32; i += 8)
        Wt[(size_t)(nb + i) * Kd + kb + tx] = (_Float16)t[tx][i];
}

// Fused BN-fold weight prep: Wt[n][k] = W[k][n]*s[k] (f16) AND bias2[n] += sum_k t[k]W[k][n]
__global__ void wprep(const float* __restrict__ W,
                      const float* __restrict__ sums, const float* __restrict__ sqs,
                      const float* __restrict__ g, const float* __restrict__ b,
                      _Float16* __restrict__ Wt, float* __restrict__ bias2,
                      int Kd, int Nd) {
    __shared__ float t[32][33];
    __shared__ float tks[32];
    int kb = blockIdx.y * 32, nb = blockIdx.x * 32;
    int tx = threadIdx.x, ty = threadIdx.y;   // 32 x 8
    for (int i = ty; i < 32; i += 8)
        t[i][tx] = W[(size_t)(kb + i) * Nd + nb + tx];
    int kc = kb + tx;
    float m = sums[kc] * (1.0f / NN);
    float var = sqs[kc] * (1.0f / NN) - m * m;
    float sc = rsqrtf(var + 1e-5f) * g[kc];
    if (ty == 0) tks[tx] = b[kc] - m * sc;
    __syncthreads();
    for (int i = ty; i < 32; i += 8)
        Wt[(size_t)(nb + i) * Kd + kb + tx] = (_Float16)(t[tx][i] * sc);
    if (ty == 0) {
        float acc = 0.f;
        #pragma unroll
        for (int i = 0; i < 32; ++i) acc = fmaf(tks[i], t[i][tx], acc);
        atomicAdd(&bias2[nb + tx], acc);
    }
}

// ---------------- f16 MFMA GEMM: C = A @ Bt^T, 128x64 tile, BK=64, XOR-swizzled LDS ---
// XCD-aware block swizzle. FUSE: per-graph GCN epilogue Z = relu(A_g @ C_g + cb), + stats.
template<int ACT, bool HASB, bool OUT16, bool STATS, bool FUSE>
__global__ __launch_bounds__(256)
void gemm_f16(const _Float16* __restrict__ A, int lda,
              const _Float16* __restrict__ Bt, int ldb,
              float* __restrict__ Cf, _Float16* __restrict__ Ch, int ldc,
              const float* __restrict__ bias, int K,
              float* __restrict__ sums, float* __restrict__ sqs,
              const _Float16* __restrict__ Ahg,   // pre-swizzled adjacency (FUSE)
              const float* __restrict__ cb,       // conv bias (FUSE)
              _Float16* __restrict__ Zout)        // Z base (FUSE), row stride ZD
{
    __shared__ __align__(16) char SMraw[FUSE ? 34816 : 24576];
    _Float16* As = (_Float16*)SMraw;              // [128][64]
    _Float16* Bs = (_Float16*)(SMraw + 16384);    // [64][64]
    const int tid = threadIdx.x;
    const int lane = tid & 63, wave = tid >> 6;
    const int wr = wave >> 1, wc = wave & 1;
    // XCD swizzle (bijective; total blocks % 8 == 0)
    const int ntile = gridDim.x;
    const int li = blockIdx.y * ntile + blockIdx.x;
    const int x8 = li & 7, rest = li >> 3;
    const int bt = rest % ntile;
    const int bp = (rest / ntile) * 8 + x8;
    const int bm = bp * 128, bn = bt * 64;

    f32x4 acc[4][2];
    #pragma unroll
    for (int m = 0; m < 4; ++m)
        #pragma unroll
        for (int n = 0; n < 2; ++n)
            acc[m][n] = (f32x4){0.f, 0.f, 0.f, 0.f};

    const int fl = lane & 15, kh = (lane >> 4) * 8;
    const int sw = (fl & 7) << 3;

    for (int k0 = 0; k0 < K; k0 += 64) {
        // A: 4 chunks/wave, dest linear, source k pre-swizzled by row
        #pragma unroll
        for (int j = 0; j < 4; ++j) {
            int d = wave * 2048 + j * 512 + lane * 8;
            int row = d >> 6, kk = d & 63;
            int sk = kk ^ ((row & 7) << 3);
            __builtin_amdgcn_global_load_lds(
                (const __attribute__((address_space(1))) void*)(A + (size_t)(bm + row) * lda + k0 + sk),
                (__attribute__((address_space(3))) void*)&As[wave * 2048 + j * 512], 16, 0, 0);
        }
        #pragma unroll
        for (int j = 0; j < 2; ++j) {
            int d = wave * 1024 + j * 512 + lane * 8;
            int row = d >> 6, kk = d & 63;
            int sk = kk ^ ((row & 7) << 3);
            __builtin_amdgcn_global_load_lds(
                (const __attribute__((address_space(1))) void*)(Bt + (size_t)(bn + row) * ldb + k0 + sk),
                (__attribute__((address_space(3))) void*)&Bs[wave * 1024 + j * 512], 16, 0, 0);
        }
        __syncthreads();
        #pragma unroll
        for (int kc = 0; kc < 2; ++kc) {
            int ko = (kc * 32 + kh) ^ sw;
            half8 av[4], bv[2];
            #pragma unroll
            for (int m = 0; m < 4; ++m)
                av[m] = *(const half8*)&As[(wr * 64 + m * 16 + fl) * 64 + ko];
            #pragma unroll
            for (int n = 0; n < 2; ++n)
                bv[n] = *(const half8*)&Bs[(wc * 32 + n * 16 + fl) * 64 + ko];
            #pragma unroll
            for (int m = 0; m < 4; ++m)
                #pragma unroll
                for (int n = 0; n < 2; ++n)
                    acc[m][n] = __builtin_amdgcn_mfma_f32_16x16x32_f16(av[m], bv[n], acc[m][n], 0, 0, 0);
        }
        __syncthreads();
    }

    const int orow0 = (lane >> 4) * 4;
    const int ocol  = lane & 15;

    if constexpr (!FUSE) {
        #pragma unroll
        for (int n = 0; n < 2; ++n) {
            int col = bn + wc * 32 + n * 16 + ocol;
            float bb = HASB ? bias[col] : 0.f;
            float ss = 0.f, qq = 0.f;
            #pragma unroll
            for (int m = 0; m < 4; ++m) {
                #pragma unroll
                for (int r = 0; r < 4; ++r) {
                    int rowg = bm + wr * 64 + m * 16 + orow0 + r;
                    float v = acc[m][n][r] + bb;
                    if (ACT == 2) v = v > 0.f ? v : 0.01f * v;
                    if (STATS) { ss += v; qq = fmaf(v, v, qq); }
                    if (OUT16) Ch[(size_t)rowg * ldc + col] = (_Float16)v;
                    else       Cf[(size_t)rowg * ldc + col] = v;
                }
            }
            if (STATS) {
                ss += __shfl_down(ss, 32); ss += __shfl_down(ss, 16);
                qq += __shfl_down(qq, 32); qq += __shfl_down(qq, 16);
                if (lane < 16) {
                    atomicAdd(&sums[col], ss);
                    atomicAdd(&sqs[col], qq);
                }
            }
        }
    } else {
        // ---- fused GCN epilogue: Z_g = relu(A_g @ (acc + bias) + cb) ----
        _Float16* AsA = (_Float16*)SMraw;            // [2][64][64] pre-swizzled adjacency
        _Float16* Xs  = (_Float16*)(SMraw + 16384);  // [64 cols][128 rows] swizzled C^T (f16)
        // stage adjacency for the block's 2 graphs (linear copy of pre-swizzled buffer)
        const _Float16* Ag = Ahg + (size_t)(bm >> 6) * 4096;
        #pragma unroll
        for (int j = 0; j < 4; ++j)
            __builtin_amdgcn_global_load_lds(
                (const __attribute__((address_space(1))) void*)(Ag + wave * 2048 + j * 512 + lane * 8),
                (__attribute__((address_space(3))) void*)&AsA[wave * 2048 + j * 512], 16, 0, 0);
        // write acc (+bias) -> Xs transposed f16
        #pragma unroll
        for (int n = 0; n < 2; ++n) {
            int c = wc * 32 + n * 16 + ocol;
            float bb = HASB ? bias[bn + c] : 0.f;
            int csw = (c & 7) << 3;
            #pragma unroll
            for (int m = 0; m < 4; ++m) {
                #pragma unroll
                for (int r = 0; r < 4; ++r) {
                    int srow = wr * 64 + m * 16 + orow0 + r;
                    Xs[c * 128 + (srow & 64) + ((srow & 63) ^ csw)] = (_Float16)(acc[m][n][r] + bb);
                }
            }
        }
        __syncthreads();
        // phase-2 MFMA: wave -> graph (wave>>1), row-half (wave&1)
        const int gg = wave >> 1, rh = wave & 1;
        f32x4 acc2[2][4];
        #pragma unroll
        for (int m2 = 0; m2 < 2; ++m2)
            #pragma unroll
            for (int n2 = 0; n2 < 4; ++n2)
                acc2[m2][n2] = (f32x4){0.f, 0.f, 0.f, 0.f};
        #pragma unroll
        for (int kc = 0; kc < 2; ++kc) {
            int ko = (kc * 32 + kh) ^ sw;
            #pragma unroll
            for (int m2 = 0; m2 < 2; ++m2) {
                int arow = rh * 32 + m2 * 16 + fl;
                half8 av = *(const half8*)&AsA[gg * 4096 + arow * 64 + ko];
                #pragma unroll
                for (int n2 = 0; n2 < 4; ++n2) {
                    int c = n2 * 16 + fl;
                    half8 bv = *(const half8*)&Xs[c * 128 + gg * 64 + ((kc * 32 + kh) ^ ((c & 7) << 3))];
                    acc2[m2][n2] = __builtin_amdgcn_mfma_f32_16x16x32_f16(av, bv, acc2[m2][n2], 0, 0, 0);
                }
            }
        }
        __syncthreads();
        float* Cs = (float*)SMraw;   // [128][68]
        #pragma unroll
        for (int m2 = 0; m2 < 2; ++m2)
            #pragma unroll
            for (int n2 = 0; n2 < 4; ++n2)
                #pragma unroll
                for (int r = 0; r < 4; ++r)
                    Cs[(gg * 64 + rh * 32 + m2 * 16 + orow0 + r) * 68 + n2 * 16 + ocol] = acc2[m2][n2][r];
        __syncthreads();
        // Z write (vectorized) + stats
        const int rr = tid >> 3, dq = tid & 7;
        #pragma unroll
        for (int pass = 0; pass < 4; ++pass) {
            int row = pass * 32 + rr;
            half8 hv;
            #pragma unroll
            for (int e = 0; e < 8; ++e) {
                float v = Cs[row * 68 + dq * 8 + e] + cb[bn + dq * 8 + e];
                v = v > 0.f ? v : 0.f;
                hv[e] = (_Float16)v;
            }
            *(half8*)(Zout + (size_t)(bm + row) * ZD + bn + dq * 8) = hv;
        }
        if (STATS && tid < 64) {
            float bb = cb[bn + tid];
            float ss = 0.f, qq = 0.f;
            for (int row = 0; row < 128; ++row) {
                float v = Cs[row * 68 + tid] + bb;
                v = v > 0.f ? v : 0.f;
                ss += v;
                qq = fmaf(v, v, qq);
            }
            atomicAdd(&sums[bn + tid], ss);
            atomicAdd(&sqs[bn + tid], qq);
        }
    }
}

// ---------------- per-graph Gram matrix G = Z_g Z_g^T, BK=64, swizzled ----------------
__global__ __launch_bounds__(256)
void gram_mfma(const _Float16* __restrict__ Z, float* __restrict__ G)
{
    __shared__ _Float16 Zs[4096];   // [64][64]
    const int g = blockIdx.x;
    const int tid = threadIdx.x;
    const int lane = tid & 63, wave = tid >> 6;
    const int fl = lane & 15, kh = (lane >> 4) * 8;
    const int sw = (fl & 7) << 3;

    f32x4 acc[4];
    #pragma unroll
    for (int n = 0; n < 4; ++n) acc[n] = (f32x4){0.f, 0.f, 0.f, 0.f};

    for (int k0 = 0; k0 < ZD; k0 += 64) {
        #pragma unroll
        for (int j = 0; j < 2; ++j) {
            int d = wave * 1024 + j * 512 + lane * 8;
            int row = d >> 6, kk = d & 63;
            int sk = kk ^ ((row & 7) << 3);
            __builtin_amdgcn_global_load_lds(
                (const __attribute__((address_space(1))) void*)(Z + (size_t)(g * 64 + row) * ZD + k0 + sk),
                (__attribute__((address_space(3))) void*)&Zs[wave * 1024 + j * 512], 16, 0, 0);
        }
        __syncthreads();
        #pragma unroll
        for (int kc = 0; kc < 2; ++kc) {
            int ko = (kc * 32 + kh) ^ sw;
            half8 av = *(const half8*)&Zs[(wave * 16 + fl) * 64 + ko];
            #pragma unroll
            for (int n = 0; n < 4; ++n) {
                half8 bv = *(const half8*)&Zs[(n * 16 + fl) * 64 + ko];
                acc[n] = __builtin_amdgcn_mfma_f32_16x16x32_f16(av, bv, acc[n], 0, 0, 0);
            }
        }
        __syncthreads();
    }
    const int orow0 = (lane >> 4) * 4;
    const int ocol  = lane & 15;
    #pragma unroll
    for (int n = 0; n < 4; ++n)
        #pragma unroll
        for (int r = 0; r < 4; ++r)
            G[(size_t)(g * 64 + wave * 16 + orow0 + r) * 64 + n * 16 + ocol] = acc[n][r];
}

// ---------------- edge loss (both sets in one launch; grid (128, 2)) ----------------
__global__ void edge_loss2(const int* __restrict__ ei, const int* __restrict__ nei,
                           const float* __restrict__ G, float* __restrict__ LOSS)
{
    const int setid = blockIdx.y;
    const int* e0 = setid ? nei : ei;
    const int* e1 = e0 + NE;
    float* tot = LOSS + setid * 256;
    float* cnt = tot + 128;
    __shared__ float lt[128];
    __shared__ float lc[128];
    int tid = threadIdx.x;
    if (tid < 128) { lt[tid] = 0.f; lc[tid] = 0.f; }
    __syncthreads();
    for (int e = blockIdx.x * blockDim.x + tid; e < NE; e += gridDim.x * blockDim.x) {
        int a = e0[e], b = e1[e];
        int g = a >> 6;
        float v = G[(size_t)((g << 6) + (a & 63)) * 64 + (b & 63)];
        float s = 1.f / (1.f + expf(-v));
        float p = setid ? (1.f - s) : s;
        float l = -logf(1e-4f + p);
        atomicAdd(&lt[g], l);
        atomicAdd(&lc[g], 1.f);
    }
    __syncthreads();
    if (tid < 128) {
        atomicAdd(&tot[tid], lt[tid]);
        atomicAdd(&cnt[tid], lc[tid]);
    }
}

__global__ void lrc_final(const float* __restrict__ loss, float* __restrict__ out)
{
    int t = threadIdx.x;
    float v = loss[t] / fmaxf(loss[128 + t], 1.f) + loss[256 + t] / fmaxf(loss[384 + t], 1.f);
    __shared__ float red[128];
    red[t] = v;
    __syncthreads();
    for (int s = 64; s; s >>= 1) {
        if (t < s) red[t] += red[t + s];
        __syncthreads();
    }
    if (t == 0) out[0] = red[0] * (1.0f / 128.0f);
}

// ---------------- fused attention: s1/s2 + w + agg, per (graph, head), MFMA ----------------
__global__ __launch_bounds__(256)
void attn_fused(const _Float16* __restrict__ xh, const float* __restrict__ phi,
                _Float16* __restrict__ agg)
{
    const int g = blockIdx.x, h = blockIdx.y;
    __shared__ _Float16 Xt[4096];   // [d][b] swizzled
    __shared__ _Float16 Ws[4096];   // [i][b] swizzled
    __shared__ float Cs[64 * 68];
    __shared__ float s1s[64], s2s[64];
    const int tid = threadIdx.x;
    {
        const int b = tid >> 2, dq = tid & 3;
        const _Float16* xr = xh + (size_t)(g * 64 + b) * CL + h * 64 + dq * 16;
        const float* pa = phi + h * 128 + dq * 16;
        const float* pb = pa + 64;
        float sa = 0.f, sb = 0.f;
        #pragma unroll
        for (int j = 0; j < 2; ++j) {
            half8 v = *(const half8*)(xr + j * 8);
            float4 A4 = *(const float4*)(pa + j * 8);
            float4 A5 = *(const float4*)(pa + j * 8 + 4);
            float4 B4 = *(const float4*)(pb + j * 8);
            float4 B5 = *(const float4*)(pb + j * 8 + 4);
            float aa[8] = {A4.x, A4.y, A4.z, A4.w, A5.x, A5.y, A5.z, A5.w};
            float bb[8] = {B4.x, B4.y, B4.z, B4.w, B5.x, B5.y, B5.z, B5.w};
            #pragma unroll
            for (int e = 0; e < 8; ++e) {
                int d = dq * 16 + j * 8 + e;
                float vf = (float)v[e];
                Xt[(d * 64 + b) ^ ((d & 7) << 3)] = v[e];
                sa = fmaf(vf, aa[e], sa);
                sb = fmaf(vf, bb[e], sb);
            }
        }
        sa += __shfl_down(sa, 2); sa += __shfl_down(sa, 1);
        sb += __shfl_down(sb, 2); sb += __shfl_down(sb, 1);
        if (dq == 0) { s1s[b] = sa; s2s[b] = sb; }
    }
    __syncthreads();
    {
        const int i = tid >> 2, bq = tid & 3;
        float si = s1s[i];
        #pragma unroll
        for (int e = 0; e < 16; ++e) {
            int b = bq * 16 + e;
            float t = si + s2s[b];
            t = t > 0.f ? t : 0.01f * t;
            float w = 1.f / (1.f + expf(-t));
            Ws[(i * 64 + b) ^ ((i & 7) << 3)] = (_Float16)w;
        }
    }
    __syncthreads();
    const int lane = tid & 63, wave = tid >> 6;
    const int fl = lane & 15, kh = (lane >> 4) * 8;
    f32x4 acc[4];
    #pragma unroll
    for (int n = 0; n < 4; ++n) acc[n] = (f32x4){0.f, 0.f, 0.f, 0.f};
    #pragma unroll
    for (int kc = 0; kc < 2; ++kc) {
        int rowa = wave * 16 + fl;
        half8 av = *(const half8*)&Ws[(rowa * 64 + kc * 32 + kh) ^ ((rowa & 7) << 3)];
        #pragma unroll
        for (int n = 0; n < 4; ++n) {
            int rowb = n * 16 + fl;
            half8 bv = *(const half8*)&Xt[(rowb * 64 + kc * 32 + kh) ^ ((rowb & 7) << 3)];
            acc[n] = __builtin_amdgcn_mfma_f32_16x16x32_f16(av, bv, acc[n], 0, 0, 0);
        }
    }
    const int orow0 = (lane >> 4) * 4, ocol = lane & 15;
    #pragma unroll
    for (int n = 0; n < 4; ++n)
        #pragma unroll
        for (int r = 0; r < 4; ++r)
            Cs[(wave * 16 + orow0 + r) * 68 + n * 16 + ocol] = acc[n][r];
    __syncthreads();
    {
        const int rr = tid >> 3, dq = tid & 7;
        #pragma unroll
        for (int half = 0; half < 2; ++half) {
            int nd = half * 32 + rr;
            half8 hv;
            #pragma unroll
            for (int e = 0; e < 8; ++e)
                hv[e] = (_Float16)Cs[nd * 68 + dq * 8 + e];
            *(half8*)(agg + (size_t)(g * 64 + nd) * CL + h * 64 + dq * 8) = hv;
        }
    }
}

// ---------------- classifier head + per-graph mean (fused) ----------------
__global__ void head_yp(const float* __restrict__ hid, const float* __restrict__ fc2W,
                        const float* __restrict__ fc2b,
                        float* __restrict__ preds, float* __restrict__ outlog)
{
    int g = blockIdx.x, lane = threadIdx.x;
    int n = g * 64 + lane;
    const float* hr = hid + (size_t)n * 64;
    float x[64];
    #pragma unroll
    for (int k = 0; k < 64; ++k) x[k] = hr[k];
    float lg[10];
    float mx = -1e30f;
    #pragma unroll
    for (int c = 0; c < 10; ++c) {
        float s = fc2b[c];
        #pragma unroll
        for (int k = 0; k < 64; ++k) s = fmaf(x[k], fc2W[k * 10 + c], s);
        lg[c] = s;
        mx = fmaxf(mx, s);
    }
    float sum = 0.f;
    #pragma unroll
    for (int c = 0; c < 10; ++c) {
        float t = expf(lg[c] - mx) + 1e-4f;
        lg[c] = t;
        sum += t;
    }
    float inv = 1.f / sum;
    #pragma unroll
    for (int c = 0; c < 10; ++c) {
        lg[c] *= inv;
        preds[(size_t)n * 10 + c] = lg[c];
    }
    #pragma unroll
    for (int off = 32; off; off >>= 1)
        #pragma unroll
        for (int c = 0; c < 10; ++c) lg[c] += __shfl_down(lg[c], off);
    if (lane == 0)
        #pragma unroll
        for (int c = 0; c < 10; ++c) outlog[g * 10 + c] = logf(lg[c] * (1.0f / 64.0f));
}

extern "C" void kernel_launch(void* const* d_in, const int* in_sizes, int n_in,
                              void* d_out, int out_size, void* d_ws, size_t ws_size,
                              hipStream_t stream)
{
    (void)in_sizes; (void)n_in; (void)out_size; (void)ws_size;
    const float* x     = (const float*)d_in[0];
    const int*   ei    = (const int*)d_in[1];
    const int*   nei   = (const int*)d_in[2];
    const float* fcW   = (const float*)d_in[5];
    const float* fcb   = (const float*)d_in[6];
    const float* bng   = (const float*)d_in[7];
    const float* bnb   = (const float*)d_in[8];
    const float* convW = (const float*)d_in[9];
    const float* convb = (const float*)d_in[10];
    const float* featW = (const float*)d_in[11];
    const float* phi   = (const float*)d_in[12];
    const float* fc1W  = (const float*)d_in[13];
    const float* fc1b  = (const float*)d_in[14];
    const float* fc2W  = (const float*)d_in[15];
    const float* fc2b  = (const float*)d_in[16];
    float* out = (float*)d_out;

    char* ws = (char*)d_ws;
    _Float16* Z       = (_Float16*)(ws);              // 24 MB  -> 25165824
    _Float16* H0      = (_Float16*)(ws + 25165824);   // 8 MB   -> 33554432 (XH later)
    _Float16* AGG     = (_Float16*)(ws + 33554432);   // 8 MB   -> 41943040
    _Float16* xb      = (_Float16*)(ws + 41943040);   // 2 MB   -> 44040192
    _Float16* fcWt    = (_Float16*)(ws + 44040192);   // 128 KB -> 44171264
    _Float16* convWs  = (_Float16*)(ws + 44171264);   // 512 KB -> 44695552
    _Float16* featWt  = (_Float16*)(ws + 44695552);   // 1.5 MB -> 46268416
    _Float16* fc1Wt   = (_Float16*)(ws + 46268416);   // 64 KB  -> 46333952
    _Float16* Ah      = (_Float16*)(ws + 46333952);   // 1 MB   -> 47382528
    float*    Gram    = (float*)(ws + 47382528);      // 2 MB   -> 49479680
    float*    DINV    = (float*)(ws + 49479680);      // 32 KB  -> 49512448
    float*    HID     = (float*)(ws + 49512448);      // 2 MB   -> 51609600
    // zeroed region: DEG + Amat + LOSS + BNS3 + B2x3
    float*    DEG     = (float*)(ws + 51609600);      // 32 KB  -> 51642368
    float*    Amat    = (float*)(ws + 51642368);      // 2 MB   -> 53739520
    float*    LOSS    = (float*)(ws + 53739520);      // 2 KB   -> 53741568
    float*    BNS3    = (float*)(ws + 53741568);      // 12 KB  -> 53753856
    float*    B2      = (float*)(ws + 53753856);      // 6 KB   -> 53760000
    _Float16* XH      = H0;

    const int* src = ei;
    const int* dst = ei + NE;

    hipMemsetAsync(DEG, 0, 53760000 - 51609600, stream);

    deg_kernel<<<NE / 256, 256, 0, stream>>>(dst, DEG);
    deg_finish<<<NN / 256, 256, 0, stream>>>(DEG, DINV);
    build_adj<<<NE / 256, 256, 0, stream>>>(src, dst, DINV, Amat);
    adj_diag<<<NN / 256, 256, 0, stream>>>(DEG, Amat);
    cvtA<<<(NG * 4096 / 4) / 256, 256, 0, stream>>>(Amat, Ah);

    // f16 conversions
    cvt_h<<<(NN * NF / 8) / 256, 256, 0, stream>>>(x, xb);
    cvtT<<<dim3(CL / 32, NF / 32), dim3(32, 8), 0, stream>>>(fcW, fcWt, NF, CL);
    cvtT<<<dim3(CL / 32, ZD / 32), dim3(32, 8), 0, stream>>>(featW, featWt, ZD, CL);
    cvtT<<<dim3(2, 16), dim3(32, 8), 0, stream>>>(fc1W, fc1Wt, 512, 64);

    // h0 = x @ fc_W + fc_b  (f16 out, layer-0 BN stats fused)
    gemm_f16<0, true, true, true, false><<<dim3(CL / 64, NN / 128), 256, 0, stream>>>(
        xb, NF, fcWt, NF, nullptr, H0, CL, fcb, NF, BNS3, BNS3 + 512,
        nullptr, nullptr, nullptr);

    for (int i = 0; i < 3; ++i) {
        const _Float16* Ain = (i == 0) ? H0 : (Z + (size_t)(i - 1) * CL);
        int lda = (i == 0) ? CL : ZD;
        float* sums = BNS3 + i * 1024;
        float* sqs  = sums + 512;
        float* b2   = B2 + i * 512;
        wprep<<<dim3(CL / 32, CL / 32), dim3(32, 8), 0, stream>>>(
            convW + (size_t)i * CL * CL, sums, sqs, bng + i * CL, bnb + i * CL,
            convWs, b2, CL, CL);
        if (i < 2)
            gemm_f16<0, true, false, true, true><<<dim3(CL / 64, NN / 128), 256, 0, stream>>>(
                Ain, lda, convWs, CL, nullptr, nullptr, 0, b2, CL,
                BNS3 + (i + 1) * 1024, BNS3 + (i + 1) * 1024 + 512,
                Ah, convb + i * CL, Z + (size_t)i * CL);
        else
            gemm_f16<0, true, false, false, true><<<dim3(CL / 64, NN / 128), 256, 0, stream>>>(
                Ain, lda, convWs, CL, nullptr, nullptr, 0, b2, CL,
                nullptr, nullptr, Ah, convb + i * CL, Z + (size_t)i * CL);
    }

    // edge reconstruction loss via per-graph Gram matrices (MFMA)
    gram_mfma<<<NG, 256, 0, stream>>>(Z, Gram);
    edge_loss2<<<dim3(128, 2), 256, 0, stream>>>(ei, nei, Gram, LOSS);
    lrc_final<<<1, 128, 0, stream>>>(LOSS, out + 1280);

    // xh = z @ feat_W  (f16 out into H0 region)
    gemm_f16<0, false, true, false, false><<<dim3(CL / 64, NN / 128), 256, 0, stream>>>(
        Z, ZD, featWt, ZD, nullptr, XH, CL, nullptr, ZD, nullptr, nullptr,
        nullptr, nullptr, nullptr);

    // fused s12 + attention aggregation (MFMA), f16 AGG out
    attn_fused<<<dim3(NG, 8), 256, 0, stream>>>(XH, phi, AGG);

    // hid = leaky_relu(agg @ fc1 + b)  (f32 out)
    gemm_f16<2, true, false, false, false><<<dim3(1, NN / 128), 256, 0, stream>>>(
        AGG, CL, fc1Wt, CL, HID, nullptr, 64, fc1b, CL, nullptr, nullptr,
        nullptr, nullptr, nullptr);

    // head + per-graph mean (fused)
    head_yp<<<NG, 64, 0, stream>>>(HID, fc2W, fc2b, out + 1281, out);
}

// Round 9
// 187.629 us; speedup vs baseline: 5.1740x; 1.0473x over previous
//
#include <hip/hip_runtime.h>

#define NN 8192      // nodes
#define NG 128       // graphs
#define NF 128       // input feats
#define CL 512       // hidden dim
#define ZD 1536      // concat dim (3*512)
#define NE 262144    // edges per edge set

typedef __attribute__((ext_vector_type(8))) _Float16 half8;
typedef __attribute__((ext_vector_type(4))) float f32x4;

// ---------------- degree / dense adjacency ----------------
__global__ void deg_kernel(const int* __restrict__ dst, float* __restrict__ deg) {
    int e = blockIdx.x * 256 + threadIdx.x;
    atomicAdd(&deg[dst[e]], 1.0f);
}

// dinv computed inline (deg_finish deleted)
__global__ void build_adj(const int* __restrict__ src, const int* __restrict__ dst,
                          const float* __restrict__ deg, float* __restrict__ A) {
    int e = blockIdx.x * 256 + threadIdx.x;
    int s = src[e], d = dst[e];
    int g = d >> 6;
    float w = rsqrtf(deg[s] + 1.0f) * rsqrtf(deg[d] + 1.0f);
    atomicAdd(&A[(size_t)((g << 6) + (d & 63)) * 64 + (s & 63)], w);
}

// Amat f32 -> Ah f16 PRE-SWIZZLED, with self-loop diagonal folded in.
__global__ void cvtA(const float* __restrict__ Amat, const float* __restrict__ deg,
                     _Float16* __restrict__ Ah) {
    int t = blockIdx.x * 256 + threadIdx.x;      // 4 elems per thread
    int i4 = t * 4;
    int g = i4 >> 12, loc = i4 & 4095;
    float4 v = *(const float4*)(Amat + (size_t)g * 4096 + loc);
    float vv[4] = {v.x, v.y, v.z, v.w};
    int row = loc >> 6;
    int c0 = loc & 63;
    int ed = row - c0;
    if (ed >= 0 && ed < 4) vv[ed] += 1.0f / (deg[g * 64 + row] + 1.0f);
    int swz = (row & 7) << 3;
    #pragma unroll
    for (int e = 0; e < 4; ++e)
        Ah[(size_t)g * 4096 + ((loc + e) ^ swz)] = (_Float16)vv[e];
}

// ---------------- conversions (f32 -> f16) ----------------
__global__ void cvt_h(const float* __restrict__ in, _Float16* __restrict__ out) {
    int i = blockIdx.x * 256 + threadIdx.x;
    float4 a = *(const float4*)(in + (size_t)i * 8);
    float4 b = *(const float4*)(in + (size_t)i * 8 + 4);
    half8 o;
    o[0] = (_Float16)a.x; o[1] = (_Float16)a.y; o[2] = (_Float16)a.z; o[3] = (_Float16)a.w;
    o[4] = (_Float16)b.x; o[5] = (_Float16)b.y; o[6] = (_Float16)b.z; o[7] = (_Float16)b.w;
    *(half8*)(out + (size_t)i * 8) = o;
}

// W: Kd x Nd row-major f32 -> Wt: Nd x Kd row-major f16
__global__ void cvtT(const float* __restrict__ W, _Float16* __restrict__ Wt,
                     int Kd, int Nd) {
    __shared__ float t[32][33];
    int kb = blockIdx.y * 32, nb = blockIdx.x * 32;
    int tx = threadIdx.x, ty = threadIdx.y;   // 32 x 8
    for (int i = ty; i < 32; i += 8)
        t[i][tx] = W[(size_t)(kb + i) * Nd + nb + tx];
    __syncthreads();
    for (int i = ty; i < 32; i += 8)
        Wt[(size_t)(nb + i) * Kd + kb + tx] = (_Float16)t[tx][i];
}

// Fused BN-fold weight prep: Wt[n][k] = W[k][n]*s[k] (f16) AND bias2[n] += sum_k t[k]W[k][n]
__global__ void wprep(const float* __restrict__ W,
                      const float* __restrict__ sums, const float* __restrict__ sqs,
                      const float* __restrict__ g, const float* __restrict__ b,
                      _Float16* __restrict__ Wt, float* __restrict__ bias2,
                      int Kd, int Nd) {
    __shared__ float t[32][33];
    __shared__ float tks[32];
    int kb = blockIdx.y * 32, nb = blockIdx.x * 32;
    int tx = threadIdx.x, ty = threadIdx.y;   // 32 x 8
    for (int i = ty; i < 32; i += 8)
        t[i][tx] = W[(size_t)(kb + i) * Nd + nb + tx];
    int kc = kb + tx;
    float m = sums[kc] * (1.0f / NN);
    float var = sqs[kc] * (1.0f / NN) - m * m;
    float sc = rsqrtf(var + 1e-5f) * g[kc];
    if (ty == 0) tks[tx] = b[kc] - m * sc;
    __syncthreads();
    for (int i = ty; i < 32; i += 8)
        Wt[(size_t)(nb + i) * Kd + kb + tx] = (_Float16)(t[tx][i] * sc);
    if (ty == 0) {
        float acc = 0.f;
        #pragma unroll
        for (int i = 0; i < 32; ++i) acc = fmaf(tks[i], t[i][tx], acc);
        atomicAdd(&bias2[nb + tx], acc);
    }
}

// ---------------- f16 MFMA GEMM: C = A @ Bt^T, 128x64 tile, BK=64, XOR-swizzled LDS ---
template<int ACT, bool HASB, bool OUT16, bool STATS, bool FUSE>
__global__ __launch_bounds__(256)
void gemm_f16(const _Float16* __restrict__ A, int lda,
              const _Float16* __restrict__ Bt, int ldb,
              float* __restrict__ Cf, _Float16* __restrict__ Ch, int ldc,
              const float* __restrict__ bias, int K,
              float* __restrict__ sums, float* __restrict__ sqs,
              const _Float16* __restrict__ Ahg,
              const float* __restrict__ cb,
              _Float16* __restrict__ Zout)
{
    __shared__ __align__(16) char SMraw[FUSE ? 34816 : 24576];
    _Float16* As = (_Float16*)SMraw;              // [128][64]
    _Float16* Bs = (_Float16*)(SMraw + 16384);    // [64][64]
    const int tid = threadIdx.x;
    const int lane = tid & 63, wave = tid >> 6;
    const int wr = wave >> 1, wc = wave & 1;
    const int ntile = gridDim.x;
    const int li = blockIdx.y * ntile + blockIdx.x;
    const int x8 = li & 7, rest = li >> 3;
    const int bt = rest % ntile;
    const int bp = (rest / ntile) * 8 + x8;
    const int bm = bp * 128, bn = bt * 64;

    f32x4 acc[4][2];
    #pragma unroll
    for (int m = 0; m < 4; ++m)
        #pragma unroll
        for (int n = 0; n < 2; ++n)
            acc[m][n] = (f32x4){0.f, 0.f, 0.f, 0.f};

    const int fl = lane & 15, kh = (lane >> 4) * 8;
    const int sw = (fl & 7) << 3;

    for (int k0 = 0; k0 < K; k0 += 64) {
        #pragma unroll
        for (int j = 0; j < 4; ++j) {
            int d = wave * 2048 + j * 512 + lane * 8;
            int row = d >> 6, kk = d & 63;
            int sk = kk ^ ((row & 7) << 3);
            __builtin_amdgcn_global_load_lds(
                (const __attribute__((address_space(1))) void*)(A + (size_t)(bm + row) * lda + k0 + sk),
                (__attribute__((address_space(3))) void*)&As[wave * 2048 + j * 512], 16, 0, 0);
        }
        #pragma unroll
        for (int j = 0; j < 2; ++j) {
            int d = wave * 1024 + j * 512 + lane * 8;
            int row = d >> 6, kk = d & 63;
            int sk = kk ^ ((row & 7) << 3);
            __builtin_amdgcn_global_load_lds(
                (const __attribute__((address_space(1))) void*)(Bt + (size_t)(bn + row) * ldb + k0 + sk),
                (__attribute__((address_space(3))) void*)&Bs[wave * 1024 + j * 512], 16, 0, 0);
        }
        __syncthreads();
        #pragma unroll
        for (int kc = 0; kc < 2; ++kc) {
            int ko = (kc * 32 + kh) ^ sw;
            half8 av[4], bv[2];
            #pragma unroll
            for (int m = 0; m < 4; ++m)
                av[m] = *(const half8*)&As[(wr * 64 + m * 16 + fl) * 64 + ko];
            #pragma unroll
            for (int n = 0; n < 2; ++n)
                bv[n] = *(const half8*)&Bs[(wc * 32 + n * 16 + fl) * 64 + ko];
            #pragma unroll
            for (int m = 0; m < 4; ++m)
                #pragma unroll
                for (int n = 0; n < 2; ++n)
                    acc[m][n] = __builtin_amdgcn_mfma_f32_16x16x32_f16(av[m], bv[n], acc[m][n], 0, 0, 0);
        }
        __syncthreads();
    }

    const int orow0 = (lane >> 4) * 4;
    const int ocol  = lane & 15;

    if constexpr (!FUSE) {
        #pragma unroll
        for (int n = 0; n < 2; ++n) {
            int col = bn + wc * 32 + n * 16 + ocol;
            float bb = HASB ? bias[col] : 0.f;
            float ss = 0.f, qq = 0.f;
            #pragma unroll
            for (int m = 0; m < 4; ++m) {
                #pragma unroll
                for (int r = 0; r < 4; ++r) {
                    int rowg = bm + wr * 64 + m * 16 + orow0 + r;
                    float v = acc[m][n][r] + bb;
                    if (ACT == 2) v = v > 0.f ? v : 0.01f * v;
                    if (STATS) { ss += v; qq = fmaf(v, v, qq); }
                    if (OUT16) Ch[(size_t)rowg * ldc + col] = (_Float16)v;
                    else       Cf[(size_t)rowg * ldc + col] = v;
                }
            }
            if (STATS) {
                ss += __shfl_down(ss, 32); ss += __shfl_down(ss, 16);
                qq += __shfl_down(qq, 32); qq += __shfl_down(qq, 16);
                if (lane < 16) {
                    atomicAdd(&sums[col], ss);
                    atomicAdd(&sqs[col], qq);
                }
            }
        }
    } else {
        _Float16* AsA = (_Float16*)SMraw;            // [2][64][64] pre-swizzled adjacency
        _Float16* Xs  = (_Float16*)(SMraw + 16384);  // [64 cols][128 rows] swizzled C^T
        const _Float16* Ag = Ahg + (size_t)(bm >> 6) * 4096;
        #pragma unroll
        for (int j = 0; j < 4; ++j)
            __builtin_amdgcn_global_load_lds(
                (const __attribute__((address_space(1))) void*)(Ag + wave * 2048 + j * 512 + lane * 8),
                (__attribute__((address_space(3))) void*)&AsA[wave * 2048 + j * 512], 16, 0, 0);
        #pragma unroll
        for (int n = 0; n < 2; ++n) {
            int c = wc * 32 + n * 16 + ocol;
            float bb = HASB ? bias[bn + c] : 0.f;
            int csw = (c & 7) << 3;
            #pragma unroll
            for (int m = 0; m < 4; ++m) {
                #pragma unroll
                for (int r = 0; r < 4; ++r) {
                    int srow = wr * 64 + m * 16 + orow0 + r;
                    Xs[c * 128 + (srow & 64) + ((srow & 63) ^ csw)] = (_Float16)(acc[m][n][r] + bb);
                }
            }
        }
        __syncthreads();
        const int gg = wave >> 1, rh = wave & 1;
        f32x4 acc2[2][4];
        #pragma unroll
        for (int m2 = 0; m2 < 2; ++m2)
            #pragma unroll
            for (int n2 = 0; n2 < 4; ++n2)
                acc2[m2][n2] = (f32x4){0.f, 0.f, 0.f, 0.f};
        #pragma unroll
        for (int kc = 0; kc < 2; ++kc) {
            int ko = (kc * 32 + kh) ^ sw;
            #pragma unroll
            for (int m2 = 0; m2 < 2; ++m2) {
                int arow = rh * 32 + m2 * 16 + fl;
                half8 av = *(const half8*)&AsA[gg * 4096 + arow * 64 + ko];
                #pragma unroll
                for (int n2 = 0; n2 < 4; ++n2) {
                    int c = n2 * 16 + fl;
                    half8 bv = *(const half8*)&Xs[c * 128 + gg * 64 + ((kc * 32 + kh) ^ ((c & 7) << 3))];
                    acc2[m2][n2] = __builtin_amdgcn_mfma_f32_16x16x32_f16(av, bv, acc2[m2][n2], 0, 0, 0);
                }
            }
        }
        __syncthreads();
        float* Cs = (float*)SMraw;   // [128][68]
        #pragma unroll
        for (int m2 = 0; m2 < 2; ++m2)
            #pragma unroll
            for (int n2 = 0; n2 < 4; ++n2)
                #pragma unroll
                for (int r = 0; r < 4; ++r)
                    Cs[(gg * 64 + rh * 32 + m2 * 16 + orow0 + r) * 68 + n2 * 16 + ocol] = acc2[m2][n2][r];
        __syncthreads();
        const int rr = tid >> 3, dq = tid & 7;
        #pragma unroll
        for (int pass = 0; pass < 4; ++pass) {
            int row = pass * 32 + rr;
            half8 hv;
            #pragma unroll
            for (int e = 0; e < 8; ++e) {
                float v = Cs[row * 68 + dq * 8 + e] + cb[bn + dq * 8 + e];
                v = v > 0.f ? v : 0.f;
                hv[e] = (_Float16)v;
            }
            *(half8*)(Zout + (size_t)(bm + row) * ZD + bn + dq * 8) = hv;
        }
        if (STATS && tid < 64) {
            float bb = cb[bn + tid];
            float ss = 0.f, qq = 0.f;
            for (int row = 0; row < 128; ++row) {
                float v = Cs[row * 68 + tid] + bb;
                v = v > 0.f ? v : 0.f;
                ss += v;
                qq = fmaf(v, v, qq);
            }
            atomicAdd(&sums[bn + tid], ss);
            atomicAdd(&sqs[bn + tid], qq);
        }
    }
}

// ---------------- per-graph Gram, split-K: grid (NG, 2), part kh -> Gpart[kh] -------
__global__ __launch_bounds__(256)
void gram_mfma(const _Float16* __restrict__ Z, float* __restrict__ Gparts)
{
    __shared__ _Float16 Zs[4096];   // [64][64]
    const int g = blockIdx.x, khalf = blockIdx.y;
    const int tid = threadIdx.x;
    const int lane = tid & 63, wave = tid >> 6;
    const int fl = lane & 15, kh = (lane >> 4) * 8;
    const int sw = (fl & 7) << 3;
    float* G = Gparts + (size_t)khalf * NG * 4096;

    f32x4 acc[4];
    #pragma unroll
    for (int n = 0; n < 4; ++n) acc[n] = (f32x4){0.f, 0.f, 0.f, 0.f};

    for (int k0 = khalf * (ZD / 2); k0 < (khalf + 1) * (ZD / 2); k0 += 64) {
        #pragma unroll
        for (int j = 0; j < 2; ++j) {
            int d = wave * 1024 + j * 512 + lane * 8;
            int row = d >> 6, kk = d & 63;
            int sk = kk ^ ((row & 7) << 3);
            __builtin_amdgcn_global_load_lds(
                (const __attribute__((address_space(1))) void*)(Z + (size_t)(g * 64 + row) * ZD + k0 + sk),
                (__attribute__((address_space(3))) void*)&Zs[wave * 1024 + j * 512], 16, 0, 0);
        }
        __syncthreads();
        #pragma unroll
        for (int kc = 0; kc < 2; ++kc) {
            int ko = (kc * 32 + kh) ^ sw;
            half8 av = *(const half8*)&Zs[(wave * 16 + fl) * 64 + ko];
            #pragma unroll
            for (int n = 0; n < 4; ++n) {
                half8 bv = *(const half8*)&Zs[(n * 16 + fl) * 64 + ko];
                acc[n] = __builtin_amdgcn_mfma_f32_16x16x32_f16(av, bv, acc[n], 0, 0, 0);
            }
        }
        __syncthreads();
    }
    const int orow0 = (lane >> 4) * 4;
    const int ocol  = lane & 15;
    #pragma unroll
    for (int n = 0; n < 4; ++n)
        #pragma unroll
        for (int r = 0; r < 4; ++r)
            G[(size_t)(g * 64 + wave * 16 + orow0 + r) * 64 + n * 16 + ocol] = acc[n][r];
}

// ---------------- edge loss (both sets; G = G0 + G1) ----------------
__global__ void edge_loss2(const int* __restrict__ ei, const int* __restrict__ nei,
                           const float* __restrict__ G0, float* __restrict__ LOSS)
{
    const int setid = blockIdx.y;
    const int* e0 = setid ? nei : ei;
    const int* e1 = e0 + NE;
    float* tot = LOSS + setid * 256;
    float* cnt = tot + 128;
    const float* G1 = G0 + (size_t)NG * 4096;
    __shared__ float lt[128];
    __shared__ float lc[128];
    int tid = threadIdx.x;
    if (tid < 128) { lt[tid] = 0.f; lc[tid] = 0.f; }
    __syncthreads();
    for (int e = blockIdx.x * blockDim.x + tid; e < NE; e += gridDim.x * blockDim.x) {
        int a = e0[e], b = e1[e];
        int g = a >> 6;
        size_t idx = (size_t)((g << 6) + (a & 63)) * 64 + (b & 63);
        float v = G0[idx] + G1[idx];
        float s = 1.f / (1.f + expf(-v));
        float p = setid ? (1.f - s) : s;
        float l = -logf(1e-4f + p);
        atomicAdd(&lt[g], l);
        atomicAdd(&lc[g], 1.f);
    }
    __syncthreads();
    if (tid < 128) {
        atomicAdd(&tot[tid], lt[tid]);
        atomicAdd(&cnt[tid], lc[tid]);
    }
}

__global__ void lrc_final(const float* __restrict__ loss, float* __restrict__ out)
{
    int t = threadIdx.x;
    float v = loss[t] / fmaxf(loss[128 + t], 1.f) + loss[256 + t] / fmaxf(loss[384 + t], 1.f);
    __shared__ float red[128];
    red[t] = v;
    __syncthreads();
    for (int s = 64; s; s >>= 1) {
        if (t < s) red[t] += red[t + s];
        __syncthreads();
    }
    if (t == 0) out[0] = red[0] * (1.0f / 128.0f);
}

// ---------------- fused featW-GEMM + attention, per (head, graph) ----------------
// Phase 1: XH_tile = Z_g @ featW[h-slice]^T (K=ZD). Phase 2: s1/s2, W, PV, AGG.
__global__ __launch_bounds__(256)
void featattn(const _Float16* __restrict__ Z, const _Float16* __restrict__ featWt,
              const float* __restrict__ phi, _Float16* __restrict__ agg)
{
    __shared__ __align__(16) char SMraw[34816];
    _Float16* As = (_Float16*)SMraw;              // [64][64] Z tile
    _Float16* Bs = (_Float16*)(SMraw + 8192);     // [64][64] featW tile
    float*    Cs = (float*)SMraw;                 // [64][68] f32 (phase 2, aliases As/Bs)
    _Float16* Xt = (_Float16*)(SMraw + 17408);    // [d][b] swizzled
    _Float16* Ws = (_Float16*)(SMraw + 25600);    // [i][b] swizzled
    float*    s1s = (float*)(SMraw + 33792);      // 64
    float*    s2s = (float*)(SMraw + 34048);      // 64
    const int h = blockIdx.x, g = blockIdx.y;
    const int tid = threadIdx.x;
    const int lane = tid & 63, wave = tid >> 6;
    const int fl = lane & 15, kh = (lane >> 4) * 8;
    const int sw = (fl & 7) << 3;

    f32x4 acc[4];
    #pragma unroll
    for (int n = 0; n < 4; ++n) acc[n] = (f32x4){0.f, 0.f, 0.f, 0.f};

    for (int k0 = 0; k0 < ZD; k0 += 64) {
        #pragma unroll
        for (int j = 0; j < 2; ++j) {
            int d = wave * 1024 + j * 512 + lane * 8;
            int row = d >> 6, kk = d & 63;
            int sk = kk ^ ((row & 7) << 3);
            __builtin_amdgcn_global_load_lds(
                (const __attribute__((address_space(1))) void*)(Z + (size_t)(g * 64 + row) * ZD + k0 + sk),
                (__attribute__((address_space(3))) void*)&As[wave * 1024 + j * 512], 16, 0, 0);
            __builtin_amdgcn_global_load_lds(
                (const __attribute__((address_space(1))) void*)(featWt + (size_t)(h * 64 + row) * ZD + k0 + sk),
                (__attribute__((address_space(3))) void*)&Bs[wave * 1024 + j * 512], 16, 0, 0);
        }
        __syncthreads();
        #pragma unroll
        for (int kc = 0; kc < 2; ++kc) {
            int ko = (kc * 32 + kh) ^ sw;
            half8 av = *(const half8*)&As[(wave * 16 + fl) * 64 + ko];
            #pragma unroll
            for (int n = 0; n < 4; ++n) {
                half8 bv = *(const half8*)&Bs[(n * 16 + fl) * 64 + ko];
                acc[n] = __builtin_amdgcn_mfma_f32_16x16x32_f16(av, bv, acc[n], 0, 0, 0);
            }
        }
        __syncthreads();
    }
    const int orow0 = (lane >> 4) * 4, ocol = lane & 15;
    #pragma unroll
    for (int n = 0; n < 4; ++n)
        #pragma unroll
        for (int r = 0; r < 4; ++r)
            Cs[(wave * 16 + orow0 + r) * 68 + n * 16 + ocol] = acc[n][r];
    __syncthreads();
    // s1/s2 partial dots + build Xt (d-major f16 swizzled) from Cs
    {
        const int b = tid >> 2, dq = tid & 3;
        const float* pa = phi + h * 128 + dq * 16;
        const float* pb = pa + 64;
        float sa = 0.f, sb = 0.f;
        #pragma unroll
        for (int j = 0; j < 16; ++j) {
            int d = dq * 16 + j;
            float vf = Cs[b * 68 + d];
            Xt[(d * 64 + b) ^ ((d & 7) << 3)] = (_Float16)vf;
            sa = fmaf(vf, pa[j], sa);
            sb = fmaf(vf, pb[j], sb);
        }
        sa += __shfl_down(sa, 2); sa += __shfl_down(sa, 1);
        sb += __shfl_down(sb, 2); sb += __shfl_down(sb, 1);
        if (dq == 0) { s1s[b] = sa; s2s[b] = sb; }
    }
    __syncthreads();
    {
        const int i = tid >> 2, bq = tid & 3;
        float si = s1s[i];
        #pragma unroll
        for (int e = 0; e < 16; ++e) {
            int b = bq * 16 + e;
            float t = si + s2s[b];
            t = t > 0.f ? t : 0.01f * t;
            float w = 1.f / (1.f + expf(-t));
            Ws[(i * 64 + b) ^ ((i & 7) << 3)] = (_Float16)w;
        }
    }
    __syncthreads();
    f32x4 acc2[4];
    #pragma unroll
    for (int n = 0; n < 4; ++n) acc2[n] = (f32x4){0.f, 0.f, 0.f, 0.f};
    #pragma unroll
    for (int kc = 0; kc < 2; ++kc) {
        int rowa = wave * 16 + fl;
        half8 av = *(const half8*)&Ws[(rowa * 64 + kc * 32 + kh) ^ ((rowa & 7) << 3)];
        #pragma unroll
        for (int n = 0; n < 4; ++n) {
            int rowb = n * 16 + fl;
            half8 bv = *(const half8*)&Xt[(rowb * 64 + kc * 32 + kh) ^ ((rowb & 7) << 3)];
            acc2[n] = __builtin_amdgcn_mfma_f32_16x16x32_f16(av, bv, acc2[n], 0, 0, 0);
        }
    }
    __syncthreads();
    #pragma unroll
    for (int n = 0; n < 4; ++n)
        #pragma unroll
        for (int r = 0; r < 4; ++r)
            Cs[(wave * 16 + orow0 + r) * 68 + n * 16 + ocol] = acc2[n][r];
    __syncthreads();
    {
        const int rr = tid >> 3, dq = tid & 7;
        #pragma unroll
        for (int half = 0; half < 2; ++half) {
            int nd = half * 32 + rr;
            half8 hv;
            #pragma unroll
            for (int e = 0; e < 8; ++e)
                hv[e] = (_Float16)Cs[nd * 68 + dq * 8 + e];
            *(half8*)(agg + (size_t)(g * 64 + nd) * CL + h * 64 + dq * 8) = hv;
        }
    }
}

// ---------------- fused fc1 + head + per-graph mean, per graph ----------------
__global__ __launch_bounds__(256)
void fc1head(const _Float16* __restrict__ AGG, const _Float16* __restrict__ fc1Wt,
             const float* __restrict__ fc1b,
             const float* __restrict__ fc2W, const float* __restrict__ fc2b,
             float* __restrict__ preds, float* __restrict__ outlog)
{
    __shared__ __align__(16) char SMraw[17664];
    _Float16* As = (_Float16*)SMraw;              // [64][64]
    _Float16* Bs = (_Float16*)(SMraw + 8192);     // [64][64]
    float*    Cs = (float*)SMraw;                 // [64][69] f32 hid
    const int g = blockIdx.x;
    const int tid = threadIdx.x;
    const int lane = tid & 63, wave = tid >> 6;
    const int fl = lane & 15, kh = (lane >> 4) * 8;
    const int sw = (fl & 7) << 3;

    f32x4 acc[4];
    #pragma unroll
    for (int n = 0; n < 4; ++n) acc[n] = (f32x4){0.f, 0.f, 0.f, 0.f};

    for (int k0 = 0; k0 < CL; k0 += 64) {
        #pragma unroll
        for (int j = 0; j < 2; ++j) {
            int d = wave * 1024 + j * 512 + lane * 8;
            int row = d >> 6, kk = d & 63;
            int sk = kk ^ ((row & 7) << 3);
            __builtin_amdgcn_global_load_lds(
                (const __attribute__((address_space(1))) void*)(AGG + (size_t)(g * 64 + row) * CL + k0 + sk),
                (__attribute__((address_space(3))) void*)&As[wave * 1024 + j * 512], 16, 0, 0);
            __builtin_amdgcn_global_load_lds(
                (const __attribute__((address_space(1))) void*)(fc1Wt + (size_t)row * CL + k0 + sk),
                (__attribute__((address_space(3))) void*)&Bs[wave * 1024 + j * 512], 16, 0, 0);
        }
        __syncthreads();
        #pragma unroll
        for (int kc = 0; kc < 2; ++kc) {
            int ko = (kc * 32 + kh) ^ sw;
            half8 av = *(const half8*)&As[(wave * 16 + fl) * 64 + ko];
            #pragma unroll
            for (int n = 0; n < 4; ++n) {
                half8 bv = *(const half8*)&Bs[(n * 16 + fl) * 64 + ko];
                acc[n] = __builtin_amdgcn_mfma_f32_16x16x32_f16(av, bv, acc[n], 0, 0, 0);
            }
        }
        __syncthreads();
    }
    const int orow0 = (lane >> 4) * 4, ocol = lane & 15;
    #pragma unroll
    for (int n = 0; n < 4; ++n) {
        int col = n * 16 + ocol;
        float bb = fc1b[col];
        #pragma unroll
        for (int r = 0; r < 4; ++r) {
            float v = acc[n][r] + bb;
            v = v > 0.f ? v : 0.01f * v;
            Cs[(wave * 16 + orow0 + r) * 69 + col] = v;
        }
    }
    __syncthreads();
    if (tid < 64) {
        float lg[10];
        float mx = -1e30f;
        #pragma unroll
        for (int c = 0; c < 10; ++c) {
            float s = fc2b[c];
            #pragma unroll
            for (int k = 0; k < 64; ++k) s = fmaf(Cs[tid * 69 + k], fc2W[k * 10 + c], s);
            lg[c] = s;
            mx = fmaxf(mx, s);
        }
        float sum = 0.f;
        #pragma unroll
        for (int c = 0; c < 10; ++c) {
            float t = expf(lg[c] - mx) + 1e-4f;
            lg[c] = t;
            sum += t;
        }
        float inv = 1.f / sum;
        #pragma unroll
        for (int c = 0; c < 10; ++c) {
            lg[c] *= inv;
            preds[(size_t)(g * 64 + tid) * 10 + c] = lg[c];
        }
        #pragma unroll
        for (int off = 32; off; off >>= 1)
            #pragma unroll
            for (int c = 0; c < 10; ++c) lg[c] += __shfl_down(lg[c], off);
        if (tid == 0)
            #pragma unroll
            for (int c = 0; c < 10; ++c) outlog[g * 10 + c] = logf(lg[c] * (1.0f / 64.0f));
    }
}

extern "C" void kernel_launch(void* const* d_in, const int* in_sizes, int n_in,
                              void* d_out, int out_size, void* d_ws, size_t ws_size,
                              hipStream_t stream)
{
    (void)in_sizes; (void)n_in; (void)out_size; (void)ws_size;
    const float* x     = (const float*)d_in[0];
    const int*   ei    = (const int*)d_in[1];
    const int*   nei   = (const int*)d_in[2];
    const float* fcW   = (const float*)d_in[5];
    const float* fcb   = (const float*)d_in[6];
    const float* bng   = (const float*)d_in[7];
    const float* bnb   = (const float*)d_in[8];
    const float* convW = (const float*)d_in[9];
    const float* convb = (const float*)d_in[10];
    const float* featW = (const float*)d_in[11];
    const float* phi   = (const float*)d_in[12];
    const float* fc1W  = (const float*)d_in[13];
    const float* fc1b  = (const float*)d_in[14];
    const float* fc2W  = (const float*)d_in[15];
    const float* fc2b  = (const float*)d_in[16];
    float* out = (float*)d_out;

    char* ws = (char*)d_ws;
    _Float16* Z       = (_Float16*)(ws);              // 24 MB  -> 25165824
    _Float16* H0      = (_Float16*)(ws + 25165824);   // 8 MB   -> 33554432
    _Float16* AGG     = (_Float16*)(ws + 33554432);   // 8 MB   -> 41943040
    _Float16* xb      = (_Float16*)(ws + 41943040);   // 2 MB   -> 44040192
    _Float16* fcWt    = (_Float16*)(ws + 44040192);   // 128 KB -> 44171264
    _Float16* convWs  = (_Float16*)(ws + 44171264);   // 512 KB -> 44695552
    _Float16* featWt  = (_Float16*)(ws + 44695552);   // 1.5 MB -> 46268416
    _Float16* fc1Wt   = (_Float16*)(ws + 46268416);   // 64 KB  -> 46333952
    _Float16* Ah      = (_Float16*)(ws + 46333952);   // 1 MB   -> 47382528
    float*    Gram    = (float*)(ws + 47382528);      // 4 MB (2 parts) -> 51576832
    // zeroed region: DEG + Amat + LOSS + BNS3 + B2x3
    float*    DEG     = (float*)(ws + 51576832);      // 32 KB  -> 51609600
    float*    Amat    = (float*)(ws + 51609600);      // 2 MB   -> 53706752
    float*    LOSS    = (float*)(ws + 53706752);      // 2 KB   -> 53708800
    float*    BNS3    = (float*)(ws + 53708800);      // 12 KB  -> 53721088
    float*    B2      = (float*)(ws + 53721088);      // 6 KB   -> 53727232

    const int* src = ei;
    const int* dst = ei + NE;

    hipMemsetAsync(DEG, 0, 53727232 - 51576832, stream);

    deg_kernel<<<NE / 256, 256, 0, stream>>>(dst, DEG);
    build_adj<<<NE / 256, 256, 0, stream>>>(src, dst, DEG, Amat);
    cvtA<<<(NG * 4096 / 4) / 256, 256, 0, stream>>>(Amat, DEG, Ah);

    // f16 conversions
    cvt_h<<<(NN * NF / 8) / 256, 256, 0, stream>>>(x, xb);
    cvtT<<<dim3(CL / 32, NF / 32), dim3(32, 8), 0, stream>>>(fcW, fcWt, NF, CL);
    cvtT<<<dim3(CL / 32, ZD / 32), dim3(32, 8), 0, stream>>>(featW, featWt, ZD, CL);
    cvtT<<<dim3(2, 16), dim3(32, 8), 0, stream>>>(fc1W, fc1Wt, 512, 64);

    // h0 = x @ fc_W + fc_b  (f16 out, layer-0 BN stats fused)
    gemm_f16<0, true, true, true, false><<<dim3(CL / 64, NN / 128), 256, 0, stream>>>(
        xb, NF, fcWt, NF, nullptr, H0, CL, fcb, NF, BNS3, BNS3 + 512,
        nullptr, nullptr, nullptr);

    for (int i = 0; i < 3; ++i) {
        const _Float16* Ain = (i == 0) ? H0 : (Z + (size_t)(i - 1) * CL);
        int lda = (i == 0) ? CL : ZD;
        float* sums = BNS3 + i * 1024;
        float* sqs  = sums + 512;
        float* b2   = B2 + i * 512;
        wprep<<<dim3(CL / 32, CL / 32), dim3(32, 8), 0, stream>>>(
            convW + (size_t)i * CL * CL, sums, sqs, bng + i * CL, bnb + i * CL,
            convWs, b2, CL, CL);
        if (i < 2)
            gemm_f16<0, true, false, true, true><<<dim3(CL / 64, NN / 128), 256, 0, stream>>>(
                Ain, lda, convWs, CL, nullptr, nullptr, 0, b2, CL,
                BNS3 + (i + 1) * 1024, BNS3 + (i + 1) * 1024 + 512,
                Ah, convb + i * CL, Z + (size_t)i * CL);
        else
            gemm_f16<0, true, false, false, true><<<dim3(CL / 64, NN / 128), 256, 0, stream>>>(
                Ain, lda, convWs, CL, nullptr, nullptr, 0, b2, CL,
                nullptr, nullptr, Ah, convb + i * CL, Z + (size_t)i * CL);
    }

    // edge reconstruction loss via split-K per-graph Gram
    gram_mfma<<<dim3(NG, 2), 256, 0, stream>>>(Z, Gram);
    edge_loss2<<<dim3(128, 2), 256, 0, stream>>>(ei, nei, Gram, LOSS);
    lrc_final<<<1, 128, 0, stream>>>(LOSS, out + 1280);

    // fused featW GEMM + attention -> AGG (f16)
    featattn<<<dim3(8, NG), 256, 0, stream>>>(Z, featWt, phi, AGG);

    // fused fc1 + head + per-graph mean
    fc1head<<<NG, 256, 0, stream>>>(AGG, fc1Wt, fc1b, fc2W, fc2b, out + 1281, out);
}

// Round 10
// 177.822 us; speedup vs baseline: 5.4593x; 1.0552x over previous
//
#include <hip/hip_runtime.h>

#define NN 8192      // nodes
#define NG 128       // graphs
#define NF 128       // input feats
#define CL 512       // hidden dim
#define ZD 1536      // concat dim (3*512)
#define NE 262144    // edges per edge set

typedef __attribute__((ext_vector_type(8))) _Float16 half8;
typedef __attribute__((ext_vector_type(4))) float f32x4;

// ---------------- degree / dense adjacency ----------------
__global__ void deg_kernel(const int* __restrict__ dst, float* __restrict__ deg) {
    int e = blockIdx.x * 256 + threadIdx.x;
    atomicAdd(&deg[dst[e]], 1.0f);
}

__global__ void build_adj(const int* __restrict__ src, const int* __restrict__ dst,
                          const float* __restrict__ deg, float* __restrict__ A) {
    int e = blockIdx.x * 256 + threadIdx.x;
    int s = src[e], d = dst[e];
    int g = d >> 6;
    float w = rsqrtf(deg[s] + 1.0f) * rsqrtf(deg[d] + 1.0f);
    atomicAdd(&A[(size_t)((g << 6) + (d & 63)) * 64 + (s & 63)], w);
}

// Amat f32 -> Ah f16 PRE-SWIZZLED, with self-loop diagonal folded in.
__global__ void cvtA(const float* __restrict__ Amat, const float* __restrict__ deg,
                     _Float16* __restrict__ Ah) {
    int t = blockIdx.x * 256 + threadIdx.x;
    int i4 = t * 4;
    int g = i4 >> 12, loc = i4 & 4095;
    float4 v = *(const float4*)(Amat + (size_t)g * 4096 + loc);
    float vv[4] = {v.x, v.y, v.z, v.w};
    int row = loc >> 6;
    int c0 = loc & 63;
    int ed = row - c0;
    if (ed >= 0 && ed < 4) vv[ed] += 1.0f / (deg[g * 64 + row] + 1.0f);
    int swz = (row & 7) << 3;
    #pragma unroll
    for (int e = 0; e < 4; ++e)
        Ah[(size_t)g * 4096 + ((loc + e) ^ swz)] = (_Float16)vv[e];
}

// ---------------- conversions (f32 -> f16) ----------------
__global__ void cvt_h(const float* __restrict__ in, _Float16* __restrict__ out) {
    int i = blockIdx.x * 256 + threadIdx.x;
    float4 a = *(const float4*)(in + (size_t)i * 8);
    float4 b = *(const float4*)(in + (size_t)i * 8 + 4);
    half8 o;
    o[0] = (_Float16)a.x; o[1] = (_Float16)a.y; o[2] = (_Float16)a.z; o[3] = (_Float16)a.w;
    o[4] = (_Float16)b.x; o[5] = (_Float16)b.y; o[6] = (_Float16)b.z; o[7] = (_Float16)b.w;
    *(half8*)(out + (size_t)i * 8) = o;
}

__global__ void cvtT(const float* __restrict__ W, _Float16* __restrict__ Wt,
                     int Kd, int Nd) {
    __shared__ float t[32][33];
    int kb = blockIdx.y * 32, nb = blockIdx.x * 32;
    int tx = threadIdx.x, ty = threadIdx.y;   // 32 x 8
    for (int i = ty; i < 32; i += 8)
        t[i][tx] = W[(size_t)(kb + i) * Nd + nb + tx];
    __syncthreads();
    for (int i = ty; i < 32; i += 8)
        Wt[(size_t)(nb + i) * Kd + kb + tx] = (_Float16)t[tx][i];
}

// Fused BN-fold weight prep
__global__ void wprep(const float* __restrict__ W,
                      const float* __restrict__ sums, const float* __restrict__ sqs,
                      const float* __restrict__ g, const float* __restrict__ b,
                      _Float16* __restrict__ Wt, float* __restrict__ bias2,
                      int Kd, int Nd) {
    __shared__ float t[32][33];
    __shared__ float tks[32];
    int kb = blockIdx.y * 32, nb = blockIdx.x * 32;
    int tx = threadIdx.x, ty = threadIdx.y;
    for (int i = ty; i < 32; i += 8)
        t[i][tx] = W[(size_t)(kb + i) * Nd + nb + tx];
    int kc = kb + tx;
    float m = sums[kc] * (1.0f / NN);
    float var = sqs[kc] * (1.0f / NN) - m * m;
    float sc = rsqrtf(var + 1e-5f) * g[kc];
    if (ty == 0) tks[tx] = b[kc] - m * sc;
    __syncthreads();
    for (int i = ty; i < 32; i += 8)
        Wt[(size_t)(nb + i) * Kd + kb + tx] = (_Float16)(t[tx][i] * sc);
    if (ty == 0) {
        float acc = 0.f;
        #pragma unroll
        for (int i = 0; i < 32; ++i) acc = fmaf(tks[i], t[i][tx], acc);
        atomicAdd(&bias2[nb + tx], acc);
    }
}

// ---------------- f16 MFMA GEMM: C = A @ Bt^T, 128x64 tile, BK=64, XOR-swizzled LDS ---
template<int ACT, bool HASB, bool OUT16, bool STATS, bool FUSE>
__global__ __launch_bounds__(256)
void gemm_f16(const _Float16* __restrict__ A, int lda,
              const _Float16* __restrict__ Bt, int ldb,
              float* __restrict__ Cf, _Float16* __restrict__ Ch, int ldc,
              const float* __restrict__ bias, int K,
              float* __restrict__ sums, float* __restrict__ sqs,
              const _Float16* __restrict__ Ahg,
              const float* __restrict__ cb,
              _Float16* __restrict__ Zout)
{
    __shared__ __align__(16) char SMraw[FUSE ? 34816 : 24576];
    _Float16* As = (_Float16*)SMraw;              // [128][64]
    _Float16* Bs = (_Float16*)(SMraw + 16384);    // [64][64]
    const int tid = threadIdx.x;
    const int lane = tid & 63, wave = tid >> 6;
    const int wr = wave >> 1, wc = wave & 1;
    const int ntile = gridDim.x;
    const int li = blockIdx.y * ntile + blockIdx.x;
    const int x8 = li & 7, rest = li >> 3;
    const int bt = rest % ntile;
    const int bp = (rest / ntile) * 8 + x8;
    const int bm = bp * 128, bn = bt * 64;

    f32x4 acc[4][2];
    #pragma unroll
    for (int m = 0; m < 4; ++m)
        #pragma unroll
        for (int n = 0; n < 2; ++n)
            acc[m][n] = (f32x4){0.f, 0.f, 0.f, 0.f};

    const int fl = lane & 15, kh = (lane >> 4) * 8;
    const int sw = (fl & 7) << 3;

    for (int k0 = 0; k0 < K; k0 += 64) {
        #pragma unroll
        for (int j = 0; j < 4; ++j) {
            int d = wave * 2048 + j * 512 + lane * 8;
            int row = d >> 6, kk = d & 63;
            int sk = kk ^ ((row & 7) << 3);
            __builtin_amdgcn_global_load_lds(
                (const __attribute__((address_space(1))) void*)(A + (size_t)(bm + row) * lda + k0 + sk),
                (__attribute__((address_space(3))) void*)&As[wave * 2048 + j * 512], 16, 0, 0);
        }
        #pragma unroll
        for (int j = 0; j < 2; ++j) {
            int d = wave * 1024 + j * 512 + lane * 8;
            int row = d >> 6, kk = d & 63;
            int sk = kk ^ ((row & 7) << 3);
            __builtin_amdgcn_global_load_lds(
                (const __attribute__((address_space(1))) void*)(Bt + (size_t)(bn + row) * ldb + k0 + sk),
                (__attribute__((address_space(3))) void*)&Bs[wave * 1024 + j * 512], 16, 0, 0);
        }
        __syncthreads();
        #pragma unroll
        for (int kc = 0; kc < 2; ++kc) {
            int ko = (kc * 32 + kh) ^ sw;
            half8 av[4], bv[2];
            #pragma unroll
            for (int m = 0; m < 4; ++m)
                av[m] = *(const half8*)&As[(wr * 64 + m * 16 + fl) * 64 + ko];
            #pragma unroll
            for (int n = 0; n < 2; ++n)
                bv[n] = *(const half8*)&Bs[(wc * 32 + n * 16 + fl) * 64 + ko];
            #pragma unroll
            for (int m = 0; m < 4; ++m)
                #pragma unroll
                for (int n = 0; n < 2; ++n)
                    acc[m][n] = __builtin_amdgcn_mfma_f32_16x16x32_f16(av[m], bv[n], acc[m][n], 0, 0, 0);
        }
        __syncthreads();
    }

    const int orow0 = (lane >> 4) * 4;
    const int ocol  = lane & 15;

    if constexpr (!FUSE) {
        #pragma unroll
        for (int n = 0; n < 2; ++n) {
            int col = bn + wc * 32 + n * 16 + ocol;
            float bb = HASB ? bias[col] : 0.f;
            float ss = 0.f, qq = 0.f;
            #pragma unroll
            for (int m = 0; m < 4; ++m) {
                #pragma unroll
                for (int r = 0; r < 4; ++r) {
                    int rowg = bm + wr * 64 + m * 16 + orow0 + r;
                    float v = acc[m][n][r] + bb;
                    if (ACT == 2) v = v > 0.f ? v : 0.01f * v;
                    if (STATS) { ss += v; qq = fmaf(v, v, qq); }
                    if (OUT16) Ch[(size_t)rowg * ldc + col] = (_Float16)v;
                    else       Cf[(size_t)rowg * ldc + col] = v;
                }
            }
            if (STATS) {
                ss += __shfl_down(ss, 32); ss += __shfl_down(ss, 16);
                qq += __shfl_down(qq, 32); qq += __shfl_down(qq, 16);
                if (lane < 16) {
                    atomicAdd(&sums[col], ss);
                    atomicAdd(&sqs[col], qq);
                }
            }
        }
    } else {
        _Float16* AsA = (_Float16*)SMraw;            // [2][64][64] pre-swizzled adjacency
        _Float16* Xs  = (_Float16*)(SMraw + 16384);  // [64 cols][128 rows] swizzled C^T
        const _Float16* Ag = Ahg + (size_t)(bm >> 6) * 4096;
        #pragma unroll
        for (int j = 0; j < 4; ++j)
            __builtin_amdgcn_global_load_lds(
                (const __attribute__((address_space(1))) void*)(Ag + wave * 2048 + j * 512 + lane * 8),
                (__attribute__((address_space(3))) void*)&AsA[wave * 2048 + j * 512], 16, 0, 0);
        #pragma unroll
        for (int n = 0; n < 2; ++n) {
            int c = wc * 32 + n * 16 + ocol;
            float bb = HASB ? bias[bn + c] : 0.f;
            int csw = (c & 7) << 3;
            #pragma unroll
            for (int m = 0; m < 4; ++m) {
                #pragma unroll
                for (int r = 0; r < 4; ++r) {
                    int srow = wr * 64 + m * 16 + orow0 + r;
                    Xs[c * 128 + (srow & 64) + ((srow & 63) ^ csw)] = (_Float16)(acc[m][n][r] + bb);
                }
            }
        }
        __syncthreads();
        const int gg = wave >> 1, rh = wave & 1;
        f32x4 acc2[2][4];
        #pragma unroll
        for (int m2 = 0; m2 < 2; ++m2)
            #pragma unroll
            for (int n2 = 0; n2 < 4; ++n2)
                acc2[m2][n2] = (f32x4){0.f, 0.f, 0.f, 0.f};
        #pragma unroll
        for (int kc = 0; kc < 2; ++kc) {
            int ko = (kc * 32 + kh) ^ sw;
            #pragma unroll
            for (int m2 = 0; m2 < 2; ++m2) {
                int arow = rh * 32 + m2 * 16 + fl;
                half8 av = *(const half8*)&AsA[gg * 4096 + arow * 64 + ko];
                #pragma unroll
                for (int n2 = 0; n2 < 4; ++n2) {
                    int c = n2 * 16 + fl;
                    half8 bv = *(const half8*)&Xs[c * 128 + gg * 64 + ((kc * 32 + kh) ^ ((c & 7) << 3))];
                    acc2[m2][n2] = __builtin_amdgcn_mfma_f32_16x16x32_f16(av, bv, acc2[m2][n2], 0, 0, 0);
                }
            }
        }
        __syncthreads();
        float* Cs = (float*)SMraw;   // [128][68]
        #pragma unroll
        for (int m2 = 0; m2 < 2; ++m2)
            #pragma unroll
            for (int n2 = 0; n2 < 4; ++n2)
                #pragma unroll
                for (int r = 0; r < 4; ++r)
                    Cs[(gg * 64 + rh * 32 + m2 * 16 + orow0 + r) * 68 + n2 * 16 + ocol] = acc2[m2][n2][r];
        __syncthreads();
        const int rr = tid >> 3, dq = tid & 7;
        #pragma unroll
        for (int pass = 0; pass < 4; ++pass) {
            int row = pass * 32 + rr;
            half8 hv;
            #pragma unroll
            for (int e = 0; e < 8; ++e) {
                float v = Cs[row * 68 + dq * 8 + e] + cb[bn + dq * 8 + e];
                v = v > 0.f ? v : 0.f;
                hv[e] = (_Float16)v;
            }
            *(half8*)(Zout + (size_t)(bm + row) * ZD + bn + dq * 8) = hv;
        }
        if (STATS && tid < 64) {
            float bb = cb[bn + tid];
            float ss = 0.f, qq = 0.f;
            for (int row = 0; row < 128; ++row) {
                float v = Cs[row * 68 + tid] + bb;
                v = v > 0.f ? v : 0.f;
                ss += v;
                qq = fmaf(v, v, qq);
            }
            atomicAdd(&sums[bn + tid], ss);
            atomicAdd(&sqs[bn + tid], qq);
        }
    }
}

// ---------------- per-graph Gram, split-K: grid (NG, 2) ----------------
__global__ __launch_bounds__(256)
void gram_mfma(const _Float16* __restrict__ Z, float* __restrict__ Gparts)
{
    __shared__ _Float16 Zs[4096];   // [64][64]
    const int g = blockIdx.x, khalf = blockIdx.y;
    const int tid = threadIdx.x;
    const int lane = tid & 63, wave = tid >> 6;
    const int fl = lane & 15, kh = (lane >> 4) * 8;
    const int sw = (fl & 7) << 3;
    float* G = Gparts + (size_t)khalf * NG * 4096;

    f32x4 acc[4];
    #pragma unroll
    for (int n = 0; n < 4; ++n) acc[n] = (f32x4){0.f, 0.f, 0.f, 0.f};

    for (int k0 = khalf * (ZD / 2); k0 < (khalf + 1) * (ZD / 2); k0 += 64) {
        #pragma unroll
        for (int j = 0; j < 2; ++j) {
            int d = wave * 1024 + j * 512 + lane * 8;
            int row = d >> 6, kk = d & 63;
            int sk = kk ^ ((row & 7) << 3);
            __builtin_amdgcn_global_load_lds(
                (const __attribute__((address_space(1))) void*)(Z + (size_t)(g * 64 + row) * ZD + k0 + sk),
                (__attribute__((address_space(3))) void*)&Zs[wave * 1024 + j * 512], 16, 0, 0);
        }
        __syncthreads();
        #pragma unroll
        for (int kc = 0; kc < 2; ++kc) {
            int ko = (kc * 32 + kh) ^ sw;
            half8 av = *(const half8*)&Zs[(wave * 16 + fl) * 64 + ko];
            #pragma unroll
            for (int n = 0; n < 4; ++n) {
                half8 bv = *(const half8*)&Zs[(n * 16 + fl) * 64 + ko];
                acc[n] = __builtin_amdgcn_mfma_f32_16x16x32_f16(av, bv, acc[n], 0, 0, 0);
            }
        }
        __syncthreads();
    }
    const int orow0 = (lane >> 4) * 4;
    const int ocol  = lane & 15;
    #pragma unroll
    for (int n = 0; n < 4; ++n)
        #pragma unroll
        for (int r = 0; r < 4; ++r)
            G[(size_t)(g * 64 + wave * 16 + orow0 + r) * 64 + n * 16 + ocol] = acc[n][r];
}

// ---------------- edge loss (both sets; G = G0 + G1) ----------------
__global__ void edge_loss2(const int* __restrict__ ei, const int* __restrict__ nei,
                           const float* __restrict__ G0, float* __restrict__ LOSS)
{
    const int setid = blockIdx.y;
    const int* e0 = setid ? nei : ei;
    const int* e1 = e0 + NE;
    float* tot = LOSS + setid * 256;
    float* cnt = tot + 128;
    const float* G1 = G0 + (size_t)NG * 4096;
    __shared__ float lt[128];
    __shared__ float lc[128];
    int tid = threadIdx.x;
    if (tid < 128) { lt[tid] = 0.f; lc[tid] = 0.f; }
    __syncthreads();
    for (int e = blockIdx.x * blockDim.x + tid; e < NE; e += gridDim.x * blockDim.x) {
        int a = e0[e], b = e1[e];
        int g = a >> 6;
        size_t idx = (size_t)((g << 6) + (a & 63)) * 64 + (b & 63);
        float v = G0[idx] + G1[idx];
        float s = 1.f / (1.f + expf(-v));
        float p = setid ? (1.f - s) : s;
        float l = -logf(1e-4f + p);
        atomicAdd(&lt[g], l);
        atomicAdd(&lc[g], 1.f);
    }
    __syncthreads();
    if (tid < 128) {
        atomicAdd(&tot[tid], lt[tid]);
        atomicAdd(&cnt[tid], lc[tid]);
    }
}

__global__ void lrc_final(const float* __restrict__ loss, float* __restrict__ out)
{
    int t = threadIdx.x;
    float v = loss[t] / fmaxf(loss[128 + t], 1.f) + loss[256 + t] / fmaxf(loss[384 + t], 1.f);
    __shared__ float red[128];
    red[t] = v;
    __syncthreads();
    for (int s = 64; s; s >>= 1) {
        if (t < s) red[t] += red[t + s];
        __syncthreads();
    }
    if (t == 0) out[0] = red[0] * (1.0f / 128.0f);
}

// ---------------- fused featW-GEMM + attention: 128x64 tile (2 graphs), per (panel, head) ----
// grid (64, 8): blockIdx.x = node panel (2 graphs), blockIdx.y = head.
// Natural round-robin co-locates the 8 head-blocks of a panel on one XCD (li = h*64+p).
__global__ __launch_bounds__(256)
void featattn(const _Float16* __restrict__ Z, const _Float16* __restrict__ featWt,
              const float* __restrict__ phi, _Float16* __restrict__ agg)
{
    __shared__ __align__(16) char SMraw[68608];
    _Float16* As  = (_Float16*)SMraw;             // [128][64] Z tile (phase 1)
    _Float16* Bs  = (_Float16*)(SMraw + 16384);   // [64][64] featW tile (phase 1)
    float*    Cs  = (float*)SMraw;                // [128][68] f32 (phase 2)
    _Float16* Xt  = (_Float16*)(SMraw + 34816);   // [2][d][b] swizzled
    _Float16* Ws  = (_Float16*)(SMraw + 51200);   // [2][i][b] swizzled
    float*    s1s = (float*)(SMraw + 67584);      // 128
    float*    s2s = (float*)(SMraw + 68096);      // 128
    const int pnl = blockIdx.x, h = blockIdx.y;
    const int bm = pnl * 128;
    const int tid = threadIdx.x;
    const int lane = tid & 63, wave = tid >> 6;
    const int wr = wave >> 1, wc = wave & 1;
    const int fl = lane & 15, kh = (lane >> 4) * 8;
    const int sw = (fl & 7) << 3;

    f32x4 acc[4][2];
    #pragma unroll
    for (int m = 0; m < 4; ++m)
        #pragma unroll
        for (int n = 0; n < 2; ++n)
            acc[m][n] = (f32x4){0.f, 0.f, 0.f, 0.f};

    for (int k0 = 0; k0 < ZD; k0 += 64) {
        #pragma unroll
        for (int j = 0; j < 4; ++j) {
            int d = wave * 2048 + j * 512 + lane * 8;
            int row = d >> 6, kk = d & 63;
            int sk = kk ^ ((row & 7) << 3);
            __builtin_amdgcn_global_load_lds(
                (const __attribute__((address_space(1))) void*)(Z + (size_t)(bm + row) * ZD + k0 + sk),
                (__attribute__((address_space(3))) void*)&As[wave * 2048 + j * 512], 16, 0, 0);
        }
        #pragma unroll
        for (int j = 0; j < 2; ++j) {
            int d = wave * 1024 + j * 512 + lane * 8;
            int row = d >> 6, kk = d & 63;
            int sk = kk ^ ((row & 7) << 3);
            __builtin_amdgcn_global_load_lds(
                (const __attribute__((address_space(1))) void*)(featWt + (size_t)(h * 64 + row) * ZD + k0 + sk),
                (__attribute__((address_space(3))) void*)&Bs[wave * 1024 + j * 512], 16, 0, 0);
        }
        __syncthreads();
        #pragma unroll
        for (int kc = 0; kc < 2; ++kc) {
            int ko = (kc * 32 + kh) ^ sw;
            half8 av[4], bv[2];
            #pragma unroll
            for (int m = 0; m < 4; ++m)
                av[m] = *(const half8*)&As[(wr * 64 + m * 16 + fl) * 64 + ko];
            #pragma unroll
            for (int n = 0; n < 2; ++n)
                bv[n] = *(const half8*)&Bs[(wc * 32 + n * 16 + fl) * 64 + ko];
            #pragma unroll
            for (int m = 0; m < 4; ++m)
                #pragma unroll
                for (int n = 0; n < 2; ++n)
                    acc[m][n] = __builtin_amdgcn_mfma_f32_16x16x32_f16(av[m], bv[n], acc[m][n], 0, 0, 0);
        }
        __syncthreads();
    }
    const int orow0 = (lane >> 4) * 4, ocol = lane & 15;
    // write XH (f32) to Cs [128][68]
    #pragma unroll
    for (int n = 0; n < 2; ++n) {
        int col = wc * 32 + n * 16 + ocol;
        #pragma unroll
        for (int m = 0; m < 4; ++m)
            #pragma unroll
            for (int r = 0; r < 4; ++r)
                Cs[(wr * 64 + m * 16 + orow0 + r) * 68 + col] = acc[m][n][r];
    }
    __syncthreads();
    // s1/s2 + Xt build: thread -> (node 0..127, d-half)
    {
        const int bnode = tid >> 1, dq = tid & 1;
        const int gg = bnode >> 6, bloc = bnode & 63;
        const float* pa = phi + h * 128 + dq * 32;
        const float* pb = pa + 64;
        float sa = 0.f, sb = 0.f;
        #pragma unroll
        for (int j = 0; j < 32; ++j) {
            int d = dq * 32 + j;
            float vf = Cs[bnode * 68 + d];
            Xt[gg * 4096 + ((d * 64 + bloc) ^ ((d & 7) << 3))] = (_Float16)vf;
            sa = fmaf(vf, pa[j], sa);
            sb = fmaf(vf, pb[j], sb);
        }
        sa += __shfl_down(sa, 1);
        sb += __shfl_down(sb, 1);
        if (dq == 0) { s1s[bnode] = sa; s2s[bnode] = sb; }
    }
    __syncthreads();
    // W build: thread -> (row 0..127, b-half)
    {
        const int inode = tid >> 1, bq = tid & 1;
        const int gg = inode >> 6, iloc = inode & 63;
        float si = s1s[inode];
        #pragma unroll
        for (int e = 0; e < 32; ++e) {
            int b = bq * 32 + e;
            float t = si + s2s[gg * 64 + b];
            t = t > 0.f ? t : 0.01f * t;
            float w = 1.f / (1.f + expf(-t));
            Ws[gg * 4096 + ((iloc * 64 + b) ^ ((iloc & 7) << 3))] = (_Float16)w;
        }
    }
    __syncthreads();
    // phase 2 MFMA: wave -> (graph wave>>1, row-half wave&1)
    const int gg = wave >> 1, rh = wave & 1;
    f32x4 acc2[2][4];
    #pragma unroll
    for (int m2 = 0; m2 < 2; ++m2)
        #pragma unroll
        for (int n2 = 0; n2 < 4; ++n2)
            acc2[m2][n2] = (f32x4){0.f, 0.f, 0.f, 0.f};
    #pragma unroll
    for (int kc = 0; kc < 2; ++kc) {
        #pragma unroll
        for (int m2 = 0; m2 < 2; ++m2) {
            int arow = rh * 32 + m2 * 16 + fl;
            half8 av = *(const half8*)&Ws[gg * 4096 + ((arow * 64 + kc * 32 + kh) ^ ((arow & 7) << 3))];
            #pragma unroll
            for (int n2 = 0; n2 < 4; ++n2) {
                int rowb = n2 * 16 + fl;
                half8 bv = *(const half8*)&Xt[gg * 4096 + ((rowb * 64 + kc * 32 + kh) ^ ((rowb & 7) << 3))];
                acc2[m2][n2] = __builtin_amdgcn_mfma_f32_16x16x32_f16(av, bv, acc2[m2][n2], 0, 0, 0);
            }
        }
    }
    __syncthreads();
    #pragma unroll
    for (int m2 = 0; m2 < 2; ++m2)
        #pragma unroll
        for (int n2 = 0; n2 < 4; ++n2)
            #pragma unroll
            for (int r = 0; r < 4; ++r)
                Cs[(gg * 64 + rh * 32 + m2 * 16 + orow0 + r) * 68 + n2 * 16 + ocol] = acc2[m2][n2][r];
    __syncthreads();
    {
        const int rr = tid >> 3, dq = tid & 7;
        #pragma unroll
        for (int pass = 0; pass < 4; ++pass) {
            int row = pass * 32 + rr;
            half8 hv;
            #pragma unroll
            for (int e = 0; e < 8; ++e)
                hv[e] = (_Float16)Cs[row * 68 + dq * 8 + e];
            *(half8*)(agg + (size_t)(bm + row) * CL + h * 64 + dq * 8) = hv;
        }
    }
}

// ---------------- fused fc1 + head + per-graph mean, per graph ----------------
__global__ __launch_bounds__(256)
void fc1head(const _Float16* __restrict__ AGG, const _Float16* __restrict__ fc1Wt,
             const float* __restrict__ fc1b,
             const float* __restrict__ fc2W, const float* __restrict__ fc2b,
             float* __restrict__ preds, float* __restrict__ outlog)
{
    __shared__ __align__(16) char SMraw[17664];
    _Float16* As = (_Float16*)SMraw;              // [64][64]
    _Float16* Bs = (_Float16*)(SMraw + 8192);     // [64][64]
    float*    Cs = (float*)SMraw;                 // [64][69] f32 hid
    const int g = blockIdx.x;
    const int tid = threadIdx.x;
    const int lane = tid & 63, wave = tid >> 6;
    const int fl = lane & 15, kh = (lane >> 4) * 8;
    const int sw = (fl & 7) << 3;

    f32x4 acc[4];
    #pragma unroll
    for (int n = 0; n < 4; ++n) acc[n] = (f32x4){0.f, 0.f, 0.f, 0.f};

    for (int k0 = 0; k0 < CL; k0 += 64) {
        #pragma unroll
        for (int j = 0; j < 2; ++j) {
            int d = wave * 1024 + j * 512 + lane * 8;
            int row = d >> 6, kk = d & 63;
            int sk = kk ^ ((row & 7) << 3);
            __builtin_amdgcn_global_load_lds(
                (const __attribute__((address_space(1))) void*)(AGG + (size_t)(g * 64 + row) * CL + k0 + sk),
                (__attribute__((address_space(3))) void*)&As[wave * 1024 + j * 512], 16, 0, 0);
            __builtin_amdgcn_global_load_lds(
                (const __attribute__((address_space(1))) void*)(fc1Wt + (size_t)row * CL + k0 + sk),
                (__attribute__((address_space(3))) void*)&Bs[wave * 1024 + j * 512], 16, 0, 0);
        }
        __syncthreads();
        #pragma unroll
        for (int kc = 0; kc < 2; ++kc) {
            int ko = (kc * 32 + kh) ^ sw;
            half8 av = *(const half8*)&As[(wave * 16 + fl) * 64 + ko];
            #pragma unroll
            for (int n = 0; n < 4; ++n) {
                half8 bv = *(const half8*)&Bs[(n * 16 + fl) * 64 + ko];
                acc[n] = __builtin_amdgcn_mfma_f32_16x16x32_f16(av, bv, acc[n], 0, 0, 0);
            }
        }
        __syncthreads();
    }
    const int orow0 = (lane >> 4) * 4, ocol = lane & 15;
    #pragma unroll
    for (int n = 0; n < 4; ++n) {
        int col = n * 16 + ocol;
        float bb = fc1b[col];
        #pragma unroll
        for (int r = 0; r < 4; ++r) {
            float v = acc[n][r] + bb;
            v = v > 0.f ? v : 0.01f * v;
            Cs[(wave * 16 + orow0 + r) * 69 + col] = v;
        }
    }
    __syncthreads();
    if (tid < 64) {
        float lg[10];
        float mx = -1e30f;
        #pragma unroll
        for (int c = 0; c < 10; ++c) {
            float s = fc2b[c];
            #pragma unroll
            for (int k = 0; k < 64; ++k) s = fmaf(Cs[tid * 69 + k], fc2W[k * 10 + c], s);
            lg[c] = s;
            mx = fmaxf(mx, s);
        }
        float sum = 0.f;
        #pragma unroll
        for (int c = 0; c < 10; ++c) {
            float t = expf(lg[c] - mx) + 1e-4f;
            lg[c] = t;
            sum += t;
        }
        float inv = 1.f / sum;
        #pragma unroll
        for (int c = 0; c < 10; ++c) {
            lg[c] *= inv;
            preds[(size_t)(g * 64 + tid) * 10 + c] = lg[c];
        }
        #pragma unroll
        for (int off = 32; off; off >>= 1)
            #pragma unroll
            for (int c = 0; c < 10; ++c) lg[c] += __shfl_down(lg[c], off);
        if (tid == 0)
            #pragma unroll
            for (int c = 0; c < 10; ++c) outlog[g * 10 + c] = logf(lg[c] * (1.0f / 64.0f));
    }
}

extern "C" void kernel_launch(void* const* d_in, const int* in_sizes, int n_in,
                              void* d_out, int out_size, void* d_ws, size_t ws_size,
                              hipStream_t stream)
{
    (void)in_sizes; (void)n_in; (void)out_size; (void)ws_size;
    const float* x     = (const float*)d_in[0];
    const int*   ei    = (const int*)d_in[1];
    const int*   nei   = (const int*)d_in[2];
    const float* fcW   = (const float*)d_in[5];
    const float* fcb   = (const float*)d_in[6];
    const float* bng   = (const float*)d_in[7];
    const float* bnb   = (const float*)d_in[8];
    const float* convW = (const float*)d_in[9];
    const float* convb = (const float*)d_in[10];
    const float* featW = (const float*)d_in[11];
    const float* phi   = (const float*)d_in[12];
    const float* fc1W  = (const float*)d_in[13];
    const float* fc1b  = (const float*)d_in[14];
    const float* fc2W  = (const float*)d_in[15];
    const float* fc2b  = (const float*)d_in[16];
    float* out = (float*)d_out;

    char* ws = (char*)d_ws;
    _Float16* Z       = (_Float16*)(ws);              // 24 MB  -> 25165824
    _Float16* H0      = (_Float16*)(ws + 25165824);   // 8 MB   -> 33554432
    _Float16* AGG     = (_Float16*)(ws + 33554432);   // 8 MB   -> 41943040
    _Float16* xb      = (_Float16*)(ws + 41943040);   // 2 MB   -> 44040192
    _Float16* fcWt    = (_Float16*)(ws + 44040192);   // 128 KB -> 44171264
    _Float16* convWs  = (_Float16*)(ws + 44171264);   // 512 KB -> 44695552
    _Float16* featWt  = (_Float16*)(ws + 44695552);   // 1.5 MB -> 46268416
    _Float16* fc1Wt   = (_Float16*)(ws + 46268416);   // 64 KB  -> 46333952
    _Float16* Ah      = (_Float16*)(ws + 46333952);   // 1 MB   -> 47382528
    float*    Gram    = (float*)(ws + 47382528);      // 4 MB (2 parts) -> 51576832
    // zeroed region: DEG + Amat + LOSS + BNS3 + B2x3
    float*    DEG     = (float*)(ws + 51576832);      // 32 KB  -> 51609600
    float*    Amat    = (float*)(ws + 51609600);      // 2 MB   -> 53706752
    float*    LOSS    = (float*)(ws + 53706752);      // 2 KB   -> 53708800
    float*    BNS3    = (float*)(ws + 53708800);      // 12 KB  -> 53721088
    float*    B2      = (float*)(ws + 53721088);      // 6 KB   -> 53727232

    const int* src = ei;
    const int* dst = ei + NE;

    hipMemsetAsync(DEG, 0, 53727232 - 51576832, stream);

    deg_kernel<<<NE / 256, 256, 0, stream>>>(dst, DEG);
    build_adj<<<NE / 256, 256, 0, stream>>>(src, dst, DEG, Amat);
    cvtA<<<(NG * 4096 / 4) / 256, 256, 0, stream>>>(Amat, DEG, Ah);

    // f16 conversions
    cvt_h<<<(NN * NF / 8) / 256, 256, 0, stream>>>(x, xb);
    cvtT<<<dim3(CL / 32, NF / 32), dim3(32, 8), 0, stream>>>(fcW, fcWt, NF, CL);
    cvtT<<<dim3(CL / 32, ZD / 32), dim3(32, 8), 0, stream>>>(featW, featWt, ZD, CL);
    cvtT<<<dim3(2, 16), dim3(32, 8), 0, stream>>>(fc1W, fc1Wt, 512, 64);

    // h0 = x @ fc_W + fc_b  (f16 out, layer-0 BN stats fused)
    gemm_f16<0, true, true, true, false><<<dim3(CL / 64, NN / 128), 256, 0, stream>>>(
        xb, NF, fcWt, NF, nullptr, H0, CL, fcb, NF, BNS3, BNS3 + 512,
        nullptr, nullptr, nullptr);

    for (int i = 0; i < 3; ++i) {
        const _Float16* Ain = (i == 0) ? H0 : (Z + (size_t)(i - 1) * CL);
        int lda = (i == 0) ? CL : ZD;
        float* sums = BNS3 + i * 1024;
        float* sqs  = sums + 512;
        float* b2   = B2 + i * 512;
        wprep<<<dim3(CL / 32, CL / 32), dim3(32, 8), 0, stream>>>(
            convW + (size_t)i * CL * CL, sums, sqs, bng + i * CL, bnb + i * CL,
            convWs, b2, CL, CL);
        if (i < 2)
            gemm_f16<0, true, false, true, true><<<dim3(CL / 64, NN / 128), 256, 0, stream>>>(
                Ain, lda, convWs, CL, nullptr, nullptr, 0, b2, CL,
                BNS3 + (i + 1) * 1024, BNS3 + (i + 1) * 1024 + 512,
                Ah, convb + i * CL, Z + (size_t)i * CL);
        else
            gemm_f16<0, true, false, false, true><<<dim3(CL / 64, NN / 128), 256, 0, stream>>>(
                Ain, lda, convWs, CL, nullptr, nullptr, 0, b2, CL,
                nullptr, nullptr, Ah, convb + i * CL, Z + (size_t)i * CL);
    }

    // edge reconstruction loss via split-K per-graph Gram
    gram_mfma<<<dim3(NG, 2), 256, 0, stream>>>(Z, Gram);
    edge_loss2<<<dim3(128, 2), 256, 0, stream>>>(ei, nei, Gram, LOSS);
    lrc_final<<<1, 128, 0, stream>>>(LOSS, out + 1280);

    // fused featW GEMM (128x64 tile, 2 graphs/block) + attention -> AGG (f16)
    featattn<<<dim3(64, 8), 256, 0, stream>>>(Z, featWt, phi, AGG);

    // fused fc1 + head + per-graph mean
    fc1head<<<NG, 256, 0, stream>>>(AGG, fc1Wt, fc1b, fc2W, fc2b, out + 1281, out);
}

// Round 11
// 171.758 us; speedup vs baseline: 5.6521x; 1.0353x over previous
//
#include <hip/hip_runtime.h>

#define NN 8192      // nodes
#define NG 128       // graphs
#define NF 128       // input feats
#define CL 512       // hidden dim
#define ZD 1536      // concat dim (3*512)
#define NE 262144    // edges per edge set

typedef __attribute__((ext_vector_type(8))) _Float16 half8;
typedef __attribute__((ext_vector_type(4))) float f32x4;

// ---------------- consolidated prep: cvt_h + 3x cvtT + edge-count atomics ----------------
// grid 2400 x 256: [0,512) cvt_h, [512,1536) edge counts, [1536,1600) fcW,
// [1600,2368) featW, [2368,2400) fc1W.
__global__ __launch_bounds__(256)
void prep_misc(const float* __restrict__ x, _Float16* __restrict__ xb,
               const float* __restrict__ fcW, _Float16* __restrict__ fcWt,
               const float* __restrict__ featW, _Float16* __restrict__ featWt,
               const float* __restrict__ fc1W, _Float16* __restrict__ fc1Wt,
               const int* __restrict__ ei, float* __restrict__ Acnt)
{
    const int b = blockIdx.x, tid = threadIdx.x;
    if (b < 512) {
        int i = b * 256 + tid;
        float4 a = *(const float4*)(x + (size_t)i * 8);
        float4 c = *(const float4*)(x + (size_t)i * 8 + 4);
        half8 o;
        o[0] = (_Float16)a.x; o[1] = (_Float16)a.y; o[2] = (_Float16)a.z; o[3] = (_Float16)a.w;
        o[4] = (_Float16)c.x; o[5] = (_Float16)c.y; o[6] = (_Float16)c.z; o[7] = (_Float16)c.w;
        *(half8*)(xb + (size_t)i * 8) = o;
        return;
    }
    if (b < 1536) {
        int e = (b - 512) * 256 + tid;
        int s = ei[e], d = ei[NE + e];
        int g = d >> 6;
        atomicAdd(&Acnt[(size_t)((g << 6) + (d & 63)) * 64 + (s & 63)], 1.0f);
        return;
    }
    // cvtT variants (32x8 layout from linear tid)
    const float* W; _Float16* Wt; int Kd, Nd, bx, by;
    if (b < 1600)      { int bb = b - 1536; W = fcW;   Wt = fcWt;   Kd = NF;  Nd = CL; bx = bb % 16; by = bb / 16; }
    else if (b < 2368) { int bb = b - 1600; W = featW; Wt = featWt; Kd = ZD;  Nd = CL; bx = bb % 16; by = bb / 16; }
    else               { int bb = b - 2368; W = fc1W;  Wt = fc1Wt;  Kd = 512; Nd = 64; bx = bb % 2;  by = bb / 2; }
    __shared__ float t[32][33];
    const int tx = tid & 31, ty = tid >> 5;
    const int kb = by * 32, nb = bx * 32;
    for (int i = ty; i < 32; i += 8)
        t[i][tx] = W[(size_t)(kb + i) * Nd + nb + tx];
    __syncthreads();
    for (int i = ty; i < 32; i += 8)
        Wt[(size_t)(nb + i) * Kd + kb + tx] = (_Float16)t[tx][i];
}

// ---------------- finalize adjacency: counts -> normalized, diag, f16 pre-swizzled ------
// one block per graph; deg = row-sum of count matrix.
__global__ __launch_bounds__(256)
void finalize_adj(const float* __restrict__ Acnt, _Float16* __restrict__ Ah)
{
    __shared__ float As[4096];
    __shared__ float rs[64];
    __shared__ float dinv1[64];
    const int g = blockIdx.x, tid = threadIdx.x;
    const float* Ag = Acnt + (size_t)g * 4096;
    for (int i = tid; i < 1024; i += 256)
        *(float4*)&As[i * 4] = *(const float4*)&Ag[i * 4];
    __syncthreads();
    if (tid < 64) {
        float s = 0.f;
        #pragma unroll
        for (int j = 0; j < 64; ++j) s += As[tid * 64 + j];
        float d = s + 1.0f;
        rs[tid] = rsqrtf(d);
        dinv1[tid] = 1.0f / d;
    }
    __syncthreads();
    for (int i = tid; i < 4096; i += 256) {
        int row = i >> 6, s = i & 63;
        float v = As[i] * rs[row] * rs[s];
        if (row == s) v += dinv1[row];
        Ah[(size_t)g * 4096 + (i ^ ((row & 7) << 3))] = (_Float16)v;
    }
}

// Fused BN-fold weight prep
__global__ void wprep(const float* __restrict__ W,
                      const float* __restrict__ sums, const float* __restrict__ sqs,
                      const float* __restrict__ g, const float* __restrict__ b,
                      _Float16* __restrict__ Wt, float* __restrict__ bias2,
                      int Kd, int Nd) {
    __shared__ float t[32][33];
    __shared__ float tks[32];
    int kb = blockIdx.y * 32, nb = blockIdx.x * 32;
    int tx = threadIdx.x, ty = threadIdx.y;
    for (int i = ty; i < 32; i += 8)
        t[i][tx] = W[(size_t)(kb + i) * Nd + nb + tx];
    int kc = kb + tx;
    float m = sums[kc] * (1.0f / NN);
    float var = sqs[kc] * (1.0f / NN) - m * m;
    float sc = rsqrtf(var + 1e-5f) * g[kc];
    if (ty == 0) tks[tx] = b[kc] - m * sc;
    __syncthreads();
    for (int i = ty; i < 32; i += 8)
        Wt[(size_t)(nb + i) * Kd + kb + tx] = (_Float16)(t[tx][i] * sc);
    if (ty == 0) {
        float acc = 0.f;
        #pragma unroll
        for (int i = 0; i < 32; ++i) acc = fmaf(tks[i], t[i][tx], acc);
        atomicAdd(&bias2[nb + tx], acc);
    }
}

// ---------------- f16 MFMA GEMM: C = A @ Bt^T, 128x64 tile, BK=64, XOR-swizzled LDS ---
template<int ACT, bool HASB, bool OUT16, bool STATS, bool FUSE>
__global__ __launch_bounds__(256)
void gemm_f16(const _Float16* __restrict__ A, int lda,
              const _Float16* __restrict__ Bt, int ldb,
              float* __restrict__ Cf, _Float16* __restrict__ Ch, int ldc,
              const float* __restrict__ bias, int K,
              float* __restrict__ sums, float* __restrict__ sqs,
              const _Float16* __restrict__ Ahg,
              const float* __restrict__ cb,
              _Float16* __restrict__ Zout)
{
    __shared__ __align__(16) char SMraw[FUSE ? 34816 : 24576];
    _Float16* As = (_Float16*)SMraw;              // [128][64]
    _Float16* Bs = (_Float16*)(SMraw + 16384);    // [64][64]
    const int tid = threadIdx.x;
    const int lane = tid & 63, wave = tid >> 6;
    const int wr = wave >> 1, wc = wave & 1;
    const int ntile = gridDim.x;
    const int li = blockIdx.y * ntile + blockIdx.x;
    const int x8 = li & 7, rest = li >> 3;
    const int bt = rest % ntile;
    const int bp = (rest / ntile) * 8 + x8;
    const int bm = bp * 128, bn = bt * 64;

    f32x4 acc[4][2];
    #pragma unroll
    for (int m = 0; m < 4; ++m)
        #pragma unroll
        for (int n = 0; n < 2; ++n)
            acc[m][n] = (f32x4){0.f, 0.f, 0.f, 0.f};

    const int fl = lane & 15, kh = (lane >> 4) * 8;
    const int sw = (fl & 7) << 3;

    for (int k0 = 0; k0 < K; k0 += 64) {
        #pragma unroll
        for (int j = 0; j < 4; ++j) {
            int d = wave * 2048 + j * 512 + lane * 8;
            int row = d >> 6, kk = d & 63;
            int sk = kk ^ ((row & 7) << 3);
            __builtin_amdgcn_global_load_lds(
                (const __attribute__((address_space(1))) void*)(A + (size_t)(bm + row) * lda + k0 + sk),
                (__attribute__((address_space(3))) void*)&As[wave * 2048 + j * 512], 16, 0, 0);
        }
        #pragma unroll
        for (int j = 0; j < 2; ++j) {
            int d = wave * 1024 + j * 512 + lane * 8;
            int row = d >> 6, kk = d & 63;
            int sk = kk ^ ((row & 7) << 3);
            __builtin_amdgcn_global_load_lds(
                (const __attribute__((address_space(1))) void*)(Bt + (size_t)(bn + row) * ldb + k0 + sk),
                (__attribute__((address_space(3))) void*)&Bs[wave * 1024 + j * 512], 16, 0, 0);
        }
        __syncthreads();
        #pragma unroll
        for (int kc = 0; kc < 2; ++kc) {
            int ko = (kc * 32 + kh) ^ sw;
            half8 av[4], bv[2];
            #pragma unroll
            for (int m = 0; m < 4; ++m)
                av[m] = *(const half8*)&As[(wr * 64 + m * 16 + fl) * 64 + ko];
            #pragma unroll
            for (int n = 0; n < 2; ++n)
                bv[n] = *(const half8*)&Bs[(wc * 32 + n * 16 + fl) * 64 + ko];
            #pragma unroll
            for (int m = 0; m < 4; ++m)
                #pragma unroll
                for (int n = 0; n < 2; ++n)
                    acc[m][n] = __builtin_amdgcn_mfma_f32_16x16x32_f16(av[m], bv[n], acc[m][n], 0, 0, 0);
        }
        __syncthreads();
    }

    const int orow0 = (lane >> 4) * 4;
    const int ocol  = lane & 15;

    if constexpr (!FUSE) {
        #pragma unroll
        for (int n = 0; n < 2; ++n) {
            int col = bn + wc * 32 + n * 16 + ocol;
            float bb = HASB ? bias[col] : 0.f;
            float ss = 0.f, qq = 0.f;
            #pragma unroll
            for (int m = 0; m < 4; ++m) {
                #pragma unroll
                for (int r = 0; r < 4; ++r) {
                    int rowg = bm + wr * 64 + m * 16 + orow0 + r;
                    float v = acc[m][n][r] + bb;
                    if (ACT == 2) v = v > 0.f ? v : 0.01f * v;
                    if (STATS) { ss += v; qq = fmaf(v, v, qq); }
                    if (OUT16) Ch[(size_t)rowg * ldc + col] = (_Float16)v;
                    else       Cf[(size_t)rowg * ldc + col] = v;
                }
            }
            if (STATS) {
                ss += __shfl_down(ss, 32); ss += __shfl_down(ss, 16);
                qq += __shfl_down(qq, 32); qq += __shfl_down(qq, 16);
                if (lane < 16) {
                    atomicAdd(&sums[col], ss);
                    atomicAdd(&sqs[col], qq);
                }
            }
        }
    } else {
        _Float16* AsA = (_Float16*)SMraw;            // [2][64][64] pre-swizzled adjacency
        _Float16* Xs  = (_Float16*)(SMraw + 16384);  // [64 cols][128 rows] swizzled C^T
        const _Float16* Ag = Ahg + (size_t)(bm >> 6) * 4096;
        #pragma unroll
        for (int j = 0; j < 4; ++j)
            __builtin_amdgcn_global_load_lds(
                (const __attribute__((address_space(1))) void*)(Ag + wave * 2048 + j * 512 + lane * 8),
                (__attribute__((address_space(3))) void*)&AsA[wave * 2048 + j * 512], 16, 0, 0);
        #pragma unroll
        for (int n = 0; n < 2; ++n) {
            int c = wc * 32 + n * 16 + ocol;
            float bb = HASB ? bias[bn + c] : 0.f;
            int csw = (c & 7) << 3;
            #pragma unroll
            for (int m = 0; m < 4; ++m) {
                #pragma unroll
                for (int r = 0; r < 4; ++r) {
                    int srow = wr * 64 + m * 16 + orow0 + r;
                    Xs[c * 128 + (srow & 64) + ((srow & 63) ^ csw)] = (_Float16)(acc[m][n][r] + bb);
                }
            }
        }
        __syncthreads();
        const int gg = wave >> 1, rh = wave & 1;
        f32x4 acc2[2][4];
        #pragma unroll
        for (int m2 = 0; m2 < 2; ++m2)
            #pragma unroll
            for (int n2 = 0; n2 < 4; ++n2)
                acc2[m2][n2] = (f32x4){0.f, 0.f, 0.f, 0.f};
        #pragma unroll
        for (int kc = 0; kc < 2; ++kc) {
            int ko = (kc * 32 + kh) ^ sw;
            #pragma unroll
            for (int m2 = 0; m2 < 2; ++m2) {
                int arow = rh * 32 + m2 * 16 + fl;
                half8 av = *(const half8*)&AsA[gg * 4096 + arow * 64 + ko];
                #pragma unroll
                for (int n2 = 0; n2 < 4; ++n2) {
                    int c = n2 * 16 + fl;
                    half8 bv = *(const half8*)&Xs[c * 128 + gg * 64 + ((kc * 32 + kh) ^ ((c & 7) << 3))];
                    acc2[m2][n2] = __builtin_amdgcn_mfma_f32_16x16x32_f16(av, bv, acc2[m2][n2], 0, 0, 0);
                }
            }
        }
        __syncthreads();
        float* Cs = (float*)SMraw;   // [128][68]
        #pragma unroll
        for (int m2 = 0; m2 < 2; ++m2)
            #pragma unroll
            for (int n2 = 0; n2 < 4; ++n2)
                #pragma unroll
                for (int r = 0; r < 4; ++r)
                    Cs[(gg * 64 + rh * 32 + m2 * 16 + orow0 + r) * 68 + n2 * 16 + ocol] = acc2[m2][n2][r];
        __syncthreads();
        const int rr = tid >> 3, dq = tid & 7;
        #pragma unroll
        for (int pass = 0; pass < 4; ++pass) {
            int row = pass * 32 + rr;
            half8 hv;
            #pragma unroll
            for (int e = 0; e < 8; ++e) {
                float v = Cs[row * 68 + dq * 8 + e] + cb[bn + dq * 8 + e];
                v = v > 0.f ? v : 0.f;
                hv[e] = (_Float16)v;
            }
            *(half8*)(Zout + (size_t)(bm + row) * ZD + bn + dq * 8) = hv;
        }
        if (STATS && tid < 64) {
            float bb = cb[bn + tid];
            float ss = 0.f, qq = 0.f;
            for (int row = 0; row < 128; ++row) {
                float v = Cs[row * 68 + tid] + bb;
                v = v > 0.f ? v : 0.f;
                ss += v;
                qq = fmaf(v, v, qq);
            }
            atomicAdd(&sums[bn + tid], ss);
            atomicAdd(&sqs[bn + tid], qq);
        }
    }
}

// ---------------- per-graph Gram, split-K: grid (NG, 2) ----------------
__global__ __launch_bounds__(256)
void gram_mfma(const _Float16* __restrict__ Z, float* __restrict__ Gparts)
{
    __shared__ _Float16 Zs[4096];   // [64][64]
    const int g = blockIdx.x, khalf = blockIdx.y;
    const int tid = threadIdx.x;
    const int lane = tid & 63, wave = tid >> 6;
    const int fl = lane & 15, kh = (lane >> 4) * 8;
    const int sw = (fl & 7) << 3;
    float* G = Gparts + (size_t)khalf * NG * 4096;

    f32x4 acc[4];
    #pragma unroll
    for (int n = 0; n < 4; ++n) acc[n] = (f32x4){0.f, 0.f, 0.f, 0.f};

    for (int k0 = khalf * (ZD / 2); k0 < (khalf + 1) * (ZD / 2); k0 += 64) {
        #pragma unroll
        for (int j = 0; j < 2; ++j) {
            int d = wave * 1024 + j * 512 + lane * 8;
            int row = d >> 6, kk = d & 63;
            int sk = kk ^ ((row & 7) << 3);
            __builtin_amdgcn_global_load_lds(
                (const __attribute__((address_space(1))) void*)(Z + (size_t)(g * 64 + row) * ZD + k0 + sk),
                (__attribute__((address_space(3))) void*)&Zs[wave * 1024 + j * 512], 16, 0, 0);
        }
        __syncthreads();
        #pragma unroll
        for (int kc = 0; kc < 2; ++kc) {
            int ko = (kc * 32 + kh) ^ sw;
            half8 av = *(const half8*)&Zs[(wave * 16 + fl) * 64 + ko];
            #pragma unroll
            for (int n = 0; n < 4; ++n) {
                half8 bv = *(const half8*)&Zs[(n * 16 + fl) * 64 + ko];
                acc[n] = __builtin_amdgcn_mfma_f32_16x16x32_f16(av, bv, acc[n], 0, 0, 0);
            }
        }
        __syncthreads();
    }
    const int orow0 = (lane >> 4) * 4;
    const int ocol  = lane & 15;
    #pragma unroll
    for (int n = 0; n < 4; ++n)
        #pragma unroll
        for (int r = 0; r < 4; ++r)
            G[(size_t)(g * 64 + wave * 16 + orow0 + r) * 64 + n * 16 + ocol] = acc[n][r];
}

// ---------------- edge loss (both sets; G = G0 + G1), lrc_final fused (last block) ------
__global__ void edge_loss2(const int* __restrict__ ei, const int* __restrict__ nei,
                           const float* __restrict__ G0, float* __restrict__ LOSS,
                           unsigned int* __restrict__ ctr, float* __restrict__ outLrc)
{
    const int setid = blockIdx.y;
    const int* e0 = setid ? nei : ei;
    const int* e1 = e0 + NE;
    float* tot = LOSS + setid * 256;
    float* cnt = tot + 128;
    const float* G1 = G0 + (size_t)NG * 4096;
    __shared__ float lt[128];
    __shared__ float lc[128];
    __shared__ float red[128];
    __shared__ unsigned int lastS;
    int tid = threadIdx.x;
    if (tid < 128) { lt[tid] = 0.f; lc[tid] = 0.f; }
    __syncthreads();
    for (int e = blockIdx.x * blockDim.x + tid; e < NE; e += gridDim.x * blockDim.x) {
        int a = e0[e], b = e1[e];
        int g = a >> 6;
        size_t idx = (size_t)((g << 6) + (a & 63)) * 64 + (b & 63);
        float v = G0[idx] + G1[idx];
        float s = 1.f / (1.f + expf(-v));
        float p = setid ? (1.f - s) : s;
        float l = -logf(1e-4f + p);
        atomicAdd(&lt[g], l);
        atomicAdd(&lc[g], 1.f);
    }
    __syncthreads();
    if (tid < 128) {
        atomicAdd(&tot[tid], lt[tid]);
        atomicAdd(&cnt[tid], lc[tid]);
    }
    __threadfence();
    __syncthreads();
    if (tid == 0) lastS = atomicAdd(ctr, 1u);
    __syncthreads();
    if (lastS == gridDim.x * gridDim.y - 1) {
        __threadfence();
        if (tid < 128) {
            float v = LOSS[tid] / fmaxf(LOSS[128 + tid], 1.f) +
                      LOSS[256 + tid] / fmaxf(LOSS[384 + tid], 1.f);
            red[tid] = v;
        }
        __syncthreads();
        for (int s = 64; s; s >>= 1) {
            if (tid < s && tid + s < 128) red[tid] += red[tid + s];
            __syncthreads();
        }
        if (tid == 0) outLrc[0] = red[0] * (1.0f / 128.0f);
    }
}

// ---------------- fused featW-GEMM + attention: 128x64 tile (2 graphs), per (panel, head) ----
__global__ __launch_bounds__(256)
void featattn(const _Float16* __restrict__ Z, const _Float16* __restrict__ featWt,
              const float* __restrict__ phi, _Float16* __restrict__ agg)
{
    __shared__ __align__(16) char SMraw[68608];
    _Float16* As  = (_Float16*)SMraw;             // [128][64] Z tile (phase 1)
    _Float16* Bs  = (_Float16*)(SMraw + 16384);   // [64][64] featW tile (phase 1)
    float*    Cs  = (float*)SMraw;                // [128][68] f32 (phase 2)
    _Float16* Xt  = (_Float16*)(SMraw + 34816);   // [2][d][b] swizzled
    _Float16* Ws  = (_Float16*)(SMraw + 51200);   // [2][i][b] swizzled
    float*    s1s = (float*)(SMraw + 67584);      // 128
    float*    s2s = (float*)(SMraw + 68096);      // 128
    const int pnl = blockIdx.x, h = blockIdx.y;
    const int bm = pnl * 128;
    const int tid = threadIdx.x;
    const int lane = tid & 63, wave = tid >> 6;
    const int wr = wave >> 1, wc = wave & 1;
    const int fl = lane & 15, kh = (lane >> 4) * 8;
    const int sw = (fl & 7) << 3;

    f32x4 acc[4][2];
    #pragma unroll
    for (int m = 0; m < 4; ++m)
        #pragma unroll
        for (int n = 0; n < 2; ++n)
            acc[m][n] = (f32x4){0.f, 0.f, 0.f, 0.f};

    for (int k0 = 0; k0 < ZD; k0 += 64) {
        #pragma unroll
        for (int j = 0; j < 4; ++j) {
            int d = wave * 2048 + j * 512 + lane * 8;
            int row = d >> 6, kk = d & 63;
            int sk = kk ^ ((row & 7) << 3);
            __builtin_amdgcn_global_load_lds(
                (const __attribute__((address_space(1))) void*)(Z + (size_t)(bm + row) * ZD + k0 + sk),
                (__attribute__((address_space(3))) void*)&As[wave * 2048 + j * 512], 16, 0, 0);
        }
        #pragma unroll
        for (int j = 0; j < 2; ++j) {
            int d = wave * 1024 + j * 512 + lane * 8;
            int row = d >> 6, kk = d & 63;
            int sk = kk ^ ((row & 7) << 3);
            __builtin_amdgcn_global_load_lds(
                (const __attribute__((address_space(1))) void*)(featWt + (size_t)(h * 64 + row) * ZD + k0 + sk),
                (__attribute__((address_space(3))) void*)&Bs[wave * 1024 + j * 512], 16, 0, 0);
        }
        __syncthreads();
        #pragma unroll
        for (int kc = 0; kc < 2; ++kc) {
            int ko = (kc * 32 + kh) ^ sw;
            half8 av[4], bv[2];
            #pragma unroll
            for (int m = 0; m < 4; ++m)
                av[m] = *(const half8*)&As[(wr * 64 + m * 16 + fl) * 64 + ko];
            #pragma unroll
            for (int n = 0; n < 2; ++n)
                bv[n] = *(const half8*)&Bs[(wc * 32 + n * 16 + fl) * 64 + ko];
            #pragma unroll
            for (int m = 0; m < 4; ++m)
                #pragma unroll
                for (int n = 0; n < 2; ++n)
                    acc[m][n] = __builtin_amdgcn_mfma_f32_16x16x32_f16(av[m], bv[n], acc[m][n], 0, 0, 0);
        }
        __syncthreads();
    }
    const int orow0 = (lane >> 4) * 4, ocol = lane & 15;
    #pragma unroll
    for (int n = 0; n < 2; ++n) {
        int col = wc * 32 + n * 16 + ocol;
        #pragma unroll
        for (int m = 0; m < 4; ++m)
            #pragma unroll
            for (int r = 0; r < 4; ++r)
                Cs[(wr * 64 + m * 16 + orow0 + r) * 68 + col] = acc[m][n][r];
    }
    __syncthreads();
    {
        const int bnode = tid >> 1, dq = tid & 1;
        const int gg = bnode >> 6, bloc = bnode & 63;
        const float* pa = phi + h * 128 + dq * 32;
        const float* pb = pa + 64;
        float sa = 0.f, sb = 0.f;
        #pragma unroll
        for (int j = 0; j < 32; ++j) {
            int d = dq * 32 + j;
            float vf = Cs[bnode * 68 + d];
            Xt[gg * 4096 + ((d * 64 + bloc) ^ ((d & 7) << 3))] = (_Float16)vf;
            sa = fmaf(vf, pa[j], sa);
            sb = fmaf(vf, pb[j], sb);
        }
        sa += __shfl_down(sa, 1);
        sb += __shfl_down(sb, 1);
        if (dq == 0) { s1s[bnode] = sa; s2s[bnode] = sb; }
    }
    __syncthreads();
    {
        const int inode = tid >> 1, bq = tid & 1;
        const int gg = inode >> 6, iloc = inode & 63;
        float si = s1s[inode];
        #pragma unroll
        for (int e = 0; e < 32; ++e) {
            int b = bq * 32 + e;
            float t = si + s2s[gg * 64 + b];
            t = t > 0.f ? t : 0.01f * t;
            float w = 1.f / (1.f + expf(-t));
            Ws[gg * 4096 + ((iloc * 64 + b) ^ ((iloc & 7) << 3))] = (_Float16)w;
        }
    }
    __syncthreads();
    const int gg = wave >> 1, rh = wave & 1;
    f32x4 acc2[2][4];
    #pragma unroll
    for (int m2 = 0; m2 < 2; ++m2)
        #pragma unroll
        for (int n2 = 0; n2 < 4; ++n2)
            acc2[m2][n2] = (f32x4){0.f, 0.f, 0.f, 0.f};
    #pragma unroll
    for (int kc = 0; kc < 2; ++kc) {
        #pragma unroll
        for (int m2 = 0; m2 < 2; ++m2) {
            int arow = rh * 32 + m2 * 16 + fl;
            half8 av = *(const half8*)&Ws[gg * 4096 + ((arow * 64 + kc * 32 + kh) ^ ((arow & 7) << 3))];
            #pragma unroll
            for (int n2 = 0; n2 < 4; ++n2) {
                int rowb = n2 * 16 + fl;
                half8 bv = *(const half8*)&Xt[gg * 4096 + ((rowb * 64 + kc * 32 + kh) ^ ((rowb & 7) << 3))];
                acc2[m2][n2] = __builtin_amdgcn_mfma_f32_16x16x32_f16(av, bv, acc2[m2][n2], 0, 0, 0);
            }
        }
    }
    __syncthreads();
    #pragma unroll
    for (int m2 = 0; m2 < 2; ++m2)
        #pragma unroll
        for (int n2 = 0; n2 < 4; ++n2)
            #pragma unroll
            for (int r = 0; r < 4; ++r)
                Cs[(gg * 64 + rh * 32 + m2 * 16 + orow0 + r) * 68 + n2 * 16 + ocol] = acc2[m2][n2][r];
    __syncthreads();
    {
        const int rr = tid >> 3, dq = tid & 7;
        #pragma unroll
        for (int pass = 0; pass < 4; ++pass) {
            int row = pass * 32 + rr;
            half8 hv;
            #pragma unroll
            for (int e = 0; e < 8; ++e)
                hv[e] = (_Float16)Cs[row * 68 + dq * 8 + e];
            *(half8*)(agg + (size_t)(bm + row) * CL + h * 64 + dq * 8) = hv;
        }
    }
}

// ---------------- fused fc1 + head + per-graph mean, per graph ----------------
__global__ __launch_bounds__(256)
void fc1head(const _Float16* __restrict__ AGG, const _Float16* __restrict__ fc1Wt,
             const float* __restrict__ fc1b,
             const float* __restrict__ fc2W, const float* __restrict__ fc2b,
             float* __restrict__ preds, float* __restrict__ outlog)
{
    __shared__ __align__(16) char SMraw[17664];
    _Float16* As = (_Float16*)SMraw;              // [64][64]
    _Float16* Bs = (_Float16*)(SMraw + 8192);     // [64][64]
    float*    Cs = (float*)SMraw;                 // [64][69] f32 hid
    const int g = blockIdx.x;
    const int tid = threadIdx.x;
    const int lane = tid & 63, wave = tid >> 6;
    const int fl = lane & 15, kh = (lane >> 4) * 8;
    const int sw = (fl & 7) << 3;

    f32x4 acc[4];
    #pragma unroll
    for (int n = 0; n < 4; ++n) acc[n] = (f32x4){0.f, 0.f, 0.f, 0.f};

    for (int k0 = 0; k0 < CL; k0 += 64) {
        #pragma unroll
        for (int j = 0; j < 2; ++j) {
            int d = wave * 1024 + j * 512 + lane * 8;
            int row = d >> 6, kk = d & 63;
            int sk = kk ^ ((row & 7) << 3);
            __builtin_amdgcn_global_load_lds(
                (const __attribute__((address_space(1))) void*)(AGG + (size_t)(g * 64 + row) * CL + k0 + sk),
                (__attribute__((address_space(3))) void*)&As[wave * 1024 + j * 512], 16, 0, 0);
            __builtin_amdgcn_global_load_lds(
                (const __attribute__((address_space(1))) void*)(fc1Wt + (size_t)row * CL + k0 + sk),
                (__attribute__((address_space(3))) void*)&Bs[wave * 1024 + j * 512], 16, 0, 0);
        }
        __syncthreads();
        #pragma unroll
        for (int kc = 0; kc < 2; ++kc) {
            int ko = (kc * 32 + kh) ^ sw;
            half8 av = *(const half8*)&As[(wave * 16 + fl) * 64 + ko];
            #pragma unroll
            for (int n = 0; n < 4; ++n) {
                half8 bv = *(const half8*)&Bs[(n * 16 + fl) * 64 + ko];
                acc[n] = __builtin_amdgcn_mfma_f32_16x16x32_f16(av, bv, acc[n], 0, 0, 0);
            }
        }
        __syncthreads();
    }
    const int orow0 = (lane >> 4) * 4, ocol = lane & 15;
    #pragma unroll
    for (int n = 0; n < 4; ++n) {
        int col = n * 16 + ocol;
        float bb = fc1b[col];
        #pragma unroll
        for (int r = 0; r < 4; ++r) {
            float v = acc[n][r] + bb;
            v = v > 0.f ? v : 0.01f * v;
            Cs[(wave * 16 + orow0 + r) * 69 + col] = v;
        }
    }
    __syncthreads();
    if (tid < 64) {
        float lg[10];
        float mx = -1e30f;
        #pragma unroll
        for (int c = 0; c < 10; ++c) {
            float s = fc2b[c];
            #pragma unroll
            for (int k = 0; k < 64; ++k) s = fmaf(Cs[tid * 69 + k], fc2W[k * 10 + c], s);
            lg[c] = s;
            mx = fmaxf(mx, s);
        }
        float sum = 0.f;
        #pragma unroll
        for (int c = 0; c < 10; ++c) {
            float t = expf(lg[c] - mx) + 1e-4f;
            lg[c] = t;
            sum += t;
        }
        float inv = 1.f / sum;
        #pragma unroll
        for (int c = 0; c < 10; ++c) {
            lg[c] *= inv;
            preds[(size_t)(g * 64 + tid) * 10 + c] = lg[c];
        }
        #pragma unroll
        for (int off = 32; off; off >>= 1)
            #pragma unroll
            for (int c = 0; c < 10; ++c) lg[c] += __shfl_down(lg[c], off);
        if (tid == 0)
            #pragma unroll
            for (int c = 0; c < 10; ++c) outlog[g * 10 + c] = logf(lg[c] * (1.0f / 64.0f));
    }
}

extern "C" void kernel_launch(void* const* d_in, const int* in_sizes, int n_in,
                              void* d_out, int out_size, void* d_ws, size_t ws_size,
                              hipStream_t stream)
{
    (void)in_sizes; (void)n_in; (void)out_size; (void)ws_size;
    const float* x     = (const float*)d_in[0];
    const int*   ei    = (const int*)d_in[1];
    const int*   nei   = (const int*)d_in[2];
    const float* fcW   = (const float*)d_in[5];
    const float* fcb   = (const float*)d_in[6];
    const float* bng   = (const float*)d_in[7];
    const float* bnb   = (const float*)d_in[8];
    const float* convW = (const float*)d_in[9];
    const float* convb = (const float*)d_in[10];
    const float* featW = (const float*)d_in[11];
    const float* phi   = (const float*)d_in[12];
    const float* fc1W  = (const float*)d_in[13];
    const float* fc1b  = (const float*)d_in[14];
    const float* fc2W  = (const float*)d_in[15];
    const float* fc2b  = (const float*)d_in[16];
    float* out = (float*)d_out;

    char* ws = (char*)d_ws;
    _Float16* Z       = (_Float16*)(ws);              // 24 MB  -> 25165824
    _Float16* H0      = (_Float16*)(ws + 25165824);   // 8 MB   -> 33554432
    _Float16* AGG     = (_Float16*)(ws + 33554432);   // 8 MB   -> 41943040
    _Float16* xb      = (_Float16*)(ws + 41943040);   // 2 MB   -> 44040192
    _Float16* fcWt    = (_Float16*)(ws + 44040192);   // 128 KB -> 44171264
    _Float16* convWs  = (_Float16*)(ws + 44171264);   // 512 KB -> 44695552
    _Float16* featWt  = (_Float16*)(ws + 44695552);   // 1.5 MB -> 46268416
    _Float16* fc1Wt   = (_Float16*)(ws + 46268416);   // 64 KB  -> 46333952
    _Float16* Ah      = (_Float16*)(ws + 46333952);   // 1 MB   -> 47382528
    float*    Gram    = (float*)(ws + 47382528);      // 4 MB (2 parts) -> 51576832
    // zeroed region: Acnt + LOSS + BNS3 + B2x3 + CTR
    float*    Acnt    = (float*)(ws + 51576832);      // 2 MB   -> 53673984
    float*    LOSS    = (float*)(ws + 53673984);      // 2 KB   -> 53676032
    float*    BNS3    = (float*)(ws + 53676032);      // 12 KB  -> 53688320
    float*    B2      = (float*)(ws + 53688320);      // 6 KB   -> 53694464
    unsigned int* CTR = (unsigned int*)(ws + 53694464); // 256 B -> 53694720

    hipMemsetAsync(Acnt, 0, 53694720 - 51576832, stream);

    // consolidated prep: cvt_h + 3x weight transpose + edge-count atomics
    prep_misc<<<2400, 256, 0, stream>>>(x, xb, fcW, fcWt, featW, featWt,
                                        fc1W, fc1Wt, ei, Acnt);
    // counts -> normalized f16 pre-swizzled adjacency (deg from row-sums, diag folded)
    finalize_adj<<<NG, 256, 0, stream>>>(Acnt, Ah);

    // h0 = x @ fc_W + fc_b  (f16 out, layer-0 BN stats fused)
    gemm_f16<0, true, true, true, false><<<dim3(CL / 64, NN / 128), 256, 0, stream>>>(
        xb, NF, fcWt, NF, nullptr, H0, CL, fcb, NF, BNS3, BNS3 + 512,
        nullptr, nullptr, nullptr);

    for (int i = 0; i < 3; ++i) {
        const _Float16* Ain = (i == 0) ? H0 : (Z + (size_t)(i - 1) * CL);
        int lda = (i == 0) ? CL : ZD;
        float* sums = BNS3 + i * 1024;
        float* sqs  = sums + 512;
        float* b2   = B2 + i * 512;
        wprep<<<dim3(CL / 32, CL / 32), dim3(32, 8), 0, stream>>>(
            convW + (size_t)i * CL * CL, sums, sqs, bng + i * CL, bnb + i * CL,
            convWs, b2, CL, CL);
        if (i < 2)
            gemm_f16<0, true, false, true, true><<<dim3(CL / 64, NN / 128), 256, 0, stream>>>(
                Ain, lda, convWs, CL, nullptr, nullptr, 0, b2, CL,
                BNS3 + (i + 1) * 1024, BNS3 + (i + 1) * 1024 + 512,
                Ah, convb + i * CL, Z + (size_t)i * CL);
        else
            gemm_f16<0, true, false, false, true><<<dim3(CL / 64, NN / 128), 256, 0, stream>>>(
                Ain, lda, convWs, CL, nullptr, nullptr, 0, b2, CL,
                nullptr, nullptr, Ah, convb + i * CL, Z + (size_t)i * CL);
    }

    // edge reconstruction loss via split-K per-graph Gram (lrc fused into edge_loss2)
    gram_mfma<<<dim3(NG, 2), 256, 0, stream>>>(Z, Gram);
    edge_loss2<<<dim3(128, 2), 256, 0, stream>>>(ei, nei, Gram, LOSS, CTR, out + 1280);

    // fused featW GEMM (128x64 tile, 2 graphs/block) + attention -> AGG (f16)
    featattn<<<dim3(64, 8), 256, 0, stream>>>(Z, featWt, phi, AGG);

    // fused fc1 + head + per-graph mean
    fc1head<<<NG, 256, 0, stream>>>(AGG, fc1Wt, fc1b, fc2W, fc2b, out + 1281, out);
}